// Round 4
// baseline (23083.067 us; speedup 1.0000x reference)
//
#include <hip/hip_runtime.h>
#include <hip/hip_bf16.h>

// ---- model dims ----
constexpr int TB = 512, TL = 200, TH = 128, TNH = 4, TD = 32;
constexpr int TFT = 32, TTP = 64, TIP = 200;
constexpr int TSH = 512, TFH = 256;
constexpr int TITEMS = 100001;
constexpr int TNT = TB * TTP;   // 32768
constexpr int TNI = TB * TIP;   // 102400

__device__ inline float gelu_exact(float x) {
    return 0.5f * x * (1.0f + erff(x * 0.7071067811865476f));
}

__device__ inline float block_reduce_sum(float v, float* red) {
    for (int o = 32; o > 0; o >>= 1) v += __shfl_down(v, o, 64);
    int nw = blockDim.x >> 6;
    if ((threadIdx.x & 63) == 0) red[threadIdx.x >> 6] = v;
    __syncthreads();
    float r = 0.f;
    for (int w = 0; w < nw; ++w) r += red[w];
    __syncthreads();
    return r;
}

__device__ inline float block_reduce_max(float v, float* red) {
    for (int o = 32; o > 0; o >>= 1) v = fmaxf(v, __shfl_down(v, o, 64));
    int nw = blockDim.x >> 6;
    if ((threadIdx.x & 63) == 0) red[threadIdx.x >> 6] = v;
    __syncthreads();
    float r = -INFINITY;
    for (int w = 0; w < nw; ++w) r = fmaxf(r, red[w]);
    __syncthreads();
    return r;
}

// out[r,:] = table[idx[r],:]
__global__ __launch_bounds__(256) void k_gather(const float* __restrict__ tab,
                                                const int* __restrict__ idx,
                                                float* __restrict__ out, int nrows) {
    int e = blockIdx.x * blockDim.x + threadIdx.x;
    if (e >= nrows * 32) return;
    int r = e >> 5, c = e & 31;
    ((float4*)out)[e] = ((const float4*)tab)[(size_t)idx[r] * 32 + c];
}

// row-wise LayerNorm over H=128: 8 rows / 256-thread block, float4 lanes
__global__ __launch_bounds__(256) void k_ln(const float* __restrict__ x, float* __restrict__ y,
                                            const float* __restrict__ g, const float* __restrict__ b) {
    int row = blockIdx.x * 8 + (threadIdx.x >> 5);
    int lane = threadIdx.x & 31;
    const float4 v = ((const float4*)(x + (size_t)row * TH))[lane];
    float s = v.x + v.y + v.z + v.w;
    for (int o = 16; o > 0; o >>= 1) s += __shfl_down(s, o, 32);
    float mean = __shfl(s, 0, 32) * (1.f / 128.f);
    float4 d;
    d.x = v.x - mean; d.y = v.y - mean; d.z = v.z - mean; d.w = v.w - mean;
    float q = d.x * d.x + d.y * d.y + d.z * d.z + d.w * d.w;
    for (int o = 16; o > 0; o >>= 1) q += __shfl_down(q, o, 32);
    float inv = rsqrtf(__shfl(q, 0, 32) * (1.f / 128.f) + 1e-8f);
    const float4 gg = ((const float4*)g)[lane];
    const float4 bb = ((const float4*)b)[lane];
    float4 o4;
    o4.x = d.x * inv * gg.x + bb.x;
    o4.y = d.y * inv * gg.y + bb.y;
    o4.z = d.z * inv * gg.z + bb.z;
    o4.w = d.w * inv * gg.w + bb.w;
    ((float4*)(y + (size_t)row * TH))[lane] = o4;
}

// fused seq-mixing block; 16 h-columns per block
__global__ __launch_bounds__(256) void k_scb(const float* __restrict__ nv, float* __restrict__ vs,
                                             const float* __restrict__ w1, const float* __restrict__ w2) {
    __shared__ __align__(16) float nvc[TL][16];
    __shared__ __align__(16) float tt[TSH][20];
    int b = blockIdx.x >> 3;
    int h0 = (blockIdx.x & 7) * 16;
    int tid = threadIdx.x;
    for (int i = tid; i < TL * 4; i += 256) {
        int l = i >> 2, q = i & 3;
        const float4 v = *(const float4*)(nv + (size_t)(b * TL + l) * TH + h0 + q * 4);
        nvc[l][q * 4 + 0] = v.x; nvc[l][q * 4 + 1] = v.y;
        nvc[l][q * 4 + 2] = v.z; nvc[l][q * 4 + 3] = v.w;
    }
    __syncthreads();
    {
        float a0[16], a1[16];
#pragma unroll
        for (int j = 0; j < 16; ++j) { a0[j] = 0.f; a1[j] = 0.f; }
        for (int l = 0; l < TL; ++l) {
            const float4 n0 = *(const float4*)&nvc[l][0];
            const float4 n1 = *(const float4*)&nvc[l][4];
            const float4 n2 = *(const float4*)&nvc[l][8];
            const float4 n3 = *(const float4*)&nvc[l][12];
            float wa = w1[l * TSH + tid];
            float wb = w1[l * TSH + tid + 256];
            a0[0] += n0.x * wa; a0[1] += n0.y * wa; a0[2] += n0.z * wa; a0[3] += n0.w * wa;
            a0[4] += n1.x * wa; a0[5] += n1.y * wa; a0[6] += n1.z * wa; a0[7] += n1.w * wa;
            a0[8] += n2.x * wa; a0[9] += n2.y * wa; a0[10] += n2.z * wa; a0[11] += n2.w * wa;
            a0[12] += n3.x * wa; a0[13] += n3.y * wa; a0[14] += n3.z * wa; a0[15] += n3.w * wa;
            a1[0] += n0.x * wb; a1[1] += n0.y * wb; a1[2] += n0.z * wb; a1[3] += n0.w * wb;
            a1[4] += n1.x * wb; a1[5] += n1.y * wb; a1[6] += n1.z * wb; a1[7] += n1.w * wb;
            a1[8] += n2.x * wb; a1[9] += n2.y * wb; a1[10] += n2.z * wb; a1[11] += n2.w * wb;
            a1[12] += n3.x * wb; a1[13] += n3.y * wb; a1[14] += n3.z * wb; a1[15] += n3.w * wb;
        }
#pragma unroll
        for (int q = 0; q < 4; ++q) {
            float4 u;
            u.x = gelu_exact(a0[q * 4 + 0]); u.y = gelu_exact(a0[q * 4 + 1]);
            u.z = gelu_exact(a0[q * 4 + 2]); u.w = gelu_exact(a0[q * 4 + 3]);
            *(float4*)&tt[tid][q * 4] = u;
            float4 v;
            v.x = gelu_exact(a1[q * 4 + 0]); v.y = gelu_exact(a1[q * 4 + 1]);
            v.z = gelu_exact(a1[q * 4 + 2]); v.w = gelu_exact(a1[q * 4 + 3]);
            *(float4*)&tt[tid + 256][q * 4] = v;
        }
    }
    __syncthreads();
    if (tid < TL) {
        float acc[16];
#pragma unroll
        for (int j = 0; j < 16; ++j) acc[j] = nvc[tid][j];
        for (int s = 0; s < TSH; ++s) {
            const float4 t0 = *(const float4*)&tt[s][0];
            const float4 t1 = *(const float4*)&tt[s][4];
            const float4 t2 = *(const float4*)&tt[s][8];
            const float4 t3 = *(const float4*)&tt[s][12];
            float wl = w2[s * TL + tid];
            acc[0] += t0.x * wl; acc[1] += t0.y * wl; acc[2] += t0.z * wl; acc[3] += t0.w * wl;
            acc[4] += t1.x * wl; acc[5] += t1.y * wl; acc[6] += t1.z * wl; acc[7] += t1.w * wl;
            acc[8] += t2.x * wl; acc[9] += t2.y * wl; acc[10] += t2.z * wl; acc[11] += t2.w * wl;
            acc[12] += t3.x * wl; acc[13] += t3.y * wl; acc[14] += t3.z * wl; acc[15] += t3.w * wl;
        }
        float* vp = &vs[(size_t)(b * TL + tid) * TH + h0];
#pragma unroll
        for (int q = 0; q < 4; ++q) {
            float4 u;
            u.x = acc[q * 4 + 0]; u.y = acc[q * 4 + 1];
            u.z = acc[q * 4 + 2]; u.w = acc[q * 4 + 3];
            *(float4*)(vp + q * 4) = u;
        }
    }
}

// Y[NR,256](bf16) = gelu(A[NR,32] @ W[32,256]); NR multiple of 64
__global__ __launch_bounds__(256) void k_fcb1(const float* __restrict__ A, const float* __restrict__ W,
                                              __hip_bfloat16* __restrict__ Y) {
    __shared__ __align__(16) float At[32][64];
    __shared__ __align__(16) float Ws[32][256];
    int row0 = blockIdx.x * 64;
    int tid = threadIdx.x;
    for (int i = tid; i < 512; i += 256) {
        int r = i >> 3, c4 = i & 7;
        const float4 v = ((const float4*)(A + (size_t)(row0 + r) * 32))[c4];
        At[c4 * 4 + 0][r] = v.x; At[c4 * 4 + 1][r] = v.y;
        At[c4 * 4 + 2][r] = v.z; At[c4 * 4 + 3][r] = v.w;
    }
    for (int i = tid; i < 2048; i += 256) {
        int c = i >> 6, f4 = i & 63;
        ((float4*)&Ws[c][0])[f4] = ((const float4*)(W + c * 256))[f4];
    }
    __syncthreads();
    int rm = (tid >> 4) * 4;
    int fg = (tid & 15) * 4;
    float acc[4][4][4];   // [q][row][col]
#pragma unroll
    for (int q = 0; q < 4; ++q)
#pragma unroll
        for (int j = 0; j < 4; ++j)
#pragma unroll
            for (int i = 0; i < 4; ++i) acc[q][j][i] = 0.f;
    for (int c = 0; c < 32; ++c) {
        const float4 av = *(const float4*)&At[c][rm];
        float a[4] = {av.x, av.y, av.z, av.w};
#pragma unroll
        for (int q = 0; q < 4; ++q) {
            const float4 wv = *(const float4*)&Ws[c][fg + q * 64];
#pragma unroll
            for (int j = 0; j < 4; ++j) {
                acc[q][j][0] += a[j] * wv.x;
                acc[q][j][1] += a[j] * wv.y;
                acc[q][j][2] += a[j] * wv.z;
                acc[q][j][3] += a[j] * wv.w;
            }
        }
    }
#pragma unroll
    for (int q = 0; q < 4; ++q)
#pragma unroll
        for (int j = 0; j < 4; ++j) {
            ushort4 u;
            __hip_bfloat16 h0 = __float2bfloat16(gelu_exact(acc[q][j][0]));
            __hip_bfloat16 h1 = __float2bfloat16(gelu_exact(acc[q][j][1]));
            __hip_bfloat16 h2 = __float2bfloat16(gelu_exact(acc[q][j][2]));
            __hip_bfloat16 h3 = __float2bfloat16(gelu_exact(acc[q][j][3]));
            u.x = *reinterpret_cast<unsigned short*>(&h0);
            u.y = *reinterpret_cast<unsigned short*>(&h1);
            u.z = *reinterpret_cast<unsigned short*>(&h2);
            u.w = *reinterpret_cast<unsigned short*>(&h3);
            *(ushort4*)(Y + (size_t)(row0 + rm + j) * 256 + fg + q * 64) = u;
        }
}

// Z[NRH,32](f32) = Y[NRH,256](bf16) @ W2[256,32]; NRH multiple of 128
__global__ __launch_bounds__(256) void k_fcb2(const __hip_bfloat16* __restrict__ Y,
                                              const float* __restrict__ W2, float* __restrict__ Z) {
    __shared__ __align__(16) float w2s[256][32];
    __shared__ __align__(16) float At[32][132];
    int row0 = blockIdx.x * 128;
    int tid = threadIdx.x;
    for (int i = tid; i < 2048; i += 256) {
        int s = i >> 3, c4 = i & 7;
        ((float4*)&w2s[s][0])[c4] = ((const float4*)(W2 + s * 32))[c4];
    }
    int g = tid >> 4;                 // 0..15
    int rma = g * 4, rmb = 64 + g * 4;
    int c0 = (tid & 15) * 2;
    float acc[8][2];
#pragma unroll
    for (int j = 0; j < 8; ++j) { acc[j][0] = 0.f; acc[j][1] = 0.f; }
    for (int kc = 0; kc < 8; ++kc) {
        __syncthreads();
        for (int i = tid; i < 512; i += 256) {
            int r = i >> 2, j8 = i & 3;
            const uint4 u = *(const uint4*)(Y + (size_t)(row0 + r) * 256 + kc * 32 + j8 * 8);
            unsigned int w0 = u.x, w1v = u.y, w2v = u.z, w3v = u.w;
            At[j8 * 8 + 0][r] = __uint_as_float(w0 << 16);
            At[j8 * 8 + 1][r] = __uint_as_float(w0 & 0xffff0000u);
            At[j8 * 8 + 2][r] = __uint_as_float(w1v << 16);
            At[j8 * 8 + 3][r] = __uint_as_float(w1v & 0xffff0000u);
            At[j8 * 8 + 4][r] = __uint_as_float(w2v << 16);
            At[j8 * 8 + 5][r] = __uint_as_float(w2v & 0xffff0000u);
            At[j8 * 8 + 6][r] = __uint_as_float(w3v << 16);
            At[j8 * 8 + 7][r] = __uint_as_float(w3v & 0xffff0000u);
        }
        __syncthreads();
        for (int k = 0; k < 32; ++k) {
            const float4 a0 = *(const float4*)&At[k][rma];
            const float4 a1 = *(const float4*)&At[k][rmb];
            const float2 wv = *(const float2*)&w2s[kc * 32 + k][c0];
            acc[0][0] += a0.x * wv.x; acc[0][1] += a0.x * wv.y;
            acc[1][0] += a0.y * wv.x; acc[1][1] += a0.y * wv.y;
            acc[2][0] += a0.z * wv.x; acc[2][1] += a0.z * wv.y;
            acc[3][0] += a0.w * wv.x; acc[3][1] += a0.w * wv.y;
            acc[4][0] += a1.x * wv.x; acc[4][1] += a1.x * wv.y;
            acc[5][0] += a1.y * wv.x; acc[5][1] += a1.y * wv.y;
            acc[6][0] += a1.z * wv.x; acc[6][1] += a1.z * wv.y;
            acc[7][0] += a1.w * wv.x; acc[7][1] += a1.w * wv.y;
        }
    }
#pragma unroll
    for (int j = 0; j < 4; ++j) {
        float2 u0; u0.x = acc[j][0]; u0.y = acc[j][1];
        *(float2*)(Z + (size_t)(row0 + rma + j) * 32 + c0) = u0;
        float2 u1; u1.x = acc[4 + j][0]; u1.y = acc[4 + j][1];
        *(float2*)(Z + (size_t)(row0 + rmb + j) * 32 + c0) = u1;
    }
}

// C[N,128] = A[N,128] @ W[128,128] (+R); N multiple of 64
__global__ __launch_bounds__(256) void k_gk128(const float* __restrict__ A, const float* __restrict__ W,
                                               float* __restrict__ C, const float* __restrict__ R) {
    __shared__ __align__(16) float Ws[32][128];
    __shared__ __align__(16) float At[32][68];
    int row0 = blockIdx.x * 64;
    int tid = threadIdx.x;
    int rm = (tid >> 4) * 4;
    int fg = (tid & 15) * 4;
    float acc[2][4][4];   // [q][row][col]
#pragma unroll
    for (int q = 0; q < 2; ++q)
#pragma unroll
        for (int j = 0; j < 4; ++j)
#pragma unroll
            for (int i = 0; i < 4; ++i) acc[q][j][i] = 0.f;
    for (int kc = 0; kc < 4; ++kc) {
        __syncthreads();
        for (int i = tid; i < 512; i += 256) {
            int r = i >> 3, c4 = i & 7;
            const float4 v = *(const float4*)(A + (size_t)(row0 + r) * 128 + kc * 32 + c4 * 4);
            At[c4 * 4 + 0][r] = v.x; At[c4 * 4 + 1][r] = v.y;
            At[c4 * 4 + 2][r] = v.z; At[c4 * 4 + 3][r] = v.w;
        }
        for (int i = tid; i < 1024; i += 256) {
            int k = i >> 5, f4 = i & 31;
            ((float4*)&Ws[k][0])[f4] = ((const float4*)(W + (kc * 32 + k) * 128))[f4];
        }
        __syncthreads();
        for (int k = 0; k < 32; ++k) {
            const float4 av = *(const float4*)&At[k][rm];
            float a[4] = {av.x, av.y, av.z, av.w};
#pragma unroll
            for (int q = 0; q < 2; ++q) {
                const float4 wv = *(const float4*)&Ws[k][fg + q * 64];
#pragma unroll
                for (int j = 0; j < 4; ++j) {
                    acc[q][j][0] += a[j] * wv.x;
                    acc[q][j][1] += a[j] * wv.y;
                    acc[q][j][2] += a[j] * wv.z;
                    acc[q][j][3] += a[j] * wv.w;
                }
            }
        }
    }
#pragma unroll
    for (int q = 0; q < 2; ++q)
#pragma unroll
        for (int j = 0; j < 4; ++j) {
            size_t off = (size_t)(row0 + rm + j) * 128 + fg + q * 64;
            float4 u;
            u.x = acc[q][j][0]; u.y = acc[q][j][1]; u.z = acc[q][j][2]; u.w = acc[q][j][3];
            if (R) {
                const float4 rv = *(const float4*)(R + off);
                u.x += rv.x; u.y += rv.y; u.z += rv.z; u.w += rv.w;
            }
            *(float4*)(C + off) = u;
        }
}

// alpha = softmax(V@wv over L); g = sum_l alpha*V
__global__ __launch_bounds__(256) void k_pool(const float* __restrict__ V, const float* __restrict__ wv,
                                              float* __restrict__ g) {
    __shared__ float sc[TL];
    __shared__ float red[4];
    int b = blockIdx.x, tid = threadIdx.x;
    if (tid < TL) {
        float a = 0.f;
        const float* vp = V + (size_t)(b * TL + tid) * TH;
        for (int h = 0; h < TH; ++h) a += vp[h] * wv[h];
        sc[tid] = a;
    }
    __syncthreads();
    float m = (tid < TL) ? sc[tid] : -INFINITY;
    m = block_reduce_max(m, red);
    float e = (tid < TL) ? expf(sc[tid] - m) : 0.f;
    float s = block_reduce_sum(e, red);
    if (tid < TL) sc[tid] = e / s;
    __syncthreads();
    if (tid < TH) {
        float a = 0.f;
        for (int l = 0; l < TL; ++l) a += sc[l] * V[(size_t)(b * TL + l) * TH + tid];
        g[b * TH + tid] = a;
    }
}

// out[n,k] = sum_d f[n, k*32+d] * vec[k*32+d]
__global__ __launch_bounds__(256) void k_scores(const float* __restrict__ f, const float* __restrict__ vec,
                                                float* __restrict__ out, int n) {
    int idx = blockIdx.x * blockDim.x + threadIdx.x;
    if (idx >= n * TNH) return;
    int node = idx >> 2, k = idx & 3;
    const float* fp = f + (size_t)node * TH + k * TD;
    const float* vp = vec + k * TD;
    float a = 0.f;
#pragma unroll
    for (int d = 0; d < TD; ++d) a += fp[d] * vp[d];
    out[idx] = a;
}

// fused per-dst-node GAT for both graphs
__global__ __launch_bounds__(128) void k_gat(const float* __restrict__ tax_cur,
                                             const float* __restrict__ fs_i, const float* __restrict__ el_i,
                                             const float* __restrict__ er_i, const int* __restrict__ src_i,
                                             const float* __restrict__ bi,
                                             const float* __restrict__ fs_t, const float* __restrict__ el_t,
                                             const float* __restrict__ er_t, const int* __restrict__ src_t,
                                             const float* __restrict__ bt,
                                             float* __restrict__ tax_nxt, float* __restrict__ acc, int hop) {
    int n = blockIdx.x, h = threadIdx.x, k = h >> 5;
    float cur = tax_cur[(size_t)n * TH + h];
    float ti, tt2;
    {
        float er = er_i[n * 4 + k];
        int s[4]; float e[4]; float m = -INFINITY;
#pragma unroll
        for (int j = 0; j < 4; ++j) {
            s[j] = src_i[n * 4 + j];
            float xx = el_i[s[j] * 4 + k] + er;
            e[j] = xx > 0.f ? xx : 0.2f * xx;
            m = fmaxf(m, e[j]);
        }
        float ssum = 0.f, av = 0.f;
#pragma unroll
        for (int j = 0; j < 4; ++j) {
            float a = expf(e[j] - m);
            ssum += a;
            av += a * fs_i[(size_t)s[j] * TH + h];
        }
        ti = fmaxf(av / ssum + cur + bi[h], 0.f);
    }
    {
        float er = er_t[n * 4 + k];
        int s[2]; float e[2]; float m = -INFINITY;
#pragma unroll
        for (int j = 0; j < 2; ++j) {
            s[j] = src_t[n * 2 + j];
            float xx = el_t[s[j] * 4 + k] + er;
            e[j] = xx > 0.f ? xx : 0.2f * xx;
            m = fmaxf(m, e[j]);
        }
        float ssum = 0.f, av = 0.f;
#pragma unroll
        for (int j = 0; j < 2; ++j) {
            float a = expf(e[j] - m);
            ssum += a;
            av += a * fs_t[(size_t)s[j] * TH + h];
        }
        tt2 = fmaxf(av / ssum + cur + bt[h], 0.f);
    }
    float nx = ti + tt2;
    size_t ai = (size_t)n * TH + h;
    tax_nxt[ai] = nx;
    acc[ai] = (hop == 0) ? nx : acc[ai] + nx;
}

// local + mul
__global__ __launch_bounds__(128) void k_local(const int* __restrict__ root, const float* __restrict__ acc,
                                               const float* __restrict__ g, float* __restrict__ local,
                                               float* __restrict__ mul) {
    __shared__ float red[2];
    int bf = blockIdx.x, b = bf >> 5;
    int h = threadIdx.x;
    int r = root[bf];
    float v = 0.f;
    if (r != -1) {
        int rc = r < 0 ? 0 : r;
        v = acc[(size_t)(b * TTP + rc) * TH + h] * 0.5f;
    }
    local[(size_t)bf * TH + h] = v;
    float s = block_reduce_sum(v * g[b * TH + h], red);
    if (h == 0) mul[bf] = s;
}

// per-b fuse; writes PT[h][b]
__global__ __launch_bounds__(128) void k_fuse(const float* __restrict__ mul, const float* __restrict__ local,
                                              const float* __restrict__ g,
                                              const float* __restrict__ liw_g, const float* __restrict__ liw_b,
                                              const float* __restrict__ int_g, const float* __restrict__ int_b,
                                              const float* __restrict__ uni_w, float* __restrict__ PT) {
    __shared__ float lm[TFT], wv_[TFT], inten[TH];
    __shared__ float red[2];
    int b = blockIdx.x, tid = threadIdx.x;
    if (tid < TFT) lm[tid] = mul[b * TFT + tid];
    __syncthreads();
    if (tid < TFT) {
        float mean = 0.f;
        for (int f = 0; f < TFT; ++f) mean += lm[f];
        mean *= (1.f / TFT);
        float var = 0.f;
        for (int f = 0; f < TFT; ++f) { float d = lm[f] - mean; var += d * d; }
        var *= (1.f / TFT);
        float ln = (lm[tid] - mean) * rsqrtf(var + 1e-8f) * liw_g[tid] + liw_b[tid];
        wv_[tid] = (lm[tid] != 0.f) ? ln : -INFINITY;
    }
    __syncthreads();
    if (tid < TFT) {
        float mx = -INFINITY;
        for (int f = 0; f < TFT; ++f) mx = fmaxf(mx, wv_[f]);
        float s = 0.f;
        for (int f = 0; f < TFT; ++f) s += expf(wv_[f] - mx);
        lm[tid] = expf(wv_[tid] - mx) / s;
    }
    __syncthreads();
    float ip = g[b * TH + tid];
    for (int f = 0; f < TFT; ++f) ip += lm[f] * local[(size_t)(b * TFT + f) * TH + tid];
    float mean = block_reduce_sum(ip, red) * (1.f / TH);
    float d = ip - mean;
    float var = block_reduce_sum(d * d, red) * (1.f / TH);
    inten[tid] = d * rsqrtf(var + 1e-8f) * int_g[tid] + int_b[tid];
    __syncthreads();
    float a = 0.f;
    for (int hp = 0; hp < TH; ++hp) a += inten[hp] * uni_w[hp * TH + tid];
    PT[tid * TB + b] = a;
}

// out[b,i] = dot(PT[:,b], E[i,:]); 64-item block, E staged once, full batch swept
__global__ __launch_bounds__(256) void k_final(const float* __restrict__ PT, const float* __restrict__ E,
                                               float* __restrict__ out) {
    __shared__ float es[64][129];
    int i0 = blockIdx.x * 64;
    int tid = threadIdx.x;
    for (int i = tid; i < 64 * 32; i += 256) {
        int ii = i >> 5, h4 = i & 31;
        int it = i0 + ii;
        float4 v;
        if (it < TITEMS) v = ((const float4*)(E + (size_t)it * TH))[h4];
        else { v.x = v.y = v.z = v.w = 0.f; }
        es[ii][h4 * 4 + 0] = v.x;
        es[ii][h4 * 4 + 1] = v.y;
        es[ii][h4 * 4 + 2] = v.z;
        es[ii][h4 * 4 + 3] = v.w;
    }
    __syncthreads();
    int iq = tid & 15, bq = tid >> 4;
#pragma unroll 1
    for (int sweep = 0; sweep < 4; ++sweep) {
        int bb = sweep * 128 + bq * 8;
        float acc[8][4];
#pragma unroll
        for (int j = 0; j < 8; ++j)
#pragma unroll
            for (int t = 0; t < 4; ++t) acc[j][t] = 0.f;
        for (int h = 0; h < TH; ++h) {
            const float4 pA = *(const float4*)(PT + h * TB + bb);
            const float4 pB = *(const float4*)(PT + h * TB + bb + 4);
            float ev[4];
            ev[0] = es[iq][h];
            ev[1] = es[iq + 16][h];
            ev[2] = es[iq + 32][h];
            ev[3] = es[iq + 48][h];
            float pv[8] = {pA.x, pA.y, pA.z, pA.w, pB.x, pB.y, pB.z, pB.w};
#pragma unroll
            for (int j = 0; j < 8; ++j)
#pragma unroll
                for (int t = 0; t < 4; ++t) acc[j][t] += pv[j] * ev[t];
        }
#pragma unroll
        for (int t = 0; t < 4; ++t) {
            int it = i0 + 16 * t + iq;
            if (it < TITEMS) {
#pragma unroll
                for (int j = 0; j < 8; ++j)
                    out[(size_t)(bb + j) * TITEMS + it] = acc[j][t];
            }
        }
    }
}

extern "C" void kernel_launch(void* const* d_in, const int* in_sizes, int n_in,
                              void* d_out, int out_size, void* d_ws, size_t ws_size,
                              hipStream_t stream) {
    const int*   seq        = (const int*)d_in[0];
    const int*   root       = (const int*)d_in[1];
    const int*   i2t_src    = (const int*)d_in[3];
    const int*   t2t_src    = (const int*)d_in[5];
    const int*   item_ids   = (const int*)d_in[6];
    const int*   tax_ids    = (const int*)d_in[7];
    const float* item_embed = (const float*)d_in[8];
    const float* tax_embed  = (const float*)d_in[9];
    const float* scb_ln_g   = (const float*)d_in[10];
    const float* scb_ln_b   = (const float*)d_in[11];
    const float* scb_w1     = (const float*)d_in[12];
    const float* scb_w2     = (const float*)d_in[13];
    const float* fcb_ln_g   = (const float*)d_in[14];
    const float* fcb_ln_b   = (const float*)d_in[15];
    const float* fcb_w1     = (const float*)d_in[16];
    const float* fcb_w2     = (const float*)d_in[17];
    const float* fcb_w3     = (const float*)d_in[18];
    const float* wv         = (const float*)d_in[19];
    const float* gi_w       = (const float*)d_in[20];
    const float* gi_al      = (const float*)d_in[21];
    const float* gi_ar      = (const float*)d_in[22];
    const float* gi_b       = (const float*)d_in[23];
    const float* gt_w       = (const float*)d_in[24];
    const float* gt_al      = (const float*)d_in[25];
    const float* gt_ar      = (const float*)d_in[26];
    const float* gt_b       = (const float*)d_in[27];
    const float* liw_g      = (const float*)d_in[28];
    const float* liw_b      = (const float*)d_in[29];
    const float* int_g      = (const float*)d_in[30];
    const float* int_b      = (const float*)d_in[31];
    const float* uni_w      = (const float*)d_in[32];

    char* w = (char*)d_ws;
    float* V     = (float*)(w + 0);           // region A: V / fs_i
    float* NV    = (float*)(w + 52428800);    // region B: nv / item_h
    float* FSI   = V;
    float* ITEMH = NV;
    __hip_bfloat16* YQ = (__hip_bfloat16*)(w + 104857600); // 52.4MB, aliases TAX0/TAX1 (mixer phase)
    float* ZQ    = (float*)(w + 157286400);   // 13.1MB, aliases FDI tail (mixer phase)
    float* TAX0  = (float*)(w + 104857600);
    float* TAX1  = (float*)(w + 121634816);
    float* ACC   = (float*)(w + 138412032);
    float* FDI   = (float*)(w + 155189248);
    float* FST   = (float*)(w + 171966464);
    float* ELI   = (float*)(w + 188743680);
    float* ERI   = (float*)(w + 190382080);
    float* ELT   = (float*)(w + 190906368);
    float* ERT   = (float*)(w + 191430656);
    float* LOCAL = (float*)(w + 191954944);
    float* G     = (float*)(w + 200343552);
    float* MUL   = (float*)(w + 200605696);
    float* PT    = FDI;                       // [TH][TB] = 256 KB
    if (ws_size < 200933376ull) return;

    // ---- global intention (mixer) ----
    k_gather<<<(TB * TL * 32 + 255) / 256, 256, 0, stream>>>(item_embed, seq, V, TB * TL);
    for (int nb = 0; nb < 2; ++nb) {
        k_ln<<<TB * TL / 8, 256, 0, stream>>>(V, NV, scb_ln_g + nb * TH, scb_ln_b + nb * TH);
        k_scb<<<TB * 8, 256, 0, stream>>>(NV, V, scb_w1 + nb * TL * TSH, scb_w2 + nb * TSH * TL);
        k_ln<<<TB * TL / 8, 256, 0, stream>>>(V, NV, fcb_ln_g + nb * TH, fcb_ln_b + nb * TH);
        for (int q = 0; q < 4; ++q) {
            const float* Aq = NV + (size_t)q * 3276800;
            float* Vq = V + (size_t)q * 3276800;
            k_fcb1<<<1600, 256, 0, stream>>>(Aq, fcb_w1 + nb * TD * TFH, YQ);
            k_fcb2<<<800, 256, 0, stream>>>(YQ, fcb_w2 + nb * TFH * TD, ZQ);
            k_gk128<<<400, 256, 0, stream>>>(ZQ, fcb_w3 + nb * TH * TH, Vq, Aq);
        }
    }
    k_pool<<<TB, 256, 0, stream>>>(V, wv, G);

    // ---- local intention (GAT) ----
    k_gather<<<(TNI * 32 + 255) / 256, 256, 0, stream>>>(item_embed, item_ids, ITEMH, TNI);
    k_gather<<<(TNT * 32 + 255) / 256, 256, 0, stream>>>(tax_embed, tax_ids, TAX0, TNT);

    float* cur = TAX0;
    float* nxt = TAX1;
    for (int hop = 0; hop < 2; ++hop) {
        const float* Wi = gi_w + hop * TH * TH;
        const float* Wt = gt_w + hop * TH * TH;
        k_gk128<<<TNI / 64, 256, 0, stream>>>(ITEMH, Wi, FSI, nullptr);
        k_gk128<<<TNT / 64, 256, 0, stream>>>(cur, Wi, FDI, nullptr);
        k_gk128<<<TNT / 64, 256, 0, stream>>>(cur, Wt, FST, nullptr);
        k_scores<<<(TNI * TNH + 255) / 256, 256, 0, stream>>>(FSI, gi_al + hop * TH, ELI, TNI);
        k_scores<<<(TNT * TNH + 255) / 256, 256, 0, stream>>>(FDI, gi_ar + hop * TH, ERI, TNT);
        k_scores<<<(TNT * TNH + 255) / 256, 256, 0, stream>>>(FST, gt_al + hop * TH, ELT, TNT);
        k_scores<<<(TNT * TNH + 255) / 256, 256, 0, stream>>>(FST, gt_ar + hop * TH, ERT, TNT);
        k_gat<<<TNT, 128, 0, stream>>>(cur, FSI, ELI, ERI, i2t_src, gi_b + hop * TH,
                                       FST, ELT, ERT, t2t_src, gt_b + hop * TH, nxt, ACC, hop);
        float* tmp = cur; cur = nxt; nxt = tmp;
    }

    // ---- fuse ----
    k_local<<<TB * TFT, 128, 0, stream>>>(root, ACC, G, LOCAL, MUL);
    k_fuse<<<TB, 128, 0, stream>>>(MUL, LOCAL, G, liw_g, liw_b, int_g, int_b, uni_w, PT);

    k_final<<<(TITEMS + 63) / 64, 256, 0, stream>>>(PT, item_embed, (float*)d_out);
}

// Round 5
// 2691.972 us; speedup vs baseline: 8.5748x; 8.5748x over previous
//
#include <hip/hip_runtime.h>
#include <hip/hip_bf16.h>

// ---- model dims ----
constexpr int TB = 512, TL = 200, TH = 128, TNH = 4, TD = 32;
constexpr int TFT = 32, TTP = 64, TIP = 200;
constexpr int TSH = 512, TFH = 256;
constexpr int TITEMS = 100001;
constexpr int TNT = TB * TTP;   // 32768
constexpr int TNI = TB * TIP;   // 102400

__device__ inline float gelu_exact(float x) {
    return 0.5f * x * (1.0f + erff(x * 0.7071067811865476f));
}

__device__ inline float block_reduce_sum(float v, float* red) {
    for (int o = 32; o > 0; o >>= 1) v += __shfl_down(v, o, 64);
    int nw = blockDim.x >> 6;
    if ((threadIdx.x & 63) == 0) red[threadIdx.x >> 6] = v;
    __syncthreads();
    float r = 0.f;
    for (int w = 0; w < nw; ++w) r += red[w];
    __syncthreads();
    return r;
}

__device__ inline float block_reduce_max(float v, float* red) {
    for (int o = 32; o > 0; o >>= 1) v = fmaxf(v, __shfl_down(v, o, 64));
    int nw = blockDim.x >> 6;
    if ((threadIdx.x & 63) == 0) red[threadIdx.x >> 6] = v;
    __syncthreads();
    float r = -INFINITY;
    for (int w = 0; w < nw; ++w) r = fmaxf(r, red[w]);
    __syncthreads();
    return r;
}

// out[r,:] = table[idx[r],:]
__global__ __launch_bounds__(256) void k_gather(const float* __restrict__ tab,
                                                const int* __restrict__ idx,
                                                float* __restrict__ out, int nrows) {
    int e = blockIdx.x * blockDim.x + threadIdx.x;
    if (e >= nrows * 32) return;
    int r = e >> 5, c = e & 31;
    ((float4*)out)[e] = ((const float4*)tab)[(size_t)idx[r] * 32 + c];
}

// row-wise LayerNorm over H=128: 8 rows / 256-thread block, float4 lanes
__global__ __launch_bounds__(256) void k_ln(const float* __restrict__ x, float* __restrict__ y,
                                            const float* __restrict__ g, const float* __restrict__ b) {
    int row = blockIdx.x * 8 + (threadIdx.x >> 5);
    int lane = threadIdx.x & 31;
    const float4 v = ((const float4*)(x + (size_t)row * TH))[lane];
    float s = v.x + v.y + v.z + v.w;
    for (int o = 16; o > 0; o >>= 1) s += __shfl_down(s, o, 32);
    float mean = __shfl(s, 0, 32) * (1.f / 128.f);
    float4 d;
    d.x = v.x - mean; d.y = v.y - mean; d.z = v.z - mean; d.w = v.w - mean;
    float q = d.x * d.x + d.y * d.y + d.z * d.z + d.w * d.w;
    for (int o = 16; o > 0; o >>= 1) q += __shfl_down(q, o, 32);
    float inv = rsqrtf(__shfl(q, 0, 32) * (1.f / 128.f) + 1e-8f);
    const float4 gg = ((const float4*)g)[lane];
    const float4 bb = ((const float4*)b)[lane];
    float4 o4;
    o4.x = d.x * inv * gg.x + bb.x;
    o4.y = d.y * inv * gg.y + bb.y;
    o4.z = d.z * inv * gg.z + bb.z;
    o4.w = d.w * inv * gg.w + bb.w;
    ((float4*)(y + (size_t)row * TH))[lane] = o4;
}

// fused seq-mixing block; 16 h-columns per block
__global__ __launch_bounds__(256) void k_scb(const float* __restrict__ nv, float* __restrict__ vs,
                                             const float* __restrict__ w1, const float* __restrict__ w2) {
    __shared__ __align__(16) float nvc[TL][16];
    __shared__ __align__(16) float tt[TSH][20];
    int b = blockIdx.x >> 3;
    int h0 = (blockIdx.x & 7) * 16;
    int tid = threadIdx.x;
    for (int i = tid; i < TL * 4; i += 256) {
        int l = i >> 2, q = i & 3;
        const float4 v = *(const float4*)(nv + (size_t)(b * TL + l) * TH + h0 + q * 4);
        nvc[l][q * 4 + 0] = v.x; nvc[l][q * 4 + 1] = v.y;
        nvc[l][q * 4 + 2] = v.z; nvc[l][q * 4 + 3] = v.w;
    }
    __syncthreads();
    {
        float a0[16], a1[16];
#pragma unroll
        for (int j = 0; j < 16; ++j) { a0[j] = 0.f; a1[j] = 0.f; }
        for (int l = 0; l < TL; ++l) {
            const float4 n0 = *(const float4*)&nvc[l][0];
            const float4 n1 = *(const float4*)&nvc[l][4];
            const float4 n2 = *(const float4*)&nvc[l][8];
            const float4 n3 = *(const float4*)&nvc[l][12];
            float wa = w1[l * TSH + tid];
            float wb = w1[l * TSH + tid + 256];
            a0[0] += n0.x * wa; a0[1] += n0.y * wa; a0[2] += n0.z * wa; a0[3] += n0.w * wa;
            a0[4] += n1.x * wa; a0[5] += n1.y * wa; a0[6] += n1.z * wa; a0[7] += n1.w * wa;
            a0[8] += n2.x * wa; a0[9] += n2.y * wa; a0[10] += n2.z * wa; a0[11] += n2.w * wa;
            a0[12] += n3.x * wa; a0[13] += n3.y * wa; a0[14] += n3.z * wa; a0[15] += n3.w * wa;
            a1[0] += n0.x * wb; a1[1] += n0.y * wb; a1[2] += n0.z * wb; a1[3] += n0.w * wb;
            a1[4] += n1.x * wb; a1[5] += n1.y * wb; a1[6] += n1.z * wb; a1[7] += n1.w * wb;
            a1[8] += n2.x * wb; a1[9] += n2.y * wb; a1[10] += n2.z * wb; a1[11] += n2.w * wb;
            a1[12] += n3.x * wb; a1[13] += n3.y * wb; a1[14] += n3.z * wb; a1[15] += n3.w * wb;
        }
#pragma unroll
        for (int q = 0; q < 4; ++q) {
            float4 u;
            u.x = gelu_exact(a0[q * 4 + 0]); u.y = gelu_exact(a0[q * 4 + 1]);
            u.z = gelu_exact(a0[q * 4 + 2]); u.w = gelu_exact(a0[q * 4 + 3]);
            *(float4*)&tt[tid][q * 4] = u;
            float4 v;
            v.x = gelu_exact(a1[q * 4 + 0]); v.y = gelu_exact(a1[q * 4 + 1]);
            v.z = gelu_exact(a1[q * 4 + 2]); v.w = gelu_exact(a1[q * 4 + 3]);
            *(float4*)&tt[tid + 256][q * 4] = v;
        }
    }
    __syncthreads();
    if (tid < TL) {
        float acc[16];
#pragma unroll
        for (int j = 0; j < 16; ++j) acc[j] = nvc[tid][j];
        for (int s = 0; s < TSH; ++s) {
            const float4 t0 = *(const float4*)&tt[s][0];
            const float4 t1 = *(const float4*)&tt[s][4];
            const float4 t2 = *(const float4*)&tt[s][8];
            const float4 t3 = *(const float4*)&tt[s][12];
            float wl = w2[s * TL + tid];
            acc[0] += t0.x * wl; acc[1] += t0.y * wl; acc[2] += t0.z * wl; acc[3] += t0.w * wl;
            acc[4] += t1.x * wl; acc[5] += t1.y * wl; acc[6] += t1.z * wl; acc[7] += t1.w * wl;
            acc[8] += t2.x * wl; acc[9] += t2.y * wl; acc[10] += t2.z * wl; acc[11] += t2.w * wl;
            acc[12] += t3.x * wl; acc[13] += t3.y * wl; acc[14] += t3.z * wl; acc[15] += t3.w * wl;
        }
        float* vp = &vs[(size_t)(b * TL + tid) * TH + h0];
#pragma unroll
        for (int q = 0; q < 4; ++q) {
            float4 u;
            u.x = acc[q * 4 + 0]; u.y = acc[q * 4 + 1];
            u.z = acc[q * 4 + 2]; u.w = acc[q * 4 + 3];
            *(float4*)(vp + q * 4) = u;
        }
    }
}

// Y[NR,256](f32) = gelu(A[NR,32] @ W[32,256]); NR multiple of 64
__global__ __launch_bounds__(256) void k_fcb1(const float* __restrict__ A, const float* __restrict__ W,
                                              float* __restrict__ Y) {
    __shared__ __align__(16) float At[32][64];
    __shared__ __align__(16) float Ws[32][256];
    int row0 = blockIdx.x * 64;
    int tid = threadIdx.x;
    for (int i = tid; i < 512; i += 256) {
        int r = i >> 3, c4 = i & 7;
        const float4 v = ((const float4*)(A + (size_t)(row0 + r) * 32))[c4];
        At[c4 * 4 + 0][r] = v.x; At[c4 * 4 + 1][r] = v.y;
        At[c4 * 4 + 2][r] = v.z; At[c4 * 4 + 3][r] = v.w;
    }
    for (int i = tid; i < 2048; i += 256) {
        int c = i >> 6, f4 = i & 63;
        ((float4*)&Ws[c][0])[f4] = ((const float4*)(W + c * 256))[f4];
    }
    __syncthreads();
    int rm = (tid >> 4) * 4;
    int fg = (tid & 15) * 4;
    float acc[4][4][4];   // [q][row][col]
#pragma unroll
    for (int q = 0; q < 4; ++q)
#pragma unroll
        for (int j = 0; j < 4; ++j)
#pragma unroll
            for (int i = 0; i < 4; ++i) acc[q][j][i] = 0.f;
    for (int c = 0; c < 32; ++c) {
        const float4 av = *(const float4*)&At[c][rm];
        float a[4] = {av.x, av.y, av.z, av.w};
#pragma unroll
        for (int q = 0; q < 4; ++q) {
            const float4 wv = *(const float4*)&Ws[c][fg + q * 64];
#pragma unroll
            for (int j = 0; j < 4; ++j) {
                acc[q][j][0] += a[j] * wv.x;
                acc[q][j][1] += a[j] * wv.y;
                acc[q][j][2] += a[j] * wv.z;
                acc[q][j][3] += a[j] * wv.w;
            }
        }
    }
#pragma unroll
    for (int q = 0; q < 4; ++q)
#pragma unroll
        for (int j = 0; j < 4; ++j) {
            float4 u;
            u.x = gelu_exact(acc[q][j][0]);
            u.y = gelu_exact(acc[q][j][1]);
            u.z = gelu_exact(acc[q][j][2]);
            u.w = gelu_exact(acc[q][j][3]);
            *(float4*)(Y + (size_t)(row0 + rm + j) * 256 + fg + q * 64) = u;
        }
}

// Z[N,32] = Y[N,256] @ W2[256,32]; N multiple of 128; gk128-pattern
__global__ __launch_bounds__(256) void k_fcb2n(const float* __restrict__ Y,
                                               const float* __restrict__ W2, float* __restrict__ Z) {
    __shared__ __align__(16) float At[32][132];
    __shared__ __align__(16) float Ws[32][32];
    int row0 = blockIdx.x * 128;
    int tid = threadIdx.x;
    int rg = (tid >> 3) * 4;        // 32 row-groups of 4 rows
    int cg = (tid & 7) * 4;         // 8 col-groups of 4 cols
    float acc[4][4];
#pragma unroll
    for (int j = 0; j < 4; ++j)
#pragma unroll
        for (int i = 0; i < 4; ++i) acc[j][i] = 0.f;
    for (int kc = 0; kc < 8; ++kc) {
        __syncthreads();
        for (int i = tid; i < 1024; i += 256) {
            int r = i >> 3, c4 = i & 7;
            const float4 v = *(const float4*)(Y + (size_t)(row0 + r) * 256 + kc * 32 + c4 * 4);
            At[c4 * 4 + 0][r] = v.x; At[c4 * 4 + 1][r] = v.y;
            At[c4 * 4 + 2][r] = v.z; At[c4 * 4 + 3][r] = v.w;
        }
        {
            int k = tid >> 3, c4 = tid & 7;
            ((float4*)&Ws[k][0])[c4] = ((const float4*)(W2 + (kc * 32 + k) * 32))[c4];
        }
        __syncthreads();
        for (int k = 0; k < 32; ++k) {
            const float4 av = *(const float4*)&At[k][rg];
            const float4 wv = *(const float4*)&Ws[k][cg];
            float a[4] = {av.x, av.y, av.z, av.w};
#pragma unroll
            for (int j = 0; j < 4; ++j) {
                acc[j][0] += a[j] * wv.x;
                acc[j][1] += a[j] * wv.y;
                acc[j][2] += a[j] * wv.z;
                acc[j][3] += a[j] * wv.w;
            }
        }
    }
#pragma unroll
    for (int j = 0; j < 4; ++j) {
        float4 u;
        u.x = acc[j][0]; u.y = acc[j][1]; u.z = acc[j][2]; u.w = acc[j][3];
        *(float4*)(Z + (size_t)(row0 + rg + j) * 32 + cg) = u;
    }
}

// C[N,128] = A[N,128] @ W[128,128] (+R); N multiple of 64
__global__ __launch_bounds__(256) void k_gk128(const float* __restrict__ A, const float* __restrict__ W,
                                               float* __restrict__ C, const float* __restrict__ R) {
    __shared__ __align__(16) float Ws[32][128];
    __shared__ __align__(16) float At[32][68];
    int row0 = blockIdx.x * 64;
    int tid = threadIdx.x;
    int rm = (tid >> 4) * 4;
    int fg = (tid & 15) * 4;
    float acc[2][4][4];   // [q][row][col]
#pragma unroll
    for (int q = 0; q < 2; ++q)
#pragma unroll
        for (int j = 0; j < 4; ++j)
#pragma unroll
            for (int i = 0; i < 4; ++i) acc[q][j][i] = 0.f;
    for (int kc = 0; kc < 4; ++kc) {
        __syncthreads();
        for (int i = tid; i < 512; i += 256) {
            int r = i >> 3, c4 = i & 7;
            const float4 v = *(const float4*)(A + (size_t)(row0 + r) * 128 + kc * 32 + c4 * 4);
            At[c4 * 4 + 0][r] = v.x; At[c4 * 4 + 1][r] = v.y;
            At[c4 * 4 + 2][r] = v.z; At[c4 * 4 + 3][r] = v.w;
        }
        for (int i = tid; i < 1024; i += 256) {
            int k = i >> 5, f4 = i & 31;
            ((float4*)&Ws[k][0])[f4] = ((const float4*)(W + (kc * 32 + k) * 128))[f4];
        }
        __syncthreads();
        for (int k = 0; k < 32; ++k) {
            const float4 av = *(const float4*)&At[k][rm];
            float a[4] = {av.x, av.y, av.z, av.w};
#pragma unroll
            for (int q = 0; q < 2; ++q) {
                const float4 wv = *(const float4*)&Ws[k][fg + q * 64];
#pragma unroll
                for (int j = 0; j < 4; ++j) {
                    acc[q][j][0] += a[j] * wv.x;
                    acc[q][j][1] += a[j] * wv.y;
                    acc[q][j][2] += a[j] * wv.z;
                    acc[q][j][3] += a[j] * wv.w;
                }
            }
        }
    }
#pragma unroll
    for (int q = 0; q < 2; ++q)
#pragma unroll
        for (int j = 0; j < 4; ++j) {
            size_t off = (size_t)(row0 + rm + j) * 128 + fg + q * 64;
            float4 u;
            u.x = acc[q][j][0]; u.y = acc[q][j][1]; u.z = acc[q][j][2]; u.w = acc[q][j][3];
            if (R) {
                const float4 rv = *(const float4*)(R + off);
                u.x += rv.x; u.y += rv.y; u.z += rv.z; u.w += rv.w;
            }
            *(float4*)(C + off) = u;
        }
}

// alpha = softmax(V@wv over L); g = sum_l alpha*V
__global__ __launch_bounds__(256) void k_pool(const float* __restrict__ V, const float* __restrict__ wv,
                                              float* __restrict__ g) {
    __shared__ float sc[TL];
    __shared__ float red[4];
    int b = blockIdx.x, tid = threadIdx.x;
    if (tid < TL) {
        float a = 0.f;
        const float* vp = V + (size_t)(b * TL + tid) * TH;
        for (int h = 0; h < TH; ++h) a += vp[h] * wv[h];
        sc[tid] = a;
    }
    __syncthreads();
    float m = (tid < TL) ? sc[tid] : -INFINITY;
    m = block_reduce_max(m, red);
    float e = (tid < TL) ? expf(sc[tid] - m) : 0.f;
    float s = block_reduce_sum(e, red);
    if (tid < TL) sc[tid] = e / s;
    __syncthreads();
    if (tid < TH) {
        float a = 0.f;
        for (int l = 0; l < TL; ++l) a += sc[l] * V[(size_t)(b * TL + l) * TH + tid];
        g[b * TH + tid] = a;
    }
}

// out[n,k] = sum_d f[n, k*32+d] * vec[k*32+d]
__global__ __launch_bounds__(256) void k_scores(const float* __restrict__ f, const float* __restrict__ vec,
                                                float* __restrict__ out, int n) {
    int idx = blockIdx.x * blockDim.x + threadIdx.x;
    if (idx >= n * TNH) return;
    int node = idx >> 2, k = idx & 3;
    const float* fp = f + (size_t)node * TH + k * TD;
    const float* vp = vec + k * TD;
    float a = 0.f;
#pragma unroll
    for (int d = 0; d < TD; ++d) a += fp[d] * vp[d];
    out[idx] = a;
}

// fused per-dst-node GAT for both graphs
__global__ __launch_bounds__(128) void k_gat(const float* __restrict__ tax_cur,
                                             const float* __restrict__ fs_i, const float* __restrict__ el_i,
                                             const float* __restrict__ er_i, const int* __restrict__ src_i,
                                             const float* __restrict__ bi,
                                             const float* __restrict__ fs_t, const float* __restrict__ el_t,
                                             const float* __restrict__ er_t, const int* __restrict__ src_t,
                                             const float* __restrict__ bt,
                                             float* __restrict__ tax_nxt, float* __restrict__ acc, int hop) {
    int n = blockIdx.x, h = threadIdx.x, k = h >> 5;
    float cur = tax_cur[(size_t)n * TH + h];
    float ti, tt2;
    {
        float er = er_i[n * 4 + k];
        int s[4]; float e[4]; float m = -INFINITY;
#pragma unroll
        for (int j = 0; j < 4; ++j) {
            s[j] = src_i[n * 4 + j];
            float xx = el_i[s[j] * 4 + k] + er;
            e[j] = xx > 0.f ? xx : 0.2f * xx;
            m = fmaxf(m, e[j]);
        }
        float ssum = 0.f, av = 0.f;
#pragma unroll
        for (int j = 0; j < 4; ++j) {
            float a = expf(e[j] - m);
            ssum += a;
            av += a * fs_i[(size_t)s[j] * TH + h];
        }
        ti = fmaxf(av / ssum + cur + bi[h], 0.f);
    }
    {
        float er = er_t[n * 4 + k];
        int s[2]; float e[2]; float m = -INFINITY;
#pragma unroll
        for (int j = 0; j < 2; ++j) {
            s[j] = src_t[n * 2 + j];
            float xx = el_t[s[j] * 4 + k] + er;
            e[j] = xx > 0.f ? xx : 0.2f * xx;
            m = fmaxf(m, e[j]);
        }
        float ssum = 0.f, av = 0.f;
#pragma unroll
        for (int j = 0; j < 2; ++j) {
            float a = expf(e[j] - m);
            ssum += a;
            av += a * fs_t[(size_t)s[j] * TH + h];
        }
        tt2 = fmaxf(av / ssum + cur + bt[h], 0.f);
    }
    float nx = ti + tt2;
    size_t ai = (size_t)n * TH + h;
    tax_nxt[ai] = nx;
    acc[ai] = (hop == 0) ? nx : acc[ai] + nx;
}

// local + mul
__global__ __launch_bounds__(128) void k_local(const int* __restrict__ root, const float* __restrict__ acc,
                                               const float* __restrict__ g, float* __restrict__ local,
                                               float* __restrict__ mul) {
    __shared__ float red[2];
    int bf = blockIdx.x, b = bf >> 5;
    int h = threadIdx.x;
    int r = root[bf];
    float v = 0.f;
    if (r != -1) {
        int rc = r < 0 ? 0 : r;
        v = acc[(size_t)(b * TTP + rc) * TH + h] * 0.5f;
    }
    local[(size_t)bf * TH + h] = v;
    float s = block_reduce_sum(v * g[b * TH + h], red);
    if (h == 0) mul[bf] = s;
}

// per-b fuse; writes PT[h][b]
__global__ __launch_bounds__(128) void k_fuse(const float* __restrict__ mul, const float* __restrict__ local,
                                              const float* __restrict__ g,
                                              const float* __restrict__ liw_g, const float* __restrict__ liw_b,
                                              const float* __restrict__ int_g, const float* __restrict__ int_b,
                                              const float* __restrict__ uni_w, float* __restrict__ PT) {
    __shared__ float lm[TFT], wv_[TFT], inten[TH];
    __shared__ float red[2];
    int b = blockIdx.x, tid = threadIdx.x;
    if (tid < TFT) lm[tid] = mul[b * TFT + tid];
    __syncthreads();
    if (tid < TFT) {
        float mean = 0.f;
        for (int f = 0; f < TFT; ++f) mean += lm[f];
        mean *= (1.f / TFT);
        float var = 0.f;
        for (int f = 0; f < TFT; ++f) { float d = lm[f] - mean; var += d * d; }
        var *= (1.f / TFT);
        float ln = (lm[tid] - mean) * rsqrtf(var + 1e-8f) * liw_g[tid] + liw_b[tid];
        wv_[tid] = (lm[tid] != 0.f) ? ln : -INFINITY;
    }
    __syncthreads();
    if (tid < TFT) {
        float mx = -INFINITY;
        for (int f = 0; f < TFT; ++f) mx = fmaxf(mx, wv_[f]);
        float s = 0.f;
        for (int f = 0; f < TFT; ++f) s += expf(wv_[f] - mx);
        lm[tid] = expf(wv_[tid] - mx) / s;
    }
    __syncthreads();
    float ip = g[b * TH + tid];
    for (int f = 0; f < TFT; ++f) ip += lm[f] * local[(size_t)(b * TFT + f) * TH + tid];
    float mean = block_reduce_sum(ip, red) * (1.f / TH);
    float d = ip - mean;
    float var = block_reduce_sum(d * d, red) * (1.f / TH);
    inten[tid] = d * rsqrtf(var + 1e-8f) * int_g[tid] + int_b[tid];
    __syncthreads();
    float a = 0.f;
    for (int hp = 0; hp < TH; ++hp) a += inten[hp] * uni_w[hp * TH + tid];
    PT[tid * TB + b] = a;
}

// out[b,i] = dot(PT[:,b], E[i,:]); 64-item block, E staged once, full batch swept
__global__ __launch_bounds__(256) void k_final(const float* __restrict__ PT, const float* __restrict__ E,
                                               float* __restrict__ out) {
    __shared__ float es[64][129];
    int i0 = blockIdx.x * 64;
    int tid = threadIdx.x;
    for (int i = tid; i < 64 * 32; i += 256) {
        int ii = i >> 5, h4 = i & 31;
        int it = i0 + ii;
        float4 v;
        if (it < TITEMS) v = ((const float4*)(E + (size_t)it * TH))[h4];
        else { v.x = v.y = v.z = v.w = 0.f; }
        es[ii][h4 * 4 + 0] = v.x;
        es[ii][h4 * 4 + 1] = v.y;
        es[ii][h4 * 4 + 2] = v.z;
        es[ii][h4 * 4 + 3] = v.w;
    }
    __syncthreads();
    int iq = tid & 15, bq = tid >> 4;
#pragma unroll 1
    for (int sweep = 0; sweep < 4; ++sweep) {
        int bb = sweep * 128 + bq * 8;
        float acc[8][4];
#pragma unroll
        for (int j = 0; j < 8; ++j)
#pragma unroll
            for (int t = 0; t < 4; ++t) acc[j][t] = 0.f;
        for (int h = 0; h < TH; ++h) {
            const float4 pA = *(const float4*)(PT + h * TB + bb);
            const float4 pB = *(const float4*)(PT + h * TB + bb + 4);
            float ev[4];
            ev[0] = es[iq][h];
            ev[1] = es[iq + 16][h];
            ev[2] = es[iq + 32][h];
            ev[3] = es[iq + 48][h];
            float pv[8] = {pA.x, pA.y, pA.z, pA.w, pB.x, pB.y, pB.z, pB.w};
#pragma unroll
            for (int j = 0; j < 8; ++j)
#pragma unroll
                for (int t = 0; t < 4; ++t) acc[j][t] += pv[j] * ev[t];
        }
#pragma unroll
        for (int t = 0; t < 4; ++t) {
            int it = i0 + 16 * t + iq;
            if (it < TITEMS) {
#pragma unroll
                for (int j = 0; j < 8; ++j)
                    out[(size_t)(bb + j) * TITEMS + it] = acc[j][t];
            }
        }
    }
}

extern "C" void kernel_launch(void* const* d_in, const int* in_sizes, int n_in,
                              void* d_out, int out_size, void* d_ws, size_t ws_size,
                              hipStream_t stream) {
    const int*   seq        = (const int*)d_in[0];
    const int*   root       = (const int*)d_in[1];
    const int*   i2t_src    = (const int*)d_in[3];
    const int*   t2t_src    = (const int*)d_in[5];
    const int*   item_ids   = (const int*)d_in[6];
    const int*   tax_ids    = (const int*)d_in[7];
    const float* item_embed = (const float*)d_in[8];
    const float* tax_embed  = (const float*)d_in[9];
    const float* scb_ln_g   = (const float*)d_in[10];
    const float* scb_ln_b   = (const float*)d_in[11];
    const float* scb_w1     = (const float*)d_in[12];
    const float* scb_w2     = (const float*)d_in[13];
    const float* fcb_ln_g   = (const float*)d_in[14];
    const float* fcb_ln_b   = (const float*)d_in[15];
    const float* fcb_w1     = (const float*)d_in[16];
    const float* fcb_w2     = (const float*)d_in[17];
    const float* fcb_w3     = (const float*)d_in[18];
    const float* wv         = (const float*)d_in[19];
    const float* gi_w       = (const float*)d_in[20];
    const float* gi_al      = (const float*)d_in[21];
    const float* gi_ar      = (const float*)d_in[22];
    const float* gi_b       = (const float*)d_in[23];
    const float* gt_w       = (const float*)d_in[24];
    const float* gt_al      = (const float*)d_in[25];
    const float* gt_ar      = (const float*)d_in[26];
    const float* gt_b       = (const float*)d_in[27];
    const float* liw_g      = (const float*)d_in[28];
    const float* liw_b      = (const float*)d_in[29];
    const float* int_g      = (const float*)d_in[30];
    const float* int_b      = (const float*)d_in[31];
    const float* uni_w      = (const float*)d_in[32];

    char* w = (char*)d_ws;
    float* V     = (float*)(w + 0);           // region A: V / fs_i
    float* NV    = (float*)(w + 52428800);    // region B: nv / item_h
    float* FSI   = V;
    float* ITEMH = NV;
    float* YQf   = (float*)(w + 104857600);   // 52.4MB (mixer phase; aliases TAX0/TAX1/ACC/+2MB of FDI)
    float* ZQ    = (float*)(w + 157286400);   // 6.6MB (mixer phase; inside FDI region)
    float* TAX0  = (float*)(w + 104857600);
    float* TAX1  = (float*)(w + 121634816);
    float* ACC   = (float*)(w + 138412032);
    float* FDI   = (float*)(w + 155189248);
    float* FST   = (float*)(w + 171966464);
    float* ELI   = (float*)(w + 188743680);
    float* ERI   = (float*)(w + 190382080);
    float* ELT   = (float*)(w + 190906368);
    float* ERT   = (float*)(w + 191430656);
    float* LOCAL = (float*)(w + 191954944);
    float* G     = (float*)(w + 200343552);
    float* MUL   = (float*)(w + 200605696);
    float* PT    = FDI;                       // [TH][TB] = 256 KB
    if (ws_size < 200933376ull) return;

    // ---- global intention (mixer) ----
    k_gather<<<(TB * TL * 32 + 255) / 256, 256, 0, stream>>>(item_embed, seq, V, TB * TL);
    for (int nb = 0; nb < 2; ++nb) {
        k_ln<<<TB * TL / 8, 256, 0, stream>>>(V, NV, scb_ln_g + nb * TH, scb_ln_b + nb * TH);
        k_scb<<<TB * 8, 256, 0, stream>>>(NV, V, scb_w1 + nb * TL * TSH, scb_w2 + nb * TSH * TL);
        k_ln<<<TB * TL / 8, 256, 0, stream>>>(V, NV, fcb_ln_g + nb * TH, fcb_ln_b + nb * TH);
        for (int q = 0; q < 8; ++q) {
            const float* Aq = NV + (size_t)q * 1638400;   // 12800 (b,l)-rows
            float* Vq = V + (size_t)q * 1638400;
            k_fcb1<<<800, 256, 0, stream>>>(Aq, fcb_w1 + nb * TD * TFH, YQf);
            k_fcb2n<<<400, 256, 0, stream>>>(YQf, fcb_w2 + nb * TFH * TD, ZQ);
            k_gk128<<<200, 256, 0, stream>>>(ZQ, fcb_w3 + nb * TH * TH, Vq, Aq);
        }
    }
    k_pool<<<TB, 256, 0, stream>>>(V, wv, G);

    // ---- local intention (GAT) ----
    k_gather<<<(TNI * 32 + 255) / 256, 256, 0, stream>>>(item_embed, item_ids, ITEMH, TNI);
    k_gather<<<(TNT * 32 + 255) / 256, 256, 0, stream>>>(tax_embed, tax_ids, TAX0, TNT);

    float* cur = TAX0;
    float* nxt = TAX1;
    for (int hop = 0; hop < 2; ++hop) {
        const float* Wi = gi_w + hop * TH * TH;
        const float* Wt = gt_w + hop * TH * TH;
        k_gk128<<<TNI / 64, 256, 0, stream>>>(ITEMH, Wi, FSI, nullptr);
        k_gk128<<<TNT / 64, 256, 0, stream>>>(cur, Wi, FDI, nullptr);
        k_gk128<<<TNT / 64, 256, 0, stream>>>(cur, Wt, FST, nullptr);
        k_scores<<<(TNI * TNH + 255) / 256, 256, 0, stream>>>(FSI, gi_al + hop * TH, ELI, TNI);
        k_scores<<<(TNT * TNH + 255) / 256, 256, 0, stream>>>(FDI, gi_ar + hop * TH, ERI, TNT);
        k_scores<<<(TNT * TNH + 255) / 256, 256, 0, stream>>>(FST, gt_al + hop * TH, ELT, TNT);
        k_scores<<<(TNT * TNH + 255) / 256, 256, 0, stream>>>(FST, gt_ar + hop * TH, ERT, TNT);
        k_gat<<<TNT, 128, 0, stream>>>(cur, FSI, ELI, ERI, i2t_src, gi_b + hop * TH,
                                       FST, ELT, ERT, t2t_src, gt_b + hop * TH, nxt, ACC, hop);
        float* tmp = cur; cur = nxt; nxt = tmp;
    }

    // ---- fuse ----
    k_local<<<TB * TFT, 128, 0, stream>>>(root, ACC, G, LOCAL, MUL);
    k_fuse<<<TB, 128, 0, stream>>>(MUL, LOCAL, G, liw_g, liw_b, int_g, int_b, uni_w, PT);

    k_final<<<(TITEMS + 63) / 64, 256, 0, stream>>>(PT, item_embed, (float*)d_out);
}

// Round 6
// 2213.311 us; speedup vs baseline: 10.4292x; 1.2163x over previous
//
#include <hip/hip_runtime.h>
#include <hip/hip_bf16.h>

// ---- model dims ----
constexpr int TB = 512, TL = 200, TH = 128, TNH = 4, TD = 32;
constexpr int TFT = 32, TTP = 64, TIP = 200;
constexpr int TSH = 512, TFH = 256;
constexpr int TITEMS = 100001;
constexpr int TNT = TB * TTP;   // 32768
constexpr int TNI = TB * TIP;   // 102400
constexpr int TLP = 224;        // L padded to mult of 32 (K of GEMM1)

typedef __attribute__((ext_vector_type(8))) short short8v;
typedef __attribute__((ext_vector_type(4))) float f32x4;

__device__ inline float gelu_exact(float x) {
    return 0.5f * x * (1.0f + erff(x * 0.7071067811865476f));
}
__device__ inline unsigned short to_bf16u(float x) {
    __hip_bfloat16 h = __float2bfloat16(x);
    return *reinterpret_cast<unsigned short*>(&h);
}

__device__ inline float block_reduce_sum(float v, float* red) {
    for (int o = 32; o > 0; o >>= 1) v += __shfl_down(v, o, 64);
    int nw = blockDim.x >> 6;
    if ((threadIdx.x & 63) == 0) red[threadIdx.x >> 6] = v;
    __syncthreads();
    float r = 0.f;
    for (int w = 0; w < nw; ++w) r += red[w];
    __syncthreads();
    return r;
}

__device__ inline float block_reduce_max(float v, float* red) {
    for (int o = 32; o > 0; o >>= 1) v = fmaxf(v, __shfl_down(v, o, 64));
    int nw = blockDim.x >> 6;
    if ((threadIdx.x & 63) == 0) red[threadIdx.x >> 6] = v;
    __syncthreads();
    float r = -INFINITY;
    for (int w = 0; w < nw; ++w) r = fmaxf(r, red[w]);
    __syncthreads();
    return r;
}

// out[r,:] = table[idx[r],:]
__global__ __launch_bounds__(256) void k_gather(const float* __restrict__ tab,
                                                const int* __restrict__ idx,
                                                float* __restrict__ out, int nrows) {
    int e = blockIdx.x * blockDim.x + threadIdx.x;
    if (e >= nrows * 32) return;
    int r = e >> 5, c = e & 31;
    ((float4*)out)[e] = ((const float4*)tab)[(size_t)idx[r] * 32 + c];
}

// row-wise LayerNorm over H=128: 8 rows / 256-thread block, float4 lanes
__global__ __launch_bounds__(256) void k_ln(const float* __restrict__ x, float* __restrict__ y,
                                            const float* __restrict__ g, const float* __restrict__ b) {
    int row = blockIdx.x * 8 + (threadIdx.x >> 5);
    int lane = threadIdx.x & 31;
    const float4 v = ((const float4*)(x + (size_t)row * TH))[lane];
    float s = v.x + v.y + v.z + v.w;
    for (int o = 16; o > 0; o >>= 1) s += __shfl_down(s, o, 32);
    float mean = __shfl(s, 0, 32) * (1.f / 128.f);
    float4 d;
    d.x = v.x - mean; d.y = v.y - mean; d.z = v.z - mean; d.w = v.w - mean;
    float q = d.x * d.x + d.y * d.y + d.z * d.z + d.w * d.w;
    for (int o = 16; o > 0; o >>= 1) q += __shfl_down(q, o, 32);
    float inv = rsqrtf(__shfl(q, 0, 32) * (1.f / 128.f) + 1e-8f);
    const float4 gg = ((const float4*)g)[lane];
    const float4 bb = ((const float4*)b)[lane];
    float4 o4;
    o4.x = d.x * inv * gg.x + bb.x;
    o4.y = d.y * inv * gg.y + bb.y;
    o4.z = d.z * inv * gg.z + bb.z;
    o4.w = d.w * inv * gg.w + bb.w;
    ((float4*)(y + (size_t)row * TH))[lane] = o4;
}

// NV[b][l][h] f32 -> NVT[b][h][lp] bf16 (l zero-padded to 224)
__global__ __launch_bounds__(128) void k_nvt(const float* __restrict__ NV,
                                             unsigned short* __restrict__ NVT) {
    __shared__ float tl[64][129];
    int b = blockIdx.y, l0 = blockIdx.x * 64, tid = threadIdx.x;
    for (int i = tid; i < 2048; i += 128) {
        int r = i >> 5, c = i & 31;
        int l = l0 + r;
        float4 v = {0.f, 0.f, 0.f, 0.f};
        if (l < TL) v = *(const float4*)(NV + ((size_t)b * TL + l) * TH + c * 4);
        tl[r][c * 4 + 0] = v.x; tl[r][c * 4 + 1] = v.y;
        tl[r][c * 4 + 2] = v.z; tl[r][c * 4 + 3] = v.w;
    }
    __syncthreads();
    int h = tid;
    int ng = (l0 + 64 > TLP) ? (TLP - l0) / 8 : 8;
    for (int lg = 0; lg < ng; ++lg) {
        uint4 u;
        unsigned int p[4];
#pragma unroll
        for (int q = 0; q < 4; ++q) {
            unsigned short ua = to_bf16u(tl[lg * 8 + q * 2 + 0][h]);
            unsigned short ub = to_bf16u(tl[lg * 8 + q * 2 + 1][h]);
            p[q] = (unsigned int)ua | ((unsigned int)ub << 16);
        }
        u.x = p[0]; u.y = p[1]; u.z = p[2]; u.w = p[3];
        *(uint4*)(NVT + ((size_t)b * TH + h) * TLP + l0 + lg * 8) = u;
    }
}

// w1[l][s] f32 -> W1T[s][lp] bf16  (grid 512 blocks = s, block 256 = l)
__global__ __launch_bounds__(256) void k_w1t(const float* __restrict__ w1,
                                             unsigned short* __restrict__ W1T) {
    int s = blockIdx.x, l = threadIdx.x;
    if (l >= TLP) return;
    float v = (l < TL) ? w1[(size_t)l * TSH + s] : 0.f;
    W1T[(size_t)s * TLP + l] = to_bf16u(v);
}

// w2[s][l] f32 -> W2T[lp208][s] bf16 (grid 208 blocks = l, block 256, 2 iters over s)
__global__ __launch_bounds__(256) void k_w2t(const float* __restrict__ w2,
                                             unsigned short* __restrict__ W2T) {
    int l = blockIdx.x;
    for (int it = 0; it < 2; ++it) {
        int s = it * 256 + threadIdx.x;
        float v = (l < TL) ? w2[(size_t)s * TL + l] : 0.f;
        W2T[(size_t)l * TSH + s] = to_bf16u(v);
    }
}

// GEMM1: T[b][h][s] = gelu( sum_l NVT[b][h][l] * w1[l][s] ), bf16 out.
// A=NVT rows [m=h][k=l]; B staged as Bt[n=s][k=l]=W1T rows. block: 128h x 128s, 4 waves.
__global__ __launch_bounds__(256) void k_mm1(const unsigned short* __restrict__ NVT,
                                             const unsigned short* __restrict__ W1T,
                                             unsigned short* __restrict__ T, int bh) {
    __shared__ unsigned short As[128][40];
    __shared__ unsigned short Bs[128][40];
    int tid = threadIdx.x;
    int b_local = blockIdx.y, b = bh * 256 + b_local;
    int s0 = blockIdx.x * 128;
    int lane = tid & 63, wid = tid >> 6;
    int mw = wid >> 1, nw = wid & 1;   // wave tile: 4 m-tiles x 4 n-tiles (64x64)
    f32x4 acc[4][4];
#pragma unroll
    for (int i = 0; i < 4; ++i)
#pragma unroll
        for (int j = 0; j < 4; ++j) acc[i][j] = (f32x4){0.f, 0.f, 0.f, 0.f};
    const unsigned short* Abase = NVT + (size_t)b * TH * TLP;
    const unsigned short* Bbase = W1T + (size_t)s0 * TLP;
    for (int kc = 0; kc < 7; ++kc) {
        __syncthreads();
        for (int i = tid; i < 512; i += 256) {
            int r = i >> 2, q = i & 3;
            *(uint4*)&As[r][q * 8] = *(const uint4*)(Abase + (size_t)r * TLP + kc * 32 + q * 8);
            *(uint4*)&Bs[r][q * 8] = *(const uint4*)(Bbase + (size_t)r * TLP + kc * 32 + q * 8);
        }
        __syncthreads();
        int ko = (lane >> 4) * 8;
        short8v af[4], bfr[4];
#pragma unroll
        for (int t = 0; t < 4; ++t) {
            af[t] = *(const short8v*)&As[mw * 64 + t * 16 + (lane & 15)][ko];
            bfr[t] = *(const short8v*)&Bs[nw * 64 + t * 16 + (lane & 15)][ko];
        }
#pragma unroll
        for (int i = 0; i < 4; ++i)
#pragma unroll
            for (int j = 0; j < 4; ++j)
                acc[i][j] = __builtin_amdgcn_mfma_f32_16x16x32_bf16(af[i], bfr[j], acc[i][j], 0, 0, 0);
    }
    int rbase = (lane >> 4) * 4, col = lane & 15;
#pragma unroll
    for (int i = 0; i < 4; ++i)
#pragma unroll
        for (int j = 0; j < 4; ++j) {
            int h0 = mw * 64 + i * 16 + rbase;
            int s = s0 + nw * 64 + j * 16 + col;
#pragma unroll
            for (int r = 0; r < 4; ++r)
                T[((size_t)b_local * TH + h0 + r) * TSH + s] = to_bf16u(gelu_exact(acc[i][j][r]));
        }
}

// GEMM2: VS[b][l][h] = NV[b][l][h] + sum_s T[b][h][s] * w2[s][l]
// C[m=h][n=l]; A=T rows; B staged Bt[n=l][k=s]=W2T rows. block: 128h x 64l, 4 waves.
__global__ __launch_bounds__(256) void k_mm2(const unsigned short* __restrict__ T,
                                             const unsigned short* __restrict__ W2T,
                                             const float* __restrict__ NV,
                                             float* __restrict__ VS, int bh) {
    __shared__ unsigned short As[128][40];
    __shared__ unsigned short Bs[64][40];
    int tid = threadIdx.x;
    int b_local = blockIdx.y, b = bh * 256 + b_local;
    int l0 = blockIdx.x * 64;
    int lane = tid & 63, wid = tid >> 6;   // wave tile: 2 m-tiles x 4 n-tiles
    f32x4 acc[2][4];
#pragma unroll
    for (int i = 0; i < 2; ++i)
#pragma unroll
        for (int j = 0; j < 4; ++j) acc[i][j] = (f32x4){0.f, 0.f, 0.f, 0.f};
    const unsigned short* Abase = T + (size_t)b_local * TH * TSH;
    for (int kc = 0; kc < 16; ++kc) {
        __syncthreads();
        for (int i = tid; i < 512; i += 256) {
            int r = i >> 2, q = i & 3;
            *(uint4*)&As[r][q * 8] = *(const uint4*)(Abase + (size_t)r * TSH + kc * 32 + q * 8);
        }
        {
            int r = tid >> 2, q = tid & 3;
            int l = l0 + r;
            uint4 v = {0u, 0u, 0u, 0u};
            if (l < 208) v = *(const uint4*)(W2T + (size_t)l * TSH + kc * 32 + q * 8);
            *(uint4*)&Bs[r][q * 8] = v;
        }
        __syncthreads();
        int ko = (lane >> 4) * 8;
        short8v af[2], bfr[4];
#pragma unroll
        for (int t = 0; t < 2; ++t)
            af[t] = *(const short8v*)&As[wid * 32 + t * 16 + (lane & 15)][ko];
#pragma unroll
        for (int j = 0; j < 4; ++j)
            bfr[j] = *(const short8v*)&Bs[j * 16 + (lane & 15)][ko];
#pragma unroll
        for (int i = 0; i < 2; ++i)
#pragma unroll
            for (int j = 0; j < 4; ++j)
                acc[i][j] = __builtin_amdgcn_mfma_f32_16x16x32_bf16(af[i], bfr[j], acc[i][j], 0, 0, 0);
    }
    int rbase = (lane >> 4) * 4, col = lane & 15;
#pragma unroll
    for (int i = 0; i < 2; ++i)
#pragma unroll
        for (int j = 0; j < 4; ++j) {
            int l = l0 + j * 16 + col;
            if (l < TL) {
                int h0 = wid * 32 + i * 16 + rbase;
                size_t off = ((size_t)b * TL + l) * TH + h0;
                const float4 res = *(const float4*)(NV + off);
                float4 o;
                o.x = acc[i][j][0] + res.x;
                o.y = acc[i][j][1] + res.y;
                o.z = acc[i][j][2] + res.z;
                o.w = acc[i][j][3] + res.w;
                *(float4*)(VS + off) = o;
            }
        }
}

// Y[NR,256](f32) = gelu(A[NR,32] @ W[32,256]); NR multiple of 64
__global__ __launch_bounds__(256) void k_fcb1(const float* __restrict__ A, const float* __restrict__ W,
                                              float* __restrict__ Y) {
    __shared__ __align__(16) float At[32][64];
    __shared__ __align__(16) float Ws[32][256];
    int row0 = blockIdx.x * 64;
    int tid = threadIdx.x;
    for (int i = tid; i < 512; i += 256) {
        int r = i >> 3, c4 = i & 7;
        const float4 v = ((const float4*)(A + (size_t)(row0 + r) * 32))[c4];
        At[c4 * 4 + 0][r] = v.x; At[c4 * 4 + 1][r] = v.y;
        At[c4 * 4 + 2][r] = v.z; At[c4 * 4 + 3][r] = v.w;
    }
    for (int i = tid; i < 2048; i += 256) {
        int c = i >> 6, f4 = i & 63;
        ((float4*)&Ws[c][0])[f4] = ((const float4*)(W + c * 256))[f4];
    }
    __syncthreads();
    int rm = (tid >> 4) * 4;
    int fg = (tid & 15) * 4;
    float acc[4][4][4];
#pragma unroll
    for (int q = 0; q < 4; ++q)
#pragma unroll
        for (int j = 0; j < 4; ++j)
#pragma unroll
            for (int i = 0; i < 4; ++i) acc[q][j][i] = 0.f;
    for (int c = 0; c < 32; ++c) {
        const float4 av = *(const float4*)&At[c][rm];
        float a[4] = {av.x, av.y, av.z, av.w};
#pragma unroll
        for (int q = 0; q < 4; ++q) {
            const float4 wv = *(const float4*)&Ws[c][fg + q * 64];
#pragma unroll
            for (int j = 0; j < 4; ++j) {
                acc[q][j][0] += a[j] * wv.x;
                acc[q][j][1] += a[j] * wv.y;
                acc[q][j][2] += a[j] * wv.z;
                acc[q][j][3] += a[j] * wv.w;
            }
        }
    }
#pragma unroll
    for (int q = 0; q < 4; ++q)
#pragma unroll
        for (int j = 0; j < 4; ++j) {
            float4 u;
            u.x = gelu_exact(acc[q][j][0]);
            u.y = gelu_exact(acc[q][j][1]);
            u.z = gelu_exact(acc[q][j][2]);
            u.w = gelu_exact(acc[q][j][3]);
            *(float4*)(Y + (size_t)(row0 + rm + j) * 256 + fg + q * 64) = u;
        }
}

// Z[N,32] = Y[N,256] @ W2[256,32]; N multiple of 128
__global__ __launch_bounds__(256) void k_fcb2n(const float* __restrict__ Y,
                                               const float* __restrict__ W2, float* __restrict__ Z) {
    __shared__ __align__(16) float At[32][132];
    __shared__ __align__(16) float Ws[32][32];
    int row0 = blockIdx.x * 128;
    int tid = threadIdx.x;
    int rg = (tid >> 3) * 4;
    int cg = (tid & 7) * 4;
    float acc[4][4];
#pragma unroll
    for (int j = 0; j < 4; ++j)
#pragma unroll
        for (int i = 0; i < 4; ++i) acc[j][i] = 0.f;
    for (int kc = 0; kc < 8; ++kc) {
        __syncthreads();
        for (int i = tid; i < 1024; i += 256) {
            int r = i >> 3, c4 = i & 7;
            const float4 v = *(const float4*)(Y + (size_t)(row0 + r) * 256 + kc * 32 + c4 * 4);
            At[c4 * 4 + 0][r] = v.x; At[c4 * 4 + 1][r] = v.y;
            At[c4 * 4 + 2][r] = v.z; At[c4 * 4 + 3][r] = v.w;
        }
        {
            int k = tid >> 3, c4 = tid & 7;
            ((float4*)&Ws[k][0])[c4] = ((const float4*)(W2 + (kc * 32 + k) * 32))[c4];
        }
        __syncthreads();
        for (int k = 0; k < 32; ++k) {
            const float4 av = *(const float4*)&At[k][rg];
            const float4 wv = *(const float4*)&Ws[k][cg];
            float a[4] = {av.x, av.y, av.z, av.w};
#pragma unroll
            for (int j = 0; j < 4; ++j) {
                acc[j][0] += a[j] * wv.x;
                acc[j][1] += a[j] * wv.y;
                acc[j][2] += a[j] * wv.z;
                acc[j][3] += a[j] * wv.w;
            }
        }
    }
#pragma unroll
    for (int j = 0; j < 4; ++j) {
        float4 u;
        u.x = acc[j][0]; u.y = acc[j][1]; u.z = acc[j][2]; u.w = acc[j][3];
        *(float4*)(Z + (size_t)(row0 + rg + j) * 32 + cg) = u;
    }
}

// C[N,128] = A[N,128] @ W[128,128] (+R); N multiple of 64
__global__ __launch_bounds__(256) void k_gk128(const float* __restrict__ A, const float* __restrict__ W,
                                               float* __restrict__ C, const float* __restrict__ R) {
    __shared__ __align__(16) float Ws[32][128];
    __shared__ __align__(16) float At[32][68];
    int row0 = blockIdx.x * 64;
    int tid = threadIdx.x;
    int rm = (tid >> 4) * 4;
    int fg = (tid & 15) * 4;
    float acc[2][4][4];
#pragma unroll
    for (int q = 0; q < 2; ++q)
#pragma unroll
        for (int j = 0; j < 4; ++j)
#pragma unroll
            for (int i = 0; i < 4; ++i) acc[q][j][i] = 0.f;
    for (int kc = 0; kc < 4; ++kc) {
        __syncthreads();
        for (int i = tid; i < 512; i += 256) {
            int r = i >> 3, c4 = i & 7;
            const float4 v = *(const float4*)(A + (size_t)(row0 + r) * 128 + kc * 32 + c4 * 4);
            At[c4 * 4 + 0][r] = v.x; At[c4 * 4 + 1][r] = v.y;
            At[c4 * 4 + 2][r] = v.z; At[c4 * 4 + 3][r] = v.w;
        }
        for (int i = tid; i < 1024; i += 256) {
            int k = i >> 5, f4 = i & 31;
            ((float4*)&Ws[k][0])[f4] = ((const float4*)(W + (kc * 32 + k) * 128))[f4];
        }
        __syncthreads();
        for (int k = 0; k < 32; ++k) {
            const float4 av = *(const float4*)&At[k][rm];
            float a[4] = {av.x, av.y, av.z, av.w};
#pragma unroll
            for (int q = 0; q < 2; ++q) {
                const float4 wv = *(const float4*)&Ws[k][fg + q * 64];
#pragma unroll
                for (int j = 0; j < 4; ++j) {
                    acc[q][j][0] += a[j] * wv.x;
                    acc[q][j][1] += a[j] * wv.y;
                    acc[q][j][2] += a[j] * wv.z;
                    acc[q][j][3] += a[j] * wv.w;
                }
            }
        }
    }
#pragma unroll
    for (int q = 0; q < 2; ++q)
#pragma unroll
        for (int j = 0; j < 4; ++j) {
            size_t off = (size_t)(row0 + rm + j) * 128 + fg + q * 64;
            float4 u;
            u.x = acc[q][j][0]; u.y = acc[q][j][1]; u.z = acc[q][j][2]; u.w = acc[q][j][3];
            if (R) {
                const float4 rv = *(const float4*)(R + off);
                u.x += rv.x; u.y += rv.y; u.z += rv.z; u.w += rv.w;
            }
            *(float4*)(C + off) = u;
        }
}

// alpha = softmax(V@wv over L); g = sum_l alpha*V
__global__ __launch_bounds__(256) void k_pool(const float* __restrict__ V, const float* __restrict__ wv,
                                              float* __restrict__ g) {
    __shared__ float sc[TL];
    __shared__ float red[4];
    int b = blockIdx.x, tid = threadIdx.x;
    if (tid < TL) {
        float a = 0.f;
        const float* vp = V + (size_t)(b * TL + tid) * TH;
        for (int h = 0; h < TH; ++h) a += vp[h] * wv[h];
        sc[tid] = a;
    }
    __syncthreads();
    float m = (tid < TL) ? sc[tid] : -INFINITY;
    m = block_reduce_max(m, red);
    float e = (tid < TL) ? expf(sc[tid] - m) : 0.f;
    float s = block_reduce_sum(e, red);
    if (tid < TL) sc[tid] = e / s;
    __syncthreads();
    if (tid < TH) {
        float a = 0.f;
        for (int l = 0; l < TL; ++l) a += sc[l] * V[(size_t)(b * TL + l) * TH + tid];
        g[b * TH + tid] = a;
    }
}

// out[n,k] = sum_d f[n, k*32+d] * vec[k*32+d]
__global__ __launch_bounds__(256) void k_scores(const float* __restrict__ f, const float* __restrict__ vec,
                                                float* __restrict__ out, int n) {
    int idx = blockIdx.x * blockDim.x + threadIdx.x;
    if (idx >= n * TNH) return;
    int node = idx >> 2, k = idx & 3;
    const float* fp = f + (size_t)node * TH + k * TD;
    const float* vp = vec + k * TD;
    float a = 0.f;
#pragma unroll
    for (int d = 0; d < TD; ++d) a += fp[d] * vp[d];
    out[idx] = a;
}

// fused per-dst-node GAT for both graphs
__global__ __launch_bounds__(128) void k_gat(const float* __restrict__ tax_cur,
                                             const float* __restrict__ fs_i, const float* __restrict__ el_i,
                                             const float* __restrict__ er_i, const int* __restrict__ src_i,
                                             const float* __restrict__ bi,
                                             const float* __restrict__ fs_t, const float* __restrict__ el_t,
                                             const float* __restrict__ er_t, const int* __restrict__ src_t,
                                             const float* __restrict__ bt,
                                             float* __restrict__ tax_nxt, float* __restrict__ acc, int hop) {
    int n = blockIdx.x, h = threadIdx.x, k = h >> 5;
    float cur = tax_cur[(size_t)n * TH + h];
    float ti, tt2;
    {
        float er = er_i[n * 4 + k];
        int s[4]; float e[4]; float m = -INFINITY;
#pragma unroll
        for (int j = 0; j < 4; ++j) {
            s[j] = src_i[n * 4 + j];
            float xx = el_i[s[j] * 4 + k] + er;
            e[j] = xx > 0.f ? xx : 0.2f * xx;
            m = fmaxf(m, e[j]);
        }
        float ssum = 0.f, av = 0.f;
#pragma unroll
        for (int j = 0; j < 4; ++j) {
            float a = expf(e[j] - m);
            ssum += a;
            av += a * fs_i[(size_t)s[j] * TH + h];
        }
        ti = fmaxf(av / ssum + cur + bi[h], 0.f);
    }
    {
        float er = er_t[n * 4 + k];
        int s[2]; float e[2]; float m = -INFINITY;
#pragma unroll
        for (int j = 0; j < 2; ++j) {
            s[j] = src_t[n * 2 + j];
            float xx = el_t[s[j] * 4 + k] + er;
            e[j] = xx > 0.f ? xx : 0.2f * xx;
            m = fmaxf(m, e[j]);
        }
        float ssum = 0.f, av = 0.f;
#pragma unroll
        for (int j = 0; j < 2; ++j) {
            float a = expf(e[j] - m);
            ssum += a;
            av += a * fs_t[(size_t)s[j] * TH + h];
        }
        tt2 = fmaxf(av / ssum + cur + bt[h], 0.f);
    }
    float nx = ti + tt2;
    size_t ai = (size_t)n * TH + h;
    tax_nxt[ai] = nx;
    acc[ai] = (hop == 0) ? nx : acc[ai] + nx;
}

// local + mul
__global__ __launch_bounds__(128) void k_local(const int* __restrict__ root, const float* __restrict__ acc,
                                               const float* __restrict__ g, float* __restrict__ local,
                                               float* __restrict__ mul) {
    __shared__ float red[2];
    int bf = blockIdx.x, b = bf >> 5;
    int h = threadIdx.x;
    int r = root[bf];
    float v = 0.f;
    if (r != -1) {
        int rc = r < 0 ? 0 : r;
        v = acc[(size_t)(b * TTP + rc) * TH + h] * 0.5f;
    }
    local[(size_t)bf * TH + h] = v;
    float s = block_reduce_sum(v * g[b * TH + h], red);
    if (h == 0) mul[bf] = s;
}

// per-b fuse; writes PT[h][b]
__global__ __launch_bounds__(128) void k_fuse(const float* __restrict__ mul, const float* __restrict__ local,
                                              const float* __restrict__ g,
                                              const float* __restrict__ liw_g, const float* __restrict__ liw_b,
                                              const float* __restrict__ int_g, const float* __restrict__ int_b,
                                              const float* __restrict__ uni_w, float* __restrict__ PT) {
    __shared__ float lm[TFT], wv_[TFT], inten[TH];
    __shared__ float red[2];
    int b = blockIdx.x, tid = threadIdx.x;
    if (tid < TFT) lm[tid] = mul[b * TFT + tid];
    __syncthreads();
    if (tid < TFT) {
        float mean = 0.f;
        for (int f = 0; f < TFT; ++f) mean += lm[f];
        mean *= (1.f / TFT);
        float var = 0.f;
        for (int f = 0; f < TFT; ++f) { float d = lm[f] - mean; var += d * d; }
        var *= (1.f / TFT);
        float ln = (lm[tid] - mean) * rsqrtf(var + 1e-8f) * liw_g[tid] + liw_b[tid];
        wv_[tid] = (lm[tid] != 0.f) ? ln : -INFINITY;
    }
    __syncthreads();
    if (tid < TFT) {
        float mx = -INFINITY;
        for (int f = 0; f < TFT; ++f) mx = fmaxf(mx, wv_[f]);
        float s = 0.f;
        for (int f = 0; f < TFT; ++f) s += expf(wv_[f] - mx);
        lm[tid] = expf(wv_[tid] - mx) / s;
    }
    __syncthreads();
    float ip = g[b * TH + tid];
    for (int f = 0; f < TFT; ++f) ip += lm[f] * local[(size_t)(b * TFT + f) * TH + tid];
    float mean = block_reduce_sum(ip, red) * (1.f / TH);
    float d = ip - mean;
    float var = block_reduce_sum(d * d, red) * (1.f / TH);
    inten[tid] = d * rsqrtf(var + 1e-8f) * int_g[tid] + int_b[tid];
    __syncthreads();
    float a = 0.f;
    for (int hp = 0; hp < TH; ++hp) a += inten[hp] * uni_w[hp * TH + tid];
    PT[tid * TB + b] = a;
}

// out[b,i] = dot(PT[:,b], E[i,:])
__global__ __launch_bounds__(256) void k_final(const float* __restrict__ PT, const float* __restrict__ E,
                                               float* __restrict__ out) {
    __shared__ float es[64][129];
    int i0 = blockIdx.x * 64;
    int tid = threadIdx.x;
    for (int i = tid; i < 64 * 32; i += 256) {
        int ii = i >> 5, h4 = i & 31;
        int it = i0 + ii;
        float4 v;
        if (it < TITEMS) v = ((const float4*)(E + (size_t)it * TH))[h4];
        else { v.x = v.y = v.z = v.w = 0.f; }
        es[ii][h4 * 4 + 0] = v.x;
        es[ii][h4 * 4 + 1] = v.y;
        es[ii][h4 * 4 + 2] = v.z;
        es[ii][h4 * 4 + 3] = v.w;
    }
    __syncthreads();
    int iq = tid & 15, bq = tid >> 4;
#pragma unroll 1
    for (int sweep = 0; sweep < 4; ++sweep) {
        int bb = sweep * 128 + bq * 8;
        float acc[8][4];
#pragma unroll
        for (int j = 0; j < 8; ++j)
#pragma unroll
            for (int t = 0; t < 4; ++t) acc[j][t] = 0.f;
        for (int h = 0; h < TH; ++h) {
            const float4 pA = *(const float4*)(PT + h * TB + bb);
            const float4 pB = *(const float4*)(PT + h * TB + bb + 4);
            float ev[4];
            ev[0] = es[iq][h];
            ev[1] = es[iq + 16][h];
            ev[2] = es[iq + 32][h];
            ev[3] = es[iq + 48][h];
            float pv[8] = {pA.x, pA.y, pA.z, pA.w, pB.x, pB.y, pB.z, pB.w};
#pragma unroll
            for (int j = 0; j < 8; ++j)
#pragma unroll
                for (int t = 0; t < 4; ++t) acc[j][t] += pv[j] * ev[t];
        }
#pragma unroll
        for (int t = 0; t < 4; ++t) {
            int it = i0 + 16 * t + iq;
            if (it < TITEMS) {
#pragma unroll
                for (int j = 0; j < 8; ++j)
                    out[(size_t)(bb + j) * TITEMS + it] = acc[j][t];
            }
        }
    }
}

extern "C" void kernel_launch(void* const* d_in, const int* in_sizes, int n_in,
                              void* d_out, int out_size, void* d_ws, size_t ws_size,
                              hipStream_t stream) {
    const int*   seq        = (const int*)d_in[0];
    const int*   root       = (const int*)d_in[1];
    const int*   i2t_src    = (const int*)d_in[3];
    const int*   t2t_src    = (const int*)d_in[5];
    const int*   item_ids   = (const int*)d_in[6];
    const int*   tax_ids    = (const int*)d_in[7];
    const float* item_embed = (const float*)d_in[8];
    const float* tax_embed  = (const float*)d_in[9];
    const float* scb_ln_g   = (const float*)d_in[10];
    const float* scb_ln_b   = (const float*)d_in[11];
    const float* scb_w1     = (const float*)d_in[12];
    const float* scb_w2     = (const float*)d_in[13];
    const float* fcb_ln_g   = (const float*)d_in[14];
    const float* fcb_ln_b   = (const float*)d_in[15];
    const float* fcb_w1     = (const float*)d_in[16];
    const float* fcb_w2     = (const float*)d_in[17];
    const float* fcb_w3     = (const float*)d_in[18];
    const float* wv         = (const float*)d_in[19];
    const float* gi_w       = (const float*)d_in[20];
    const float* gi_al      = (const float*)d_in[21];
    const float* gi_ar      = (const float*)d_in[22];
    const float* gi_b       = (const float*)d_in[23];
    const float* gt_w       = (const float*)d_in[24];
    const float* gt_al      = (const float*)d_in[25];
    const float* gt_ar      = (const float*)d_in[26];
    const float* gt_b       = (const float*)d_in[27];
    const float* liw_g      = (const float*)d_in[28];
    const float* liw_b      = (const float*)d_in[29];
    const float* int_g      = (const float*)d_in[30];
    const float* int_b      = (const float*)d_in[31];
    const float* uni_w      = (const float*)d_in[32];

    char* w = (char*)d_ws;
    float* V     = (float*)(w + 0);           // 52.4MB (V / fs_i)
    float* NV    = (float*)(w + 52428800);    // 52.4MB (nv / item_h)
    float* FSI   = V;
    float* ITEMH = NV;
    // mixer-GEMM phase (aliases GAT/fcb regions, disjoint in time):
    unsigned short* NVT = (unsigned short*)(w + 104857600);  // 29.36MB -> ends 134217728
    unsigned short* T   = (unsigned short*)(w + 134217728);  // 33.55MB (256 b) -> ends 167772160
    unsigned short* W1T = (unsigned short*)(w + 167772160);  // 229KB
    unsigned short* W2T = (unsigned short*)(w + 168001536);  // 213KB
    // fcb phase:
    float* YQf   = (float*)(w + 104857600);   // 52.4MB
    float* ZQ    = (float*)(w + 157286400);   // 6.6MB
    // GAT phase:
    float* TAX0  = (float*)(w + 104857600);
    float* TAX1  = (float*)(w + 121634816);
    float* ACC   = (float*)(w + 138412032);
    float* FDI   = (float*)(w + 155189248);
    float* FST   = (float*)(w + 171966464);
    float* ELI   = (float*)(w + 188743680);
    float* ERI   = (float*)(w + 190382080);
    float* ELT   = (float*)(w + 190906368);
    float* ERT   = (float*)(w + 191430656);
    float* LOCAL = (float*)(w + 191954944);
    float* G     = (float*)(w + 200343552);
    float* MUL   = (float*)(w + 200605696);
    float* PT    = FDI;
    if (ws_size < 200933376ull) return;

    // ---- global intention (mixer) ----
    k_gather<<<(TB * TL * 32 + 255) / 256, 256, 0, stream>>>(item_embed, seq, V, TB * TL);
    for (int nb = 0; nb < 2; ++nb) {
        k_ln<<<TB * TL / 8, 256, 0, stream>>>(V, NV, scb_ln_g + nb * TH, scb_ln_b + nb * TH);
        // --- scb via MFMA ---
        k_nvt<<<dim3(4, TB), 128, 0, stream>>>(NV, NVT);
        k_w1t<<<TSH, 256, 0, stream>>>(scb_w1 + nb * TL * TSH, W1T);
        k_w2t<<<208, 256, 0, stream>>>(scb_w2 + nb * TSH * TL, W2T);
        for (int bh = 0; bh < 2; ++bh) {
            k_mm1<<<dim3(4, 256), 256, 0, stream>>>(NVT, W1T, T, bh);
            k_mm2<<<dim3(4, 256), 256, 0, stream>>>(T, W2T, NV, V, bh);
        }
        // --- fcb (f32) ---
        k_ln<<<TB * TL / 8, 256, 0, stream>>>(V, NV, fcb_ln_g + nb * TH, fcb_ln_b + nb * TH);
        for (int q = 0; q < 8; ++q) {
            const float* Aq = NV + (size_t)q * 1638400;
            float* Vq = V + (size_t)q * 1638400;
            k_fcb1<<<800, 256, 0, stream>>>(Aq, fcb_w1 + nb * TD * TFH, YQf);
            k_fcb2n<<<400, 256, 0, stream>>>(YQf, fcb_w2 + nb * TFH * TD, ZQ);
            k_gk128<<<200, 256, 0, stream>>>(ZQ, fcb_w3 + nb * TH * TH, Vq, Aq);
        }
    }
    k_pool<<<TB, 256, 0, stream>>>(V, wv, G);

    // ---- local intention (GAT) ----
    k_gather<<<(TNI * 32 + 255) / 256, 256, 0, stream>>>(item_embed, item_ids, ITEMH, TNI);
    k_gather<<<(TNT * 32 + 255) / 256, 256, 0, stream>>>(tax_embed, tax_ids, TAX0, TNT);

    float* cur = TAX0;
    float* nxt = TAX1;
    for (int hop = 0; hop < 2; ++hop) {
        const float* Wi = gi_w + hop * TH * TH;
        const float* Wt = gt_w + hop * TH * TH;
        k_gk128<<<TNI / 64, 256, 0, stream>>>(ITEMH, Wi, FSI, nullptr);
        k_gk128<<<TNT / 64, 256, 0, stream>>>(cur, Wi, FDI, nullptr);
        k_gk128<<<TNT / 64, 256, 0, stream>>>(cur, Wt, FST, nullptr);
        k_scores<<<(TNI * TNH + 255) / 256, 256, 0, stream>>>(FSI, gi_al + hop * TH, ELI, TNI);
        k_scores<<<(TNT * TNH + 255) / 256, 256, 0, stream>>>(FDI, gi_ar + hop * TH, ERI, TNT);
        k_scores<<<(TNT * TNH + 255) / 256, 256, 0, stream>>>(FST, gt_al + hop * TH, ELT, TNT);
        k_scores<<<(TNT * TNH + 255) / 256, 256, 0, stream>>>(FST, gt_ar + hop * TH, ERT, TNT);
        k_gat<<<TNT, 128, 0, stream>>>(cur, FSI, ELI, ERI, i2t_src, gi_b + hop * TH,
                                       FST, ELT, ERT, t2t_src, gt_b + hop * TH, nxt, ACC, hop);
        float* tmp = cur; cur = nxt; nxt = tmp;
    }

    // ---- fuse ----
    k_local<<<TB * TFT, 128, 0, stream>>>(root, ACC, G, LOCAL, MUL);
    k_fuse<<<TB, 128, 0, stream>>>(MUL, LOCAL, G, liw_g, liw_b, int_g, int_b, uni_w, PT);

    k_final<<<(TITEMS + 63) / 64, 256, 0, stream>>>(PT, item_embed, (float*)d_out);
}

// Round 7
// 1266.743 us; speedup vs baseline: 18.2224x; 1.7472x over previous
//
#include <hip/hip_runtime.h>
#include <hip/hip_bf16.h>

// ---- model dims ----
constexpr int TB = 512, TL = 200, TH = 128, TNH = 4, TD = 32;
constexpr int TFT = 32, TTP = 64, TIP = 200;
constexpr int TSH = 512, TFH = 256;
constexpr int TITEMS = 100001;
constexpr int TNT = TB * TTP;   // 32768
constexpr int TNI = TB * TIP;   // 102400
constexpr int TLP = 224;        // L padded (K of scb GEMM1)
constexpr int TIPAD = 100096;   // items padded to 128

typedef __attribute__((ext_vector_type(8))) short short8v;
typedef __attribute__((ext_vector_type(4))) float f32x4;

__device__ inline float gelu_exact(float x) {
    return 0.5f * x * (1.0f + erff(x * 0.7071067811865476f));
}
__device__ inline unsigned short to_bf16u(float x) {
    __hip_bfloat16 h = __float2bfloat16(x);
    return *reinterpret_cast<unsigned short*>(&h);
}

__device__ inline float block_reduce_sum(float v, float* red) {
    for (int o = 32; o > 0; o >>= 1) v += __shfl_down(v, o, 64);
    int nw = blockDim.x >> 6;
    if ((threadIdx.x & 63) == 0) red[threadIdx.x >> 6] = v;
    __syncthreads();
    float r = 0.f;
    for (int w = 0; w < nw; ++w) r += red[w];
    __syncthreads();
    return r;
}

__device__ inline float block_reduce_max(float v, float* red) {
    for (int o = 32; o > 0; o >>= 1) v = fmaxf(v, __shfl_down(v, o, 64));
    int nw = blockDim.x >> 6;
    if ((threadIdx.x & 63) == 0) red[threadIdx.x >> 6] = v;
    __syncthreads();
    float r = -INFINITY;
    for (int w = 0; w < nw; ++w) r = fmaxf(r, red[w]);
    __syncthreads();
    return r;
}

// out[r,:] = table[idx[r],:]
__global__ __launch_bounds__(256) void k_gather(const float* __restrict__ tab,
                                                const int* __restrict__ idx,
                                                float* __restrict__ out, int nrows) {
    int e = blockIdx.x * blockDim.x + threadIdx.x;
    if (e >= nrows * 32) return;
    int r = e >> 5, c = e & 31;
    ((float4*)out)[e] = ((const float4*)tab)[(size_t)idx[r] * 32 + c];
}

// row-wise LayerNorm over H=128: 8 rows / 256-thread block
__global__ __launch_bounds__(256) void k_ln(const float* __restrict__ x, float* __restrict__ y,
                                            const float* __restrict__ g, const float* __restrict__ b) {
    int row = blockIdx.x * 8 + (threadIdx.x >> 5);
    int lane = threadIdx.x & 31;
    const float4 v = ((const float4*)(x + (size_t)row * TH))[lane];
    float s = v.x + v.y + v.z + v.w;
    for (int o = 16; o > 0; o >>= 1) s += __shfl_down(s, o, 32);
    float mean = __shfl(s, 0, 32) * (1.f / 128.f);
    float4 d;
    d.x = v.x - mean; d.y = v.y - mean; d.z = v.z - mean; d.w = v.w - mean;
    float q = d.x * d.x + d.y * d.y + d.z * d.z + d.w * d.w;
    for (int o = 16; o > 0; o >>= 1) q += __shfl_down(q, o, 32);
    float inv = rsqrtf(__shfl(q, 0, 32) * (1.f / 128.f) + 1e-8f);
    const float4 gg = ((const float4*)g)[lane];
    const float4 bb = ((const float4*)b)[lane];
    float4 o4;
    o4.x = d.x * inv * gg.x + bb.x;
    o4.y = d.y * inv * gg.y + bb.y;
    o4.z = d.z * inv * gg.z + bb.z;
    o4.w = d.w * inv * gg.w + bb.w;
    ((float4*)(y + (size_t)row * TH))[lane] = o4;
}

// NV[b][l][h] f32 -> NVT[b][h][lp] bf16 (l zero-padded to 224)
__global__ __launch_bounds__(128) void k_nvt(const float* __restrict__ NV,
                                             unsigned short* __restrict__ NVT) {
    __shared__ float tl[64][129];
    int b = blockIdx.y, l0 = blockIdx.x * 64, tid = threadIdx.x;
    for (int i = tid; i < 2048; i += 128) {
        int r = i >> 5, c = i & 31;
        int l = l0 + r;
        float4 v = {0.f, 0.f, 0.f, 0.f};
        if (l < TL) v = *(const float4*)(NV + ((size_t)b * TL + l) * TH + c * 4);
        tl[r][c * 4 + 0] = v.x; tl[r][c * 4 + 1] = v.y;
        tl[r][c * 4 + 2] = v.z; tl[r][c * 4 + 3] = v.w;
    }
    __syncthreads();
    int h = tid;
    int ng = (l0 + 64 > TLP) ? (TLP - l0) / 8 : 8;
    for (int lg = 0; lg < ng; ++lg) {
        uint4 u;
        unsigned int p[4];
#pragma unroll
        for (int q = 0; q < 4; ++q) {
            unsigned short ua = to_bf16u(tl[lg * 8 + q * 2 + 0][h]);
            unsigned short ub = to_bf16u(tl[lg * 8 + q * 2 + 1][h]);
            p[q] = (unsigned int)ua | ((unsigned int)ub << 16);
        }
        u.x = p[0]; u.y = p[1]; u.z = p[2]; u.w = p[3];
        *(uint4*)(NVT + ((size_t)b * TH + h) * TLP + l0 + lg * 8) = u;
    }
}

// w1[l][s] f32 -> W1T[s][lp] bf16
__global__ __launch_bounds__(256) void k_w1t(const float* __restrict__ w1,
                                             unsigned short* __restrict__ W1T) {
    int s = blockIdx.x, l = threadIdx.x;
    if (l >= TLP) return;
    float v = (l < TL) ? w1[(size_t)l * TSH + s] : 0.f;
    W1T[(size_t)s * TLP + l] = to_bf16u(v);
}

// w2[s][l] f32 -> W2T[lp208][s] bf16
__global__ __launch_bounds__(256) void k_w2t(const float* __restrict__ w2,
                                             unsigned short* __restrict__ W2T) {
    int l = blockIdx.x;
    for (int it = 0; it < 2; ++it) {
        int s = it * 256 + threadIdx.x;
        float v = (l < TL) ? w2[(size_t)s * TL + l] : 0.f;
        W2T[(size_t)l * TSH + s] = to_bf16u(v);
    }
}

// scb GEMM1: T[b][h][s] = gelu( sum_l NVT[b][h][l] * w1[l][s] )
__global__ __launch_bounds__(256) void k_mm1(const unsigned short* __restrict__ NVT,
                                             const unsigned short* __restrict__ W1T,
                                             unsigned short* __restrict__ T, int bh) {
    __shared__ unsigned short As[128][40];
    __shared__ unsigned short Bs[128][40];
    int tid = threadIdx.x;
    int b_local = blockIdx.y, b = bh * 256 + b_local;
    int s0 = blockIdx.x * 128;
    int lane = tid & 63, wid = tid >> 6;
    int mw = wid >> 1, nw = wid & 1;
    f32x4 acc[4][4];
#pragma unroll
    for (int i = 0; i < 4; ++i)
#pragma unroll
        for (int j = 0; j < 4; ++j) acc[i][j] = (f32x4){0.f, 0.f, 0.f, 0.f};
    const unsigned short* Abase = NVT + (size_t)b * TH * TLP;
    const unsigned short* Bbase = W1T + (size_t)s0 * TLP;
    for (int kc = 0; kc < 7; ++kc) {
        __syncthreads();
        for (int i = tid; i < 512; i += 256) {
            int r = i >> 2, q = i & 3;
            *(uint4*)&As[r][q * 8] = *(const uint4*)(Abase + (size_t)r * TLP + kc * 32 + q * 8);
            *(uint4*)&Bs[r][q * 8] = *(const uint4*)(Bbase + (size_t)r * TLP + kc * 32 + q * 8);
        }
        __syncthreads();
        int ko = (lane >> 4) * 8;
        short8v af[4], bfr[4];
#pragma unroll
        for (int t = 0; t < 4; ++t) {
            af[t] = *(const short8v*)&As[mw * 64 + t * 16 + (lane & 15)][ko];
            bfr[t] = *(const short8v*)&Bs[nw * 64 + t * 16 + (lane & 15)][ko];
        }
#pragma unroll
        for (int i = 0; i < 4; ++i)
#pragma unroll
            for (int j = 0; j < 4; ++j)
                acc[i][j] = __builtin_amdgcn_mfma_f32_16x16x32_bf16(af[i], bfr[j], acc[i][j], 0, 0, 0);
    }
    int rbase = (lane >> 4) * 4, col = lane & 15;
#pragma unroll
    for (int i = 0; i < 4; ++i)
#pragma unroll
        for (int j = 0; j < 4; ++j) {
            int h0 = mw * 64 + i * 16 + rbase;
            int s = s0 + nw * 64 + j * 16 + col;
#pragma unroll
            for (int r = 0; r < 4; ++r)
                T[((size_t)b_local * TH + h0 + r) * TSH + s] = to_bf16u(gelu_exact(acc[i][j][r]));
        }
}

// scb GEMM2: VS[b][l][h] = NV[b][l][h] + sum_s T[b][h][s] * w2[s][l]
__global__ __launch_bounds__(256) void k_mm2(const unsigned short* __restrict__ T,
                                             const unsigned short* __restrict__ W2T,
                                             const float* __restrict__ NV,
                                             float* __restrict__ VS, int bh) {
    __shared__ unsigned short As[128][40];
    __shared__ unsigned short Bs[64][40];
    int tid = threadIdx.x;
    int b_local = blockIdx.y, b = bh * 256 + b_local;
    int l0 = blockIdx.x * 64;
    int lane = tid & 63, wid = tid >> 6;
    f32x4 acc[2][4];
#pragma unroll
    for (int i = 0; i < 2; ++i)
#pragma unroll
        for (int j = 0; j < 4; ++j) acc[i][j] = (f32x4){0.f, 0.f, 0.f, 0.f};
    const unsigned short* Abase = T + (size_t)b_local * TH * TSH;
    for (int kc = 0; kc < 16; ++kc) {
        __syncthreads();
        for (int i = tid; i < 512; i += 256) {
            int r = i >> 2, q = i & 3;
            *(uint4*)&As[r][q * 8] = *(const uint4*)(Abase + (size_t)r * TSH + kc * 32 + q * 8);
        }
        {
            int r = tid >> 2, q = tid & 3;
            int l = l0 + r;
            uint4 v = {0u, 0u, 0u, 0u};
            if (l < 208) v = *(const uint4*)(W2T + (size_t)l * TSH + kc * 32 + q * 8);
            *(uint4*)&Bs[r][q * 8] = v;
        }
        __syncthreads();
        int ko = (lane >> 4) * 8;
        short8v af[2], bfr[4];
#pragma unroll
        for (int t = 0; t < 2; ++t)
            af[t] = *(const short8v*)&As[wid * 32 + t * 16 + (lane & 15)][ko];
#pragma unroll
        for (int j = 0; j < 4; ++j)
            bfr[j] = *(const short8v*)&Bs[j * 16 + (lane & 15)][ko];
#pragma unroll
        for (int i = 0; i < 2; ++i)
#pragma unroll
            for (int j = 0; j < 4; ++j)
                acc[i][j] = __builtin_amdgcn_mfma_f32_16x16x32_bf16(af[i], bfr[j], acc[i][j], 0, 0, 0);
    }
    int rbase = (lane >> 4) * 4, col = lane & 15;
#pragma unroll
    for (int i = 0; i < 2; ++i)
#pragma unroll
        for (int j = 0; j < 4; ++j) {
            int l = l0 + j * 16 + col;
            if (l < TL) {
                int h0 = wid * 32 + i * 16 + rbase;
                size_t off = ((size_t)b * TL + l) * TH + h0;
                const float4 res = *(const float4*)(NV + off);
                float4 o;
                o.x = acc[i][j][0] + res.x;
                o.y = acc[i][j][1] + res.y;
                o.z = acc[i][j][2] + res.z;
                o.w = acc[i][j][3] + res.w;
                *(float4*)(VS + off) = o;
            }
        }
}

// fused fcb stage1+2: per 64 rows-of-32: y=gelu(A@w1) in LDS; Z=y@w2 (bf16 out)
__global__ __launch_bounds__(256) void k_ffuse(const float* __restrict__ NV,
                                               const float* __restrict__ W1,
                                               const float* __restrict__ W2,
                                               unsigned short* __restrict__ Z) {
    __shared__ unsigned short As[64][40];
    __shared__ unsigned short Bs1[256][40];
    __shared__ unsigned short Yl[64][264];
    __shared__ unsigned short Bs2[32][264];
    int tid = threadIdx.x;
    int m0 = blockIdx.x * 64;   // rows-of-32
    int lane = tid & 63, wid = tid >> 6;
    // stage A (64 x 32, f32 -> bf16)
    for (int i = tid; i < 512; i += 256) {
        int r = i >> 3, q = i & 7;
        const float4 v = *(const float4*)(NV + (size_t)(m0 + r) * 32 + q * 4);
        ushort4 u;
        u.x = to_bf16u(v.x); u.y = to_bf16u(v.y); u.z = to_bf16u(v.z); u.w = to_bf16u(v.w);
        *(ushort4*)&As[r][q * 4] = u;
    }
    // stage B1: W1[32][256] -> Bs1[n][k]
    for (int i = tid; i < 2048; i += 256) {
        int k = i & 31, c4 = i >> 5;
        const float4 v = *(const float4*)(W1 + (size_t)k * TFH + c4 * 4);
        Bs1[c4 * 4 + 0][k] = to_bf16u(v.x);
        Bs1[c4 * 4 + 1][k] = to_bf16u(v.y);
        Bs1[c4 * 4 + 2][k] = to_bf16u(v.z);
        Bs1[c4 * 4 + 3][k] = to_bf16u(v.w);
    }
    __syncthreads();
    // f1: C[64m][256n], wave w owns n-slice w*64
    {
        f32x4 acc[4][4];
#pragma unroll
        for (int i = 0; i < 4; ++i)
#pragma unroll
            for (int j = 0; j < 4; ++j) acc[i][j] = (f32x4){0.f, 0.f, 0.f, 0.f};
        int ko = (lane >> 4) * 8;
        short8v af[4], bfr[4];
#pragma unroll
        for (int t = 0; t < 4; ++t) {
            af[t] = *(const short8v*)&As[t * 16 + (lane & 15)][ko];
            bfr[t] = *(const short8v*)&Bs1[wid * 64 + t * 16 + (lane & 15)][ko];
        }
#pragma unroll
        for (int i = 0; i < 4; ++i)
#pragma unroll
            for (int j = 0; j < 4; ++j)
                acc[i][j] = __builtin_amdgcn_mfma_f32_16x16x32_bf16(af[i], bfr[j], acc[i][j], 0, 0, 0);
        int rbase = (lane >> 4) * 4, col = lane & 15;
#pragma unroll
        for (int i = 0; i < 4; ++i)
#pragma unroll
            for (int j = 0; j < 4; ++j)
#pragma unroll
                for (int r = 0; r < 4; ++r)
                    Yl[i * 16 + rbase + r][wid * 64 + j * 16 + col] =
                        to_bf16u(gelu_exact(acc[i][j][r]));
    }
    // stage B2: W2[256][32] -> Bs2[n=32][k=256]
    for (int i = tid; i < 2048; i += 256) {
        int f = i >> 3, c4 = i & 7;
        const float4 v = *(const float4*)(W2 + (size_t)f * TD + c4 * 4);
        Bs2[c4 * 4 + 0][f] = to_bf16u(v.x);
        Bs2[c4 * 4 + 1][f] = to_bf16u(v.y);
        Bs2[c4 * 4 + 2][f] = to_bf16u(v.z);
        Bs2[c4 * 4 + 3][f] = to_bf16u(v.w);
    }
    __syncthreads();
    // f2: C[64m][32n], wave w owns m-rows w*16, K=256
    {
        f32x4 acc2[2];
        acc2[0] = (f32x4){0.f, 0.f, 0.f, 0.f};
        acc2[1] = (f32x4){0.f, 0.f, 0.f, 0.f};
        for (int kc = 0; kc < 8; ++kc) {
            int ko = kc * 32 + (lane >> 4) * 8;
            short8v af = *(const short8v*)&Yl[wid * 16 + (lane & 15)][ko];
            short8v b0 = *(const short8v*)&Bs2[(lane & 15)][ko];
            short8v b1 = *(const short8v*)&Bs2[16 + (lane & 15)][ko];
            acc2[0] = __builtin_amdgcn_mfma_f32_16x16x32_bf16(af, b0, acc2[0], 0, 0, 0);
            acc2[1] = __builtin_amdgcn_mfma_f32_16x16x32_bf16(af, b1, acc2[1], 0, 0, 0);
        }
        int rbase = (lane >> 4) * 4, col = lane & 15;
#pragma unroll
        for (int j = 0; j < 2; ++j)
#pragma unroll
            for (int r = 0; r < 4; ++r)
                Z[(size_t)(m0 + wid * 16 + rbase + r) * 32 + j * 16 + col] =
                    to_bf16u(acc2[j][r]);
    }
}

// fcb stage3: V[N,128] = Z[N,128](bf16) @ W3[128,128](f32) + NV  (f32 out)
__global__ __launch_bounds__(256) void k_f3m(const unsigned short* __restrict__ Z,
                                             const float* __restrict__ W3,
                                             const float* __restrict__ NV,
                                             float* __restrict__ V) {
    __shared__ unsigned short As[128][40];
    __shared__ unsigned short Bs[128][40];
    int tid = threadIdx.x;
    int m0 = blockIdx.x * 128;   // H-rows
    int lane = tid & 63, wid = tid >> 6;
    int mw = wid >> 1, nw = wid & 1;
    f32x4 acc[4][4];
#pragma unroll
    for (int i = 0; i < 4; ++i)
#pragma unroll
        for (int j = 0; j < 4; ++j) acc[i][j] = (f32x4){0.f, 0.f, 0.f, 0.f};
    for (int kc = 0; kc < 4; ++kc) {
        __syncthreads();
        for (int i = tid; i < 512; i += 256) {
            int r = i >> 2, q = i & 3;
            *(uint4*)&As[r][q * 8] = *(const uint4*)(Z + (size_t)(m0 + r) * TH + kc * 32 + q * 8);
        }
        for (int i = tid; i < 1024; i += 256) {
            int kk = i & 31, c4 = i >> 5;
            const float4 v = *(const float4*)(W3 + (size_t)(kc * 32 + kk) * TH + c4 * 4);
            Bs[c4 * 4 + 0][kk] = to_bf16u(v.x);
            Bs[c4 * 4 + 1][kk] = to_bf16u(v.y);
            Bs[c4 * 4 + 2][kk] = to_bf16u(v.z);
            Bs[c4 * 4 + 3][kk] = to_bf16u(v.w);
        }
        __syncthreads();
        int ko = (lane >> 4) * 8;
        short8v af[4], bfr[4];
#pragma unroll
        for (int t = 0; t < 4; ++t) {
            af[t] = *(const short8v*)&As[mw * 64 + t * 16 + (lane & 15)][ko];
            bfr[t] = *(const short8v*)&Bs[nw * 64 + t * 16 + (lane & 15)][ko];
        }
#pragma unroll
        for (int i = 0; i < 4; ++i)
#pragma unroll
            for (int j = 0; j < 4; ++j)
                acc[i][j] = __builtin_amdgcn_mfma_f32_16x16x32_bf16(af[i], bfr[j], acc[i][j], 0, 0, 0);
    }
    int rbase = (lane >> 4) * 4, col = lane & 15;
#pragma unroll
    for (int i = 0; i < 4; ++i)
#pragma unroll
        for (int j = 0; j < 4; ++j) {
            int n = nw * 64 + j * 16 + col;
#pragma unroll
            for (int r = 0; r < 4; ++r) {
                size_t off = (size_t)(m0 + mw * 64 + i * 16 + rbase + r) * TH + n;
                V[off] = acc[i][j][r] + NV[off];
            }
        }
}

// C[N,128] = A[N,128] @ W[128,128] (+R); N multiple of 64 (f32, GAT)
__global__ __launch_bounds__(256) void k_gk128(const float* __restrict__ A, const float* __restrict__ W,
                                               float* __restrict__ C, const float* __restrict__ R) {
    __shared__ __align__(16) float Ws[32][128];
    __shared__ __align__(16) float At[32][68];
    int row0 = blockIdx.x * 64;
    int tid = threadIdx.x;
    int rm = (tid >> 4) * 4;
    int fg = (tid & 15) * 4;
    float acc[2][4][4];
#pragma unroll
    for (int q = 0; q < 2; ++q)
#pragma unroll
        for (int j = 0; j < 4; ++j)
#pragma unroll
            for (int i = 0; i < 4; ++i) acc[q][j][i] = 0.f;
    for (int kc = 0; kc < 4; ++kc) {
        __syncthreads();
        for (int i = tid; i < 512; i += 256) {
            int r = i >> 3, c4 = i & 7;
            const float4 v = *(const float4*)(A + (size_t)(row0 + r) * 128 + kc * 32 + c4 * 4);
            At[c4 * 4 + 0][r] = v.x; At[c4 * 4 + 1][r] = v.y;
            At[c4 * 4 + 2][r] = v.z; At[c4 * 4 + 3][r] = v.w;
        }
        for (int i = tid; i < 1024; i += 256) {
            int k = i >> 5, f4 = i & 31;
            ((float4*)&Ws[k][0])[f4] = ((const float4*)(W + (kc * 32 + k) * 128))[f4];
        }
        __syncthreads();
        for (int k = 0; k < 32; ++k) {
            const float4 av = *(const float4*)&At[k][rm];
            float a[4] = {av.x, av.y, av.z, av.w};
#pragma unroll
            for (int q = 0; q < 2; ++q) {
                const float4 wv = *(const float4*)&Ws[k][fg + q * 64];
#pragma unroll
                for (int j = 0; j < 4; ++j) {
                    acc[q][j][0] += a[j] * wv.x;
                    acc[q][j][1] += a[j] * wv.y;
                    acc[q][j][2] += a[j] * wv.z;
                    acc[q][j][3] += a[j] * wv.w;
                }
            }
        }
    }
#pragma unroll
    for (int q = 0; q < 2; ++q)
#pragma unroll
        for (int j = 0; j < 4; ++j) {
            size_t off = (size_t)(row0 + rm + j) * 128 + fg + q * 64;
            float4 u;
            u.x = acc[q][j][0]; u.y = acc[q][j][1]; u.z = acc[q][j][2]; u.w = acc[q][j][3];
            if (R) {
                const float4 rv = *(const float4*)(R + off);
                u.x += rv.x; u.y += rv.y; u.z += rv.z; u.w += rv.w;
            }
            *(float4*)(C + off) = u;
        }
}

// alpha = softmax(V@wv over L); g = sum_l alpha*V
__global__ __launch_bounds__(256) void k_pool(const float* __restrict__ V, const float* __restrict__ wv,
                                              float* __restrict__ g) {
    __shared__ float sc[TL];
    __shared__ float red[4];
    int b = blockIdx.x, tid = threadIdx.x;
    if (tid < TL) {
        float a = 0.f;
        const float* vp = V + (size_t)(b * TL + tid) * TH;
        for (int h = 0; h < TH; ++h) a += vp[h] * wv[h];
        sc[tid] = a;
    }
    __syncthreads();
    float m = (tid < TL) ? sc[tid] : -INFINITY;
    m = block_reduce_max(m, red);
    float e = (tid < TL) ? expf(sc[tid] - m) : 0.f;
    float s = block_reduce_sum(e, red);
    if (tid < TL) sc[tid] = e / s;
    __syncthreads();
    if (tid < TH) {
        float a = 0.f;
        for (int l = 0; l < TL; ++l) a += sc[l] * V[(size_t)(b * TL + l) * TH + tid];
        g[b * TH + tid] = a;
    }
}

// out[n,k] = sum_d f[n, k*32+d] * vec[k*32+d]
__global__ __launch_bounds__(256) void k_scores(const float* __restrict__ f, const float* __restrict__ vec,
                                                float* __restrict__ out, int n) {
    int idx = blockIdx.x * blockDim.x + threadIdx.x;
    if (idx >= n * TNH) return;
    int node = idx >> 2, k = idx & 3;
    const float* fp = f + (size_t)node * TH + k * TD;
    const float* vp = vec + k * TD;
    float a = 0.f;
#pragma unroll
    for (int d = 0; d < TD; ++d) a += fp[d] * vp[d];
    out[idx] = a;
}

// fused per-dst-node GAT for both graphs
__global__ __launch_bounds__(128) void k_gat(const float* __restrict__ tax_cur,
                                             const float* __restrict__ fs_i, const float* __restrict__ el_i,
                                             const float* __restrict__ er_i, const int* __restrict__ src_i,
                                             const float* __restrict__ bi,
                                             const float* __restrict__ fs_t, const float* __restrict__ el_t,
                                             const float* __restrict__ er_t, const int* __restrict__ src_t,
                                             const float* __restrict__ bt,
                                             float* __restrict__ tax_nxt, float* __restrict__ acc, int hop) {
    int n = blockIdx.x, h = threadIdx.x, k = h >> 5;
    float cur = tax_cur[(size_t)n * TH + h];
    float ti, tt2;
    {
        float er = er_i[n * 4 + k];
        int s[4]; float e[4]; float m = -INFINITY;
#pragma unroll
        for (int j = 0; j < 4; ++j) {
            s[j] = src_i[n * 4 + j];
            float xx = el_i[s[j] * 4 + k] + er;
            e[j] = xx > 0.f ? xx : 0.2f * xx;
            m = fmaxf(m, e[j]);
        }
        float ssum = 0.f, av = 0.f;
#pragma unroll
        for (int j = 0; j < 4; ++j) {
            float a = expf(e[j] - m);
            ssum += a;
            av += a * fs_i[(size_t)s[j] * TH + h];
        }
        ti = fmaxf(av / ssum + cur + bi[h], 0.f);
    }
    {
        float er = er_t[n * 4 + k];
        int s[2]; float e[2]; float m = -INFINITY;
#pragma unroll
        for (int j = 0; j < 2; ++j) {
            s[j] = src_t[n * 2 + j];
            float xx = el_t[s[j] * 4 + k] + er;
            e[j] = xx > 0.f ? xx : 0.2f * xx;
            m = fmaxf(m, e[j]);
        }
        float ssum = 0.f, av = 0.f;
#pragma unroll
        for (int j = 0; j < 2; ++j) {
            float a = expf(e[j] - m);
            ssum += a;
            av += a * fs_t[(size_t)s[j] * TH + h];
        }
        tt2 = fmaxf(av / ssum + cur + bt[h], 0.f);
    }
    float nx = ti + tt2;
    size_t ai = (size_t)n * TH + h;
    tax_nxt[ai] = nx;
    acc[ai] = (hop == 0) ? nx : acc[ai] + nx;
}

// local + mul
__global__ __launch_bounds__(128) void k_local(const int* __restrict__ root, const float* __restrict__ acc,
                                               const float* __restrict__ g, float* __restrict__ local,
                                               float* __restrict__ mul) {
    __shared__ float red[2];
    int bf = blockIdx.x, b = bf >> 5;
    int h = threadIdx.x;
    int r = root[bf];
    float v = 0.f;
    if (r != -1) {
        int rc = r < 0 ? 0 : r;
        v = acc[(size_t)(b * TTP + rc) * TH + h] * 0.5f;
    }
    local[(size_t)bf * TH + h] = v;
    float s = block_reduce_sum(v * g[b * TH + h], red);
    if (h == 0) mul[bf] = s;
}

// per-b fuse; writes PB[b][h] bf16
__global__ __launch_bounds__(128) void k_fuse(const float* __restrict__ mul, const float* __restrict__ local,
                                              const float* __restrict__ g,
                                              const float* __restrict__ liw_g, const float* __restrict__ liw_b,
                                              const float* __restrict__ int_g, const float* __restrict__ int_b,
                                              const float* __restrict__ uni_w, unsigned short* __restrict__ PB) {
    __shared__ float lm[TFT], wv_[TFT], inten[TH];
    __shared__ float red[2];
    int b = blockIdx.x, tid = threadIdx.x;
    if (tid < TFT) lm[tid] = mul[b * TFT + tid];
    __syncthreads();
    if (tid < TFT) {
        float mean = 0.f;
        for (int f = 0; f < TFT; ++f) mean += lm[f];
        mean *= (1.f / TFT);
        float var = 0.f;
        for (int f = 0; f < TFT; ++f) { float d = lm[f] - mean; var += d * d; }
        var *= (1.f / TFT);
        float ln = (lm[tid] - mean) * rsqrtf(var + 1e-8f) * liw_g[tid] + liw_b[tid];
        wv_[tid] = (lm[tid] != 0.f) ? ln : -INFINITY;
    }
    __syncthreads();
    if (tid < TFT) {
        float mx = -INFINITY;
        for (int f = 0; f < TFT; ++f) mx = fmaxf(mx, wv_[f]);
        float s = 0.f;
        for (int f = 0; f < TFT; ++f) s += expf(wv_[f] - mx);
        lm[tid] = expf(wv_[tid] - mx) / s;
    }
    __syncthreads();
    float ip = g[b * TH + tid];
    for (int f = 0; f < TFT; ++f) ip += lm[f] * local[(size_t)(b * TFT + f) * TH + tid];
    float mean = block_reduce_sum(ip, red) * (1.f / TH);
    float d = ip - mean;
    float var = block_reduce_sum(d * d, red) * (1.f / TH);
    inten[tid] = d * rsqrtf(var + 1e-8f) * int_g[tid] + int_b[tid];
    __syncthreads();
    float a = 0.f;
    for (int hp = 0; hp < TH; ++hp) a += inten[hp] * uni_w[hp * TH + tid];
    PB[(size_t)b * TH + tid] = to_bf16u(a);
}

// E f32 -> EB bf16, rows padded to TIPAD (zeros)
__global__ __launch_bounds__(256) void k_ebc(const float* __restrict__ E,
                                             unsigned short* __restrict__ EB) {
    int t = blockIdx.x * 256 + threadIdx.x;
    if (t >= TIPAD * TH / 8) return;
    size_t base = (size_t)t * 8;
    int row = (int)(base >> 7);
    float4 a = {0.f, 0.f, 0.f, 0.f}, b = {0.f, 0.f, 0.f, 0.f};
    if (row < TITEMS) {
        a = *(const float4*)(E + base);
        b = *(const float4*)(E + base + 4);
    }
    ushort4 u0, u1;
    u0.x = to_bf16u(a.x); u0.y = to_bf16u(a.y); u0.z = to_bf16u(a.z); u0.w = to_bf16u(a.w);
    u1.x = to_bf16u(b.x); u1.y = to_bf16u(b.y); u1.z = to_bf16u(b.z); u1.w = to_bf16u(b.w);
    *(ushort4*)(EB + base) = u0;
    *(ushort4*)(EB + base + 4) = u1;
}

// out[b,i] = PB[b,:] . EB[i,:]  (bf16 MFMA, 128b x 128i tile)
__global__ __launch_bounds__(256) void k_final_m(const unsigned short* __restrict__ PB,
                                                 const unsigned short* __restrict__ EB,
                                                 float* __restrict__ out) {
    __shared__ unsigned short As[128][136];
    __shared__ unsigned short Bs[128][136];
    int tid = threadIdx.x;
    int i0 = blockIdx.x * 128, b0 = blockIdx.y * 128;
    for (int i = tid; i < 2048; i += 256) {
        int r = i >> 4, q = i & 15;
        *(uint4*)&As[r][q * 8] = *(const uint4*)(PB + (size_t)(b0 + r) * TH + q * 8);
    }
    for (int i = tid; i < 2048; i += 256) {
        int r = i >> 4, q = i & 15;
        *(uint4*)&Bs[r][q * 8] = *(const uint4*)(EB + (size_t)(i0 + r) * TH + q * 8);
    }
    __syncthreads();
    int lane = tid & 63, wid = tid >> 6;
    int mw = wid >> 1, nw = wid & 1;
    f32x4 acc[4][4];
#pragma unroll
    for (int i = 0; i < 4; ++i)
#pragma unroll
        for (int j = 0; j < 4; ++j) acc[i][j] = (f32x4){0.f, 0.f, 0.f, 0.f};
#pragma unroll
    for (int kc = 0; kc < 4; ++kc) {
        int ko = kc * 32 + (lane >> 4) * 8;
        short8v af[4], bfr[4];
#pragma unroll
        for (int t = 0; t < 4; ++t) {
            af[t] = *(const short8v*)&As[mw * 64 + t * 16 + (lane & 15)][ko];
            bfr[t] = *(const short8v*)&Bs[nw * 64 + t * 16 + (lane & 15)][ko];
        }
#pragma unroll
        for (int i = 0; i < 4; ++i)
#pragma unroll
            for (int j = 0; j < 4; ++j)
                acc[i][j] = __builtin_amdgcn_mfma_f32_16x16x32_bf16(af[i], bfr[j], acc[i][j], 0, 0, 0);
    }
    int rbase = (lane >> 4) * 4, col = lane & 15;
#pragma unroll
    for (int i = 0; i < 4; ++i)
#pragma unroll
        for (int j = 0; j < 4; ++j) {
            int ii = i0 + nw * 64 + j * 16 + col;
            if (ii < TITEMS) {
#pragma unroll
                for (int r = 0; r < 4; ++r)
                    out[(size_t)(b0 + mw * 64 + i * 16 + rbase + r) * TITEMS + ii] = acc[i][j][r];
            }
        }
}

extern "C" void kernel_launch(void* const* d_in, const int* in_sizes, int n_in,
                              void* d_out, int out_size, void* d_ws, size_t ws_size,
                              hipStream_t stream) {
    const int*   seq        = (const int*)d_in[0];
    const int*   root       = (const int*)d_in[1];
    const int*   i2t_src    = (const int*)d_in[3];
    const int*   t2t_src    = (const int*)d_in[5];
    const int*   item_ids   = (const int*)d_in[6];
    const int*   tax_ids    = (const int*)d_in[7];
    const float* item_embed = (const float*)d_in[8];
    const float* tax_embed  = (const float*)d_in[9];
    const float* scb_ln_g   = (const float*)d_in[10];
    const float* scb_ln_b   = (const float*)d_in[11];
    const float* scb_w1     = (const float*)d_in[12];
    const float* scb_w2     = (const float*)d_in[13];
    const float* fcb_ln_g   = (const float*)d_in[14];
    const float* fcb_ln_b   = (const float*)d_in[15];
    const float* fcb_w1     = (const float*)d_in[16];
    const float* fcb_w2     = (const float*)d_in[17];
    const float* fcb_w3     = (const float*)d_in[18];
    const float* wv         = (const float*)d_in[19];
    const float* gi_w       = (const float*)d_in[20];
    const float* gi_al      = (const float*)d_in[21];
    const float* gi_ar      = (const float*)d_in[22];
    const float* gi_b       = (const float*)d_in[23];
    const float* gt_w       = (const float*)d_in[24];
    const float* gt_al      = (const float*)d_in[25];
    const float* gt_ar      = (const float*)d_in[26];
    const float* gt_b       = (const float*)d_in[27];
    const float* liw_g      = (const float*)d_in[28];
    const float* liw_b      = (const float*)d_in[29];
    const float* int_g      = (const float*)d_in[30];
    const float* int_b      = (const float*)d_in[31];
    const float* uni_w      = (const float*)d_in[32];

    char* w = (char*)d_ws;
    float* V     = (float*)(w + 0);           // 52.4MB (V / fs_i)
    float* NV    = (float*)(w + 52428800);    // 52.4MB (nv / item_h)
    float* FSI   = V;
    float* ITEMH = NV;
    // mixer-scb phase:
    unsigned short* NVT = (unsigned short*)(w + 104857600);  // 29.4MB
    unsigned short* T   = (unsigned short*)(w + 134217728);  // 33.6MB
    unsigned short* W1T = (unsigned short*)(w + 167772160);  // 229KB
    unsigned short* W2T = (unsigned short*)(w + 168001536);  // 213KB
    // mixer-fcb phase:
    unsigned short* ZB  = (unsigned short*)(w + 104857600);  // 26.2MB (aliases NVT, dead)
    // GAT phase:
    float* TAX0  = (float*)(w + 104857600);
    float* TAX1  = (float*)(w + 121634816);
    float* ACC   = (float*)(w + 138412032);
    float* FDI   = (float*)(w + 155189248);
    float* FST   = (float*)(w + 171966464);
    float* ELI   = (float*)(w + 188743680);
    float* ERI   = (float*)(w + 190382080);
    float* ELT   = (float*)(w + 190906368);
    float* ERT   = (float*)(w + 191430656);
    float* LOCAL = (float*)(w + 191954944);
    float* G     = (float*)(w + 200343552);
    float* MUL   = (float*)(w + 200605696);
    // final phase:
    unsigned short* EB = (unsigned short*)(w + 155189248);   // 25.6MB (aliases FDI+FST, dead)
    unsigned short* PB = (unsigned short*)(w + 200671232);   // 128KB
    if (ws_size < 200933376ull) return;

    // ---- global intention (mixer) ----
    k_gather<<<(TB * TL * 32 + 255) / 256, 256, 0, stream>>>(item_embed, seq, V, TB * TL);
    for (int nb = 0; nb < 2; ++nb) {
        k_ln<<<TB * TL / 8, 256, 0, stream>>>(V, NV, scb_ln_g + nb * TH, scb_ln_b + nb * TH);
        // scb via MFMA
        k_nvt<<<dim3(4, TB), 128, 0, stream>>>(NV, NVT);
        k_w1t<<<TSH, 256, 0, stream>>>(scb_w1 + nb * TL * TSH, W1T);
        k_w2t<<<208, 256, 0, stream>>>(scb_w2 + nb * TSH * TL, W2T);
        for (int bh = 0; bh < 2; ++bh) {
            k_mm1<<<dim3(4, 256), 256, 0, stream>>>(NVT, W1T, T, bh);
            k_mm2<<<dim3(4, 256), 256, 0, stream>>>(T, W2T, NV, V, bh);
        }
        // fcb via MFMA (fused 1+2, then 3)
        k_ln<<<TB * TL / 8, 256, 0, stream>>>(V, NV, fcb_ln_g + nb * TH, fcb_ln_b + nb * TH);
        k_ffuse<<<TB * TL * 4 / 64, 256, 0, stream>>>(NV, fcb_w1 + nb * TD * TFH,
                                                      fcb_w2 + nb * TFH * TD, ZB);
        k_f3m<<<TB * TL / 128, 256, 0, stream>>>(ZB, fcb_w3 + nb * TH * TH, NV, V);
    }
    k_pool<<<TB, 256, 0, stream>>>(V, wv, G);

    // ---- local intention (GAT) ----
    k_gather<<<(TNI * 32 + 255) / 256, 256, 0, stream>>>(item_embed, item_ids, ITEMH, TNI);
    k_gather<<<(TNT * 32 + 255) / 256, 256, 0, stream>>>(tax_embed, tax_ids, TAX0, TNT);

    float* cur = TAX0;
    float* nxt = TAX1;
    for (int hop = 0; hop < 2; ++hop) {
        const float* Wi = gi_w + hop * TH * TH;
        const float* Wt = gt_w + hop * TH * TH;
        k_gk128<<<TNI / 64, 256, 0, stream>>>(ITEMH, Wi, FSI, nullptr);
        k_gk128<<<TNT / 64, 256, 0, stream>>>(cur, Wi, FDI, nullptr);
        k_gk128<<<TNT / 64, 256, 0, stream>>>(cur, Wt, FST, nullptr);
        k_scores<<<(TNI * TNH + 255) / 256, 256, 0, stream>>>(FSI, gi_al + hop * TH, ELI, TNI);
        k_scores<<<(TNT * TNH + 255) / 256, 256, 0, stream>>>(FDI, gi_ar + hop * TH, ERI, TNT);
        k_scores<<<(TNT * TNH + 255) / 256, 256, 0, stream>>>(FST, gt_al + hop * TH, ELT, TNT);
        k_scores<<<(TNT * TNH + 255) / 256, 256, 0, stream>>>(FST, gt_ar + hop * TH, ERT, TNT);
        k_gat<<<TNT, 128, 0, stream>>>(cur, FSI, ELI, ERI, i2t_src, gi_b + hop * TH,
                                       FST, ELT, ERT, t2t_src, gt_b + hop * TH, nxt, ACC, hop);
        float* tmp = cur; cur = nxt; nxt = tmp;
    }

    // ---- fuse + final ----
    k_local<<<TB * TFT, 128, 0, stream>>>(root, ACC, G, LOCAL, MUL);
    k_fuse<<<TB, 128, 0, stream>>>(MUL, LOCAL, G, liw_g, liw_b, int_g, int_b, uni_w, PB);
    k_ebc<<<(TIPAD * TH / 8 + 255) / 256, 256, 0, stream>>>(item_embed, EB);
    k_final_m<<<dim3(TIPAD / 128, TB / 128), 256, 0, stream>>>(PB, EB, (float*)d_out);
}

// Round 8
// 1239.409 us; speedup vs baseline: 18.6242x; 1.0221x over previous
//
#include <hip/hip_runtime.h>
#include <hip/hip_bf16.h>

// ---- model dims ----
constexpr int TB = 512, TL = 200, TH = 128, TNH = 4, TD = 32;
constexpr int TFT = 32, TTP = 64, TIP = 200;
constexpr int TSH = 512, TFH = 256;
constexpr int TITEMS = 100001;
constexpr int TNT = TB * TTP;   // 32768
constexpr int TNI = TB * TIP;   // 102400
constexpr int TLP = 224;        // L padded (K of scb GEMM1)
constexpr int TIPAD = 100096;   // items padded to 128

typedef __attribute__((ext_vector_type(8))) short short8v;
typedef __attribute__((ext_vector_type(4))) float f32x4;

__device__ inline float gelu_exact(float x) {
    return 0.5f * x * (1.0f + erff(x * 0.7071067811865476f));
}
__device__ inline unsigned short to_bf16u(float x) {
    __hip_bfloat16 h = __float2bfloat16(x);
    return *reinterpret_cast<unsigned short*>(&h);
}
__device__ inline float bfu_to_f(unsigned short u) {
    unsigned int x = ((unsigned int)u) << 16;
    return __uint_as_float(x);
}

__device__ inline float block_reduce_sum(float v, float* red) {
    for (int o = 32; o > 0; o >>= 1) v += __shfl_down(v, o, 64);
    int nw = blockDim.x >> 6;
    if ((threadIdx.x & 63) == 0) red[threadIdx.x >> 6] = v;
    __syncthreads();
    float r = 0.f;
    for (int w = 0; w < nw; ++w) r += red[w];
    __syncthreads();
    return r;
}

__device__ inline float block_reduce_max(float v, float* red) {
    for (int o = 32; o > 0; o >>= 1) v = fmaxf(v, __shfl_down(v, o, 64));
    int nw = blockDim.x >> 6;
    if ((threadIdx.x & 63) == 0) red[threadIdx.x >> 6] = v;
    __syncthreads();
    float r = -INFINITY;
    for (int w = 0; w < nw; ++w) r = fmaxf(r, red[w]);
    __syncthreads();
    return r;
}

// out[r,:] = table[idx[r],:]  (f32)
__global__ __launch_bounds__(256) void k_gather(const float* __restrict__ tab,
                                                const int* __restrict__ idx,
                                                float* __restrict__ out, int nrows) {
    int e = blockIdx.x * blockDim.x + threadIdx.x;
    if (e >= nrows * 32) return;
    int r = e >> 5, c = e & 31;
    ((float4*)out)[e] = ((const float4*)tab)[(size_t)idx[r] * 32 + c];
}

// out[r,:] = bf16(table[idx[r],:])
__global__ __launch_bounds__(256) void k_gather_bf(const float* __restrict__ tab,
                                                   const int* __restrict__ idx,
                                                   unsigned short* __restrict__ out, int nrows) {
    int e = blockIdx.x * blockDim.x + threadIdx.x;
    if (e >= nrows * 16) return;
    int r = e >> 4, c = e & 15;
    const float4 a = ((const float4*)tab)[(size_t)idx[r] * 32 + c * 2];
    const float4 b = ((const float4*)tab)[(size_t)idx[r] * 32 + c * 2 + 1];
    uint4 u;
    u.x = (unsigned int)to_bf16u(a.x) | ((unsigned int)to_bf16u(a.y) << 16);
    u.y = (unsigned int)to_bf16u(a.z) | ((unsigned int)to_bf16u(a.w) << 16);
    u.z = (unsigned int)to_bf16u(b.x) | ((unsigned int)to_bf16u(b.y) << 16);
    u.w = (unsigned int)to_bf16u(b.z) | ((unsigned int)to_bf16u(b.w) << 16);
    *(uint4*)(out + (size_t)e * 8) = u;
}

// row-wise LayerNorm over H=128: 8 rows / 256-thread block
__global__ __launch_bounds__(256) void k_ln(const float* __restrict__ x, float* __restrict__ y,
                                            const float* __restrict__ g, const float* __restrict__ b) {
    int row = blockIdx.x * 8 + (threadIdx.x >> 5);
    int lane = threadIdx.x & 31;
    const float4 v = ((const float4*)(x + (size_t)row * TH))[lane];
    float s = v.x + v.y + v.z + v.w;
    for (int o = 16; o > 0; o >>= 1) s += __shfl_down(s, o, 32);
    float mean = __shfl(s, 0, 32) * (1.f / 128.f);
    float4 d;
    d.x = v.x - mean; d.y = v.y - mean; d.z = v.z - mean; d.w = v.w - mean;
    float q = d.x * d.x + d.y * d.y + d.z * d.z + d.w * d.w;
    for (int o = 16; o > 0; o >>= 1) q += __shfl_down(q, o, 32);
    float inv = rsqrtf(__shfl(q, 0, 32) * (1.f / 128.f) + 1e-8f);
    const float4 gg = ((const float4*)g)[lane];
    const float4 bb = ((const float4*)b)[lane];
    float4 o4;
    o4.x = d.x * inv * gg.x + bb.x;
    o4.y = d.y * inv * gg.y + bb.y;
    o4.z = d.z * inv * gg.z + bb.z;
    o4.w = d.w * inv * gg.w + bb.w;
    ((float4*)(y + (size_t)row * TH))[lane] = o4;
}

// NV[b][l][h] f32 -> NVT[b][h][lp] bf16 (l zero-padded to 224)
__global__ __launch_bounds__(128) void k_nvt(const float* __restrict__ NV,
                                             unsigned short* __restrict__ NVT) {
    __shared__ float tl[64][129];
    int b = blockIdx.y, l0 = blockIdx.x * 64, tid = threadIdx.x;
    for (int i = tid; i < 2048; i += 128) {
        int r = i >> 5, c = i & 31;
        int l = l0 + r;
        float4 v = {0.f, 0.f, 0.f, 0.f};
        if (l < TL) v = *(const float4*)(NV + ((size_t)b * TL + l) * TH + c * 4);
        tl[r][c * 4 + 0] = v.x; tl[r][c * 4 + 1] = v.y;
        tl[r][c * 4 + 2] = v.z; tl[r][c * 4 + 3] = v.w;
    }
    __syncthreads();
    int h = tid;
    int ng = (l0 + 64 > TLP) ? (TLP - l0) / 8 : 8;
    for (int lg = 0; lg < ng; ++lg) {
        uint4 u;
        unsigned int p[4];
#pragma unroll
        for (int q = 0; q < 4; ++q) {
            unsigned short ua = to_bf16u(tl[lg * 8 + q * 2 + 0][h]);
            unsigned short ub = to_bf16u(tl[lg * 8 + q * 2 + 1][h]);
            p[q] = (unsigned int)ua | ((unsigned int)ub << 16);
        }
        u.x = p[0]; u.y = p[1]; u.z = p[2]; u.w = p[3];
        *(uint4*)(NVT + ((size_t)b * TH + h) * TLP + l0 + lg * 8) = u;
    }
}

// w1[l][s] f32 -> W1T[s][lp] bf16
__global__ __launch_bounds__(256) void k_w1t(const float* __restrict__ w1,
                                             unsigned short* __restrict__ W1T) {
    int s = blockIdx.x, l = threadIdx.x;
    if (l >= TLP) return;
    float v = (l < TL) ? w1[(size_t)l * TSH + s] : 0.f;
    W1T[(size_t)s * TLP + l] = to_bf16u(v);
}

// w2[s][l] f32 -> W2T[lp208][s] bf16
__global__ __launch_bounds__(256) void k_w2t(const float* __restrict__ w2,
                                             unsigned short* __restrict__ W2T) {
    int l = blockIdx.x;
    for (int it = 0; it < 2; ++it) {
        int s = it * 256 + threadIdx.x;
        float v = (l < TL) ? w2[(size_t)s * TL + l] : 0.f;
        W2T[(size_t)l * TSH + s] = to_bf16u(v);
    }
}

// scb GEMM1: T[b][h][s] = gelu( sum_l NVT[b][h][l] * w1[l][s] )
__global__ __launch_bounds__(256) void k_mm1(const unsigned short* __restrict__ NVT,
                                             const unsigned short* __restrict__ W1T,
                                             unsigned short* __restrict__ T, int bh) {
    __shared__ unsigned short As[128][40];
    __shared__ unsigned short Bs[128][40];
    int tid = threadIdx.x;
    int b_local = blockIdx.y, b = bh * 256 + b_local;
    int s0 = blockIdx.x * 128;
    int lane = tid & 63, wid = tid >> 6;
    int mw = wid >> 1, nw = wid & 1;
    f32x4 acc[4][4];
#pragma unroll
    for (int i = 0; i < 4; ++i)
#pragma unroll
        for (int j = 0; j < 4; ++j) acc[i][j] = (f32x4){0.f, 0.f, 0.f, 0.f};
    const unsigned short* Abase = NVT + (size_t)b * TH * TLP;
    const unsigned short* Bbase = W1T + (size_t)s0 * TLP;
    for (int kc = 0; kc < 7; ++kc) {
        __syncthreads();
        for (int i = tid; i < 512; i += 256) {
            int r = i >> 2, q = i & 3;
            *(uint4*)&As[r][q * 8] = *(const uint4*)(Abase + (size_t)r * TLP + kc * 32 + q * 8);
            *(uint4*)&Bs[r][q * 8] = *(const uint4*)(Bbase + (size_t)r * TLP + kc * 32 + q * 8);
        }
        __syncthreads();
        int ko = (lane >> 4) * 8;
        short8v af[4], bfr[4];
#pragma unroll
        for (int t = 0; t < 4; ++t) {
            af[t] = *(const short8v*)&As[mw * 64 + t * 16 + (lane & 15)][ko];
            bfr[t] = *(const short8v*)&Bs[nw * 64 + t * 16 + (lane & 15)][ko];
        }
#pragma unroll
        for (int i = 0; i < 4; ++i)
#pragma unroll
            for (int j = 0; j < 4; ++j)
                acc[i][j] = __builtin_amdgcn_mfma_f32_16x16x32_bf16(af[i], bfr[j], acc[i][j], 0, 0, 0);
    }
    int rbase = (lane >> 4) * 4, col = lane & 15;
#pragma unroll
    for (int i = 0; i < 4; ++i)
#pragma unroll
        for (int j = 0; j < 4; ++j) {
            int h0 = mw * 64 + i * 16 + rbase;
            int s = s0 + nw * 64 + j * 16 + col;
#pragma unroll
            for (int r = 0; r < 4; ++r)
                T[((size_t)b_local * TH + h0 + r) * TSH + s] = to_bf16u(gelu_exact(acc[i][j][r]));
        }
}

// scb GEMM2: VS[b][l][h] = NV[b][l][h] + sum_s T[b][h][s] * w2[s][l]
__global__ __launch_bounds__(256) void k_mm2(const unsigned short* __restrict__ T,
                                             const unsigned short* __restrict__ W2T,
                                             const float* __restrict__ NV,
                                             float* __restrict__ VS, int bh) {
    __shared__ unsigned short As[128][40];
    __shared__ unsigned short Bs[64][40];
    int tid = threadIdx.x;
    int b_local = blockIdx.y, b = bh * 256 + b_local;
    int l0 = blockIdx.x * 64;
    int lane = tid & 63, wid = tid >> 6;
    f32x4 acc[2][4];
#pragma unroll
    for (int i = 0; i < 2; ++i)
#pragma unroll
        for (int j = 0; j < 4; ++j) acc[i][j] = (f32x4){0.f, 0.f, 0.f, 0.f};
    const unsigned short* Abase = T + (size_t)b_local * TH * TSH;
    for (int kc = 0; kc < 16; ++kc) {
        __syncthreads();
        for (int i = tid; i < 512; i += 256) {
            int r = i >> 2, q = i & 3;
            *(uint4*)&As[r][q * 8] = *(const uint4*)(Abase + (size_t)r * TSH + kc * 32 + q * 8);
        }
        {
            int r = tid >> 2, q = tid & 3;
            int l = l0 + r;
            uint4 v = {0u, 0u, 0u, 0u};
            if (l < 208) v = *(const uint4*)(W2T + (size_t)l * TSH + kc * 32 + q * 8);
            *(uint4*)&Bs[r][q * 8] = v;
        }
        __syncthreads();
        int ko = (lane >> 4) * 8;
        short8v af[2], bfr[4];
#pragma unroll
        for (int t = 0; t < 2; ++t)
            af[t] = *(const short8v*)&As[wid * 32 + t * 16 + (lane & 15)][ko];
#pragma unroll
        for (int j = 0; j < 4; ++j)
            bfr[j] = *(const short8v*)&Bs[j * 16 + (lane & 15)][ko];
#pragma unroll
        for (int i = 0; i < 2; ++i)
#pragma unroll
            for (int j = 0; j < 4; ++j)
                acc[i][j] = __builtin_amdgcn_mfma_f32_16x16x32_bf16(af[i], bfr[j], acc[i][j], 0, 0, 0);
    }
    int rbase = (lane >> 4) * 4, col = lane & 15;
#pragma unroll
    for (int i = 0; i < 2; ++i)
#pragma unroll
        for (int j = 0; j < 4; ++j) {
            int l = l0 + j * 16 + col;
            if (l < TL) {
                int h0 = wid * 32 + i * 16 + rbase;
                size_t off = ((size_t)b * TL + l) * TH + h0;
                const float4 res = *(const float4*)(NV + off);
                float4 o;
                o.x = acc[i][j][0] + res.x;
                o.y = acc[i][j][1] + res.y;
                o.z = acc[i][j][2] + res.z;
                o.w = acc[i][j][3] + res.w;
                *(float4*)(VS + off) = o;
            }
        }
}

// fused fcb stage1+2; Yl XOR-swizzled; Bs2 aliases Bs1
__global__ __launch_bounds__(256) void k_ffuse(const float* __restrict__ NV,
                                               const float* __restrict__ W1,
                                               const float* __restrict__ W2,
                                               unsigned short* __restrict__ Z) {
    __shared__ unsigned short As[64][40];
    __shared__ unsigned short BsBuf[256 * 40];     // f1: Bs1[256][40]; f2: Bs2[32][264]
    __shared__ unsigned short Yl[64 * 264];
    int tid = threadIdx.x;
    int m0 = blockIdx.x * 64;   // rows-of-32
    int lane = tid & 63, wid = tid >> 6;
    // stage A (64 x 32, f32 -> bf16)
    for (int i = tid; i < 512; i += 256) {
        int r = i >> 3, q = i & 7;
        const float4 v = *(const float4*)(NV + (size_t)(m0 + r) * 32 + q * 4);
        ushort4 u;
        u.x = to_bf16u(v.x); u.y = to_bf16u(v.y); u.z = to_bf16u(v.z); u.w = to_bf16u(v.w);
        *(ushort4*)&As[r][q * 4] = u;
    }
    // stage B1: W1[32][256] -> Bs1[n][k] (stride 40)
    for (int i = tid; i < 2048; i += 256) {
        int k = i & 31, c4 = i >> 5;
        const float4 v = *(const float4*)(W1 + (size_t)k * TFH + c4 * 4);
        BsBuf[(c4 * 4 + 0) * 40 + k] = to_bf16u(v.x);
        BsBuf[(c4 * 4 + 1) * 40 + k] = to_bf16u(v.y);
        BsBuf[(c4 * 4 + 2) * 40 + k] = to_bf16u(v.z);
        BsBuf[(c4 * 4 + 3) * 40 + k] = to_bf16u(v.w);
    }
    __syncthreads();
    // f1 fragment loads (Bs1 dead after this)
    int ko = (lane >> 4) * 8;
    short8v af[4], bfr[4];
#pragma unroll
    for (int t = 0; t < 4; ++t) {
        af[t] = *(const short8v*)&As[t * 16 + (lane & 15)][ko];
        bfr[t] = *(const short8v*)&BsBuf[(wid * 64 + t * 16 + (lane & 15)) * 40 + ko];
    }
    __syncthreads();
    // f1 MFMA + gelu + swizzled Yl store
    {
        f32x4 acc[4][4];
#pragma unroll
        for (int i = 0; i < 4; ++i)
#pragma unroll
            for (int j = 0; j < 4; ++j) acc[i][j] = (f32x4){0.f, 0.f, 0.f, 0.f};
#pragma unroll
        for (int i = 0; i < 4; ++i)
#pragma unroll
            for (int j = 0; j < 4; ++j)
                acc[i][j] = __builtin_amdgcn_mfma_f32_16x16x32_bf16(af[i], bfr[j], acc[i][j], 0, 0, 0);
        int rbase = (lane >> 4) * 4, col = lane & 15;
#pragma unroll
        for (int i = 0; i < 4; ++i)
#pragma unroll
            for (int j = 0; j < 4; ++j)
#pragma unroll
                for (int r = 0; r < 4; ++r) {
                    int m = i * 16 + rbase + r;
                    int n = wid * 64 + j * 16 + col;
                    int idx = (m * 264 + n) ^ (((m >> 2) & 7) << 3);
                    Yl[idx] = to_bf16u(gelu_exact(acc[i][j][r]));
                }
    }
    // stage B2: W2[256][32] -> Bs2[n'=32][k=256] (stride 264), aliases Bs1
    for (int i = tid; i < 2048; i += 256) {
        int f = i >> 3, c4 = i & 7;
        const float4 v = *(const float4*)(W2 + (size_t)f * TD + c4 * 4);
        BsBuf[(c4 * 4 + 0) * 264 + f] = to_bf16u(v.x);
        BsBuf[(c4 * 4 + 1) * 264 + f] = to_bf16u(v.y);
        BsBuf[(c4 * 4 + 2) * 264 + f] = to_bf16u(v.z);
        BsBuf[(c4 * 4 + 3) * 264 + f] = to_bf16u(v.w);
    }
    __syncthreads();
    // f2: Z[m][n'] = Y @ W2, K=256
    {
        f32x4 acc2[2];
        acc2[0] = (f32x4){0.f, 0.f, 0.f, 0.f};
        acc2[1] = (f32x4){0.f, 0.f, 0.f, 0.f};
        int mrow = wid * 16 + (lane & 15);
        int sw = ((mrow >> 2) & 7) << 3;
        for (int kc = 0; kc < 8; ++kc) {
            int ko2 = kc * 32 + (lane >> 4) * 8;
            short8v a2 = *(const short8v*)&Yl[(mrow * 264 + ko2) ^ sw];
            short8v b0 = *(const short8v*)&BsBuf[(lane & 15) * 264 + ko2];
            short8v b1 = *(const short8v*)&BsBuf[(16 + (lane & 15)) * 264 + ko2];
            acc2[0] = __builtin_amdgcn_mfma_f32_16x16x32_bf16(a2, b0, acc2[0], 0, 0, 0);
            acc2[1] = __builtin_amdgcn_mfma_f32_16x16x32_bf16(a2, b1, acc2[1], 0, 0, 0);
        }
        int rbase = (lane >> 4) * 4, col = lane & 15;
#pragma unroll
        for (int j = 0; j < 2; ++j)
#pragma unroll
            for (int r = 0; r < 4; ++r)
                Z[(size_t)(m0 + wid * 16 + rbase + r) * 32 + j * 16 + col] =
                    to_bf16u(acc2[j][r]);
    }
}

// generic: C[N,128] = A[N,128](bf16) @ W[128,128](f32) (+R f32); N multiple of 128
__global__ __launch_bounds__(256) void k_gmm(const unsigned short* __restrict__ A,
                                             const float* __restrict__ W,
                                             const float* __restrict__ R,
                                             float* __restrict__ C) {
    __shared__ unsigned short As[128][40];
    __shared__ unsigned short Bs[128][40];
    int tid = threadIdx.x;
    int m0 = blockIdx.x * 128;
    int lane = tid & 63, wid = tid >> 6;
    int mw = wid >> 1, nw = wid & 1;
    f32x4 acc[4][4];
#pragma unroll
    for (int i = 0; i < 4; ++i)
#pragma unroll
        for (int j = 0; j < 4; ++j) acc[i][j] = (f32x4){0.f, 0.f, 0.f, 0.f};
    for (int kc = 0; kc < 4; ++kc) {
        __syncthreads();
        for (int i = tid; i < 512; i += 256) {
            int r = i >> 2, q = i & 3;
            *(uint4*)&As[r][q * 8] = *(const uint4*)(A + (size_t)(m0 + r) * TH + kc * 32 + q * 8);
        }
        for (int i = tid; i < 1024; i += 256) {
            int kk = i & 31, c4 = i >> 5;
            const float4 v = *(const float4*)(W + (size_t)(kc * 32 + kk) * TH + c4 * 4);
            Bs[c4 * 4 + 0][kk] = to_bf16u(v.x);
            Bs[c4 * 4 + 1][kk] = to_bf16u(v.y);
            Bs[c4 * 4 + 2][kk] = to_bf16u(v.z);
            Bs[c4 * 4 + 3][kk] = to_bf16u(v.w);
        }
        __syncthreads();
        int ko = (lane >> 4) * 8;
        short8v af[4], bfr[4];
#pragma unroll
        for (int t = 0; t < 4; ++t) {
            af[t] = *(const short8v*)&As[mw * 64 + t * 16 + (lane & 15)][ko];
            bfr[t] = *(const short8v*)&Bs[nw * 64 + t * 16 + (lane & 15)][ko];
        }
#pragma unroll
        for (int i = 0; i < 4; ++i)
#pragma unroll
            for (int j = 0; j < 4; ++j)
                acc[i][j] = __builtin_amdgcn_mfma_f32_16x16x32_bf16(af[i], bfr[j], acc[i][j], 0, 0, 0);
    }
    int rbase = (lane >> 4) * 4, col = lane & 15;
#pragma unroll
    for (int i = 0; i < 4; ++i)
#pragma unroll
        for (int j = 0; j < 4; ++j) {
            int n = nw * 64 + j * 16 + col;
#pragma unroll
            for (int r = 0; r < 4; ++r) {
                size_t off = (size_t)(m0 + mw * 64 + i * 16 + rbase + r) * TH + n;
                float v = acc[i][j][r];
                if (R) v += R[off];
                C[off] = v;
            }
        }
}

// alpha = softmax(V@wv over L); g = sum_l alpha*V
__global__ __launch_bounds__(256) void k_pool(const float* __restrict__ V, const float* __restrict__ wv,
                                              float* __restrict__ g) {
    __shared__ float sc[TL];
    __shared__ float red[4];
    int b = blockIdx.x, tid = threadIdx.x;
    if (tid < TL) {
        float a = 0.f;
        const float* vp = V + (size_t)(b * TL + tid) * TH;
        for (int h = 0; h < TH; ++h) a += vp[h] * wv[h];
        sc[tid] = a;
    }
    __syncthreads();
    float m = (tid < TL) ? sc[tid] : -INFINITY;
    m = block_reduce_max(m, red);
    float e = (tid < TL) ? expf(sc[tid] - m) : 0.f;
    float s = block_reduce_sum(e, red);
    if (tid < TL) sc[tid] = e / s;
    __syncthreads();
    if (tid < TH) {
        float a = 0.f;
        for (int l = 0; l < TL; ++l) a += sc[l] * V[(size_t)(b * TL + l) * TH + tid];
        g[b * TH + tid] = a;
    }
}

// out[n,k] = sum_d f[n, k*32+d] * vec[k*32+d]
__global__ __launch_bounds__(256) void k_scores(const float* __restrict__ f, const float* __restrict__ vec,
                                                float* __restrict__ out, int n) {
    int idx = blockIdx.x * blockDim.x + threadIdx.x;
    if (idx >= n * TNH) return;
    int node = idx >> 2, k = idx & 3;
    const float* fp = f + (size_t)node * TH + k * TD;
    const float* vp = vec + k * TD;
    float a = 0.f;
#pragma unroll
    for (int d = 0; d < TD; ++d) a += fp[d] * vp[d];
    out[idx] = a;
}

// fused per-dst-node GAT; cur bf16 in, nxt bf16 out, ACC f32
__global__ __launch_bounds__(128) void k_gat(const unsigned short* __restrict__ tax_cur,
                                             const float* __restrict__ fs_i, const float* __restrict__ el_i,
                                             const float* __restrict__ er_i, const int* __restrict__ src_i,
                                             const float* __restrict__ bi,
                                             const float* __restrict__ fs_t, const float* __restrict__ el_t,
                                             const float* __restrict__ er_t, const int* __restrict__ src_t,
                                             const float* __restrict__ bt,
                                             unsigned short* __restrict__ tax_nxt,
                                             float* __restrict__ acc, int hop) {
    int n = blockIdx.x, h = threadIdx.x, k = h >> 5;
    float cur = bfu_to_f(tax_cur[(size_t)n * TH + h]);
    float ti, tt2;
    {
        float er = er_i[n * 4 + k];
        int s[4]; float e[4]; float m = -INFINITY;
#pragma unroll
        for (int j = 0; j < 4; ++j) {
            s[j] = src_i[n * 4 + j];
            float xx = el_i[s[j] * 4 + k] + er;
            e[j] = xx > 0.f ? xx : 0.2f * xx;
            m = fmaxf(m, e[j]);
        }
        float ssum = 0.f, av = 0.f;
#pragma unroll
        for (int j = 0; j < 4; ++j) {
            float a = expf(e[j] - m);
            ssum += a;
            av += a * fs_i[(size_t)s[j] * TH + h];
        }
        ti = fmaxf(av / ssum + cur + bi[h], 0.f);
    }
    {
        float er = er_t[n * 4 + k];
        int s[2]; float e[2]; float m = -INFINITY;
#pragma unroll
        for (int j = 0; j < 2; ++j) {
            s[j] = src_t[n * 2 + j];
            float xx = el_t[s[j] * 4 + k] + er;
            e[j] = xx > 0.f ? xx : 0.2f * xx;
            m = fmaxf(m, e[j]);
        }
        float ssum = 0.f, av = 0.f;
#pragma unroll
        for (int j = 0; j < 2; ++j) {
            float a = expf(e[j] - m);
            ssum += a;
            av += a * fs_t[(size_t)s[j] * TH + h];
        }
        tt2 = fmaxf(av / ssum + cur + bt[h], 0.f);
    }
    float nx = ti + tt2;
    size_t ai = (size_t)n * TH + h;
    tax_nxt[ai] = to_bf16u(nx);
    acc[ai] = (hop == 0) ? nx : acc[ai] + nx;
}

// local + mul
__global__ __launch_bounds__(128) void k_local(const int* __restrict__ root, const float* __restrict__ acc,
                                               const float* __restrict__ g, float* __restrict__ local,
                                               float* __restrict__ mul) {
    __shared__ float red[2];
    int bf = blockIdx.x, b = bf >> 5;
    int h = threadIdx.x;
    int r = root[bf];
    float v = 0.f;
    if (r != -1) {
        int rc = r < 0 ? 0 : r;
        v = acc[(size_t)(b * TTP + rc) * TH + h] * 0.5f;
    }
    local[(size_t)bf * TH + h] = v;
    float s = block_reduce_sum(v * g[b * TH + h], red);
    if (h == 0) mul[bf] = s;
}

// per-b fuse; writes PB[b][h] bf16
__global__ __launch_bounds__(128) void k_fuse(const float* __restrict__ mul, const float* __restrict__ local,
                                              const float* __restrict__ g,
                                              const float* __restrict__ liw_g, const float* __restrict__ liw_b,
                                              const float* __restrict__ int_g, const float* __restrict__ int_b,
                                              const float* __restrict__ uni_w, unsigned short* __restrict__ PB) {
    __shared__ float lm[TFT], wv_[TFT], inten[TH];
    __shared__ float red[2];
    int b = blockIdx.x, tid = threadIdx.x;
    if (tid < TFT) lm[tid] = mul[b * TFT + tid];
    __syncthreads();
    if (tid < TFT) {
        float mean = 0.f;
        for (int f = 0; f < TFT; ++f) mean += lm[f];
        mean *= (1.f / TFT);
        float var = 0.f;
        for (int f = 0; f < TFT; ++f) { float d = lm[f] - mean; var += d * d; }
        var *= (1.f / TFT);
        float ln = (lm[tid] - mean) * rsqrtf(var + 1e-8f) * liw_g[tid] + liw_b[tid];
        wv_[tid] = (lm[tid] != 0.f) ? ln : -INFINITY;
    }
    __syncthreads();
    if (tid < TFT) {
        float mx = -INFINITY;
        for (int f = 0; f < TFT; ++f) mx = fmaxf(mx, wv_[f]);
        float s = 0.f;
        for (int f = 0; f < TFT; ++f) s += expf(wv_[f] - mx);
        lm[tid] = expf(wv_[tid] - mx) / s;
    }
    __syncthreads();
    float ip = g[b * TH + tid];
    for (int f = 0; f < TFT; ++f) ip += lm[f] * local[(size_t)(b * TFT + f) * TH + tid];
    float mean = block_reduce_sum(ip, red) * (1.f / TH);
    float d = ip - mean;
    float var = block_reduce_sum(d * d, red) * (1.f / TH);
    inten[tid] = d * rsqrtf(var + 1e-8f) * int_g[tid] + int_b[tid];
    __syncthreads();
    float a = 0.f;
    for (int hp = 0; hp < TH; ++hp) a += inten[hp] * uni_w[hp * TH + tid];
    PB[(size_t)b * TH + tid] = to_bf16u(a);
}

// E f32 -> EB bf16, rows padded to TIPAD
__global__ __launch_bounds__(256) void k_ebc(const float* __restrict__ E,
                                             unsigned short* __restrict__ EB) {
    int t = blockIdx.x * 256 + threadIdx.x;
    if (t >= TIPAD * TH / 8) return;
    size_t base = (size_t)t * 8;
    int row = (int)(base >> 7);
    float4 a = {0.f, 0.f, 0.f, 0.f}, b = {0.f, 0.f, 0.f, 0.f};
    if (row < TITEMS) {
        a = *(const float4*)(E + base);
        b = *(const float4*)(E + base + 4);
    }
    ushort4 u0, u1;
    u0.x = to_bf16u(a.x); u0.y = to_bf16u(a.y); u0.z = to_bf16u(a.z); u0.w = to_bf16u(a.w);
    u1.x = to_bf16u(b.x); u1.y = to_bf16u(b.y); u1.z = to_bf16u(b.z); u1.w = to_bf16u(b.w);
    *(ushort4*)(EB + base) = u0;
    *(ushort4*)(EB + base + 4) = u1;
}

// out[b,i] = PB[b,:] . EB[i,:]  (bf16 MFMA, 128b x 128i tile)
__global__ __launch_bounds__(256) void k_final_m(const unsigned short* __restrict__ PB,
                                                 const unsigned short* __restrict__ EB,
                                                 float* __restrict__ out) {
    __shared__ unsigned short As[128][136];
    __shared__ unsigned short Bs[128][136];
    int tid = threadIdx.x;
    int i0 = blockIdx.x * 128, b0 = blockIdx.y * 128;
    for (int i = tid; i < 2048; i += 256) {
        int r = i >> 4, q = i & 15;
        *(uint4*)&As[r][q * 8] = *(const uint4*)(PB + (size_t)(b0 + r) * TH + q * 8);
    }
    for (int i = tid; i < 2048; i += 256) {
        int r = i >> 4, q = i & 15;
        *(uint4*)&Bs[r][q * 8] = *(const uint4*)(EB + (size_t)(i0 + r) * TH + q * 8);
    }
    __syncthreads();
    int lane = tid & 63, wid = tid >> 6;
    int mw = wid >> 1, nw = wid & 1;
    f32x4 acc[4][4];
#pragma unroll
    for (int i = 0; i < 4; ++i)
#pragma unroll
        for (int j = 0; j < 4; ++j) acc[i][j] = (f32x4){0.f, 0.f, 0.f, 0.f};
#pragma unroll
    for (int kc = 0; kc < 4; ++kc) {
        int ko = kc * 32 + (lane >> 4) * 8;
        short8v af[4], bfr[4];
#pragma unroll
        for (int t = 0; t < 4; ++t) {
            af[t] = *(const short8v*)&As[mw * 64 + t * 16 + (lane & 15)][ko];
            bfr[t] = *(const short8v*)&Bs[nw * 64 + t * 16 + (lane & 15)][ko];
        }
#pragma unroll
        for (int i = 0; i < 4; ++i)
#pragma unroll
            for (int j = 0; j < 4; ++j)
                acc[i][j] = __builtin_amdgcn_mfma_f32_16x16x32_bf16(af[i], bfr[j], acc[i][j], 0, 0, 0);
    }
    int rbase = (lane >> 4) * 4, col = lane & 15;
#pragma unroll
    for (int i = 0; i < 4; ++i)
#pragma unroll
        for (int j = 0; j < 4; ++j) {
            int ii = i0 + nw * 64 + j * 16 + col;
            if (ii < TITEMS) {
#pragma unroll
                for (int r = 0; r < 4; ++r)
                    out[(size_t)(b0 + mw * 64 + i * 16 + rbase + r) * TITEMS + ii] = acc[i][j][r];
            }
        }
}

extern "C" void kernel_launch(void* const* d_in, const int* in_sizes, int n_in,
                              void* d_out, int out_size, void* d_ws, size_t ws_size,
                              hipStream_t stream) {
    const int*   seq        = (const int*)d_in[0];
    const int*   root       = (const int*)d_in[1];
    const int*   i2t_src    = (const int*)d_in[3];
    const int*   t2t_src    = (const int*)d_in[5];
    const int*   item_ids   = (const int*)d_in[6];
    const int*   tax_ids    = (const int*)d_in[7];
    const float* item_embed = (const float*)d_in[8];
    const float* tax_embed  = (const float*)d_in[9];
    const float* scb_ln_g   = (const float*)d_in[10];
    const float* scb_ln_b   = (const float*)d_in[11];
    const float* scb_w1     = (const float*)d_in[12];
    const float* scb_w2     = (const float*)d_in[13];
    const float* fcb_ln_g   = (const float*)d_in[14];
    const float* fcb_ln_b   = (const float*)d_in[15];
    const float* fcb_w1     = (const float*)d_in[16];
    const float* fcb_w2     = (const float*)d_in[17];
    const float* fcb_w3     = (const float*)d_in[18];
    const float* wv         = (const float*)d_in[19];
    const float* gi_w       = (const float*)d_in[20];
    const float* gi_al      = (const float*)d_in[21];
    const float* gi_ar      = (const float*)d_in[22];
    const float* gi_b       = (const float*)d_in[23];
    const float* gt_w       = (const float*)d_in[24];
    const float* gt_al      = (const float*)d_in[25];
    const float* gt_ar      = (const float*)d_in[26];
    const float* gt_b       = (const float*)d_in[27];
    const float* liw_g      = (const float*)d_in[28];
    const float* liw_b      = (const float*)d_in[29];
    const float* int_g      = (const float*)d_in[30];
    const float* int_b      = (const float*)d_in[31];
    const float* uni_w      = (const float*)d_in[32];

    char* w = (char*)d_ws;
    float* V     = (float*)(w + 0);           // 52.4MB (V / fs_i)
    float* NV    = (float*)(w + 52428800);    // 52.4MB (nv / ITEMHB)
    float* FSI   = V;
    unsigned short* ITEMHB = (unsigned short*)(w + 52428800);  // 26.2MB bf16 (GAT phase)
    // mixer-scb phase:
    unsigned short* NVT = (unsigned short*)(w + 104857600);  // 29.4MB
    unsigned short* T   = (unsigned short*)(w + 134217728);  // 33.6MB
    unsigned short* W1T = (unsigned short*)(w + 167772160);  // 229KB
    unsigned short* W2T = (unsigned short*)(w + 168001536);  // 213KB
    // mixer-fcb phase:
    unsigned short* ZB  = (unsigned short*)(w + 104857600);  // 26.2MB
    // GAT phase:
    unsigned short* TAXB0 = (unsigned short*)(w + 104857600); // 8.4MB bf16
    unsigned short* TAXB1 = (unsigned short*)(w + 113246208); // 8.4MB bf16
    float* ACC   = (float*)(w + 138412032);
    float* FDI   = (float*)(w + 155189248);
    float* FST   = (float*)(w + 171966464);
    float* ELI   = (float*)(w + 188743680);
    float* ERI   = (float*)(w + 190382080);
    float* ELT   = (float*)(w + 190906368);
    float* ERT   = (float*)(w + 191430656);
    float* LOCAL = (float*)(w + 191954944);
    float* G     = (float*)(w + 200343552);
    float* MUL   = (float*)(w + 200605696);
    // final phase:
    unsigned short* EB = (unsigned short*)(w + 155189248);   // 25.6MB (aliases FDI+FST)
    unsigned short* PB = (unsigned short*)(w + 200671232);   // 128KB
    if (ws_size < 200933376ull) return;

    // ---- global intention (mixer) ----
    k_gather<<<(TB * TL * 32 + 255) / 256, 256, 0, stream>>>(item_embed, seq, V, TB * TL);
    for (int nb = 0; nb < 2; ++nb) {
        k_ln<<<TB * TL / 8, 256, 0, stream>>>(V, NV, scb_ln_g + nb * TH, scb_ln_b + nb * TH);
        // scb via MFMA
        k_nvt<<<dim3(4, TB), 128, 0, stream>>>(NV, NVT);
        k_w1t<<<TSH, 256, 0, stream>>>(scb_w1 + nb * TL * TSH, W1T);
        k_w2t<<<208, 256, 0, stream>>>(scb_w2 + nb * TSH * TL, W2T);
        for (int bh = 0; bh < 2; ++bh) {
            k_mm1<<<dim3(4, 256), 256, 0, stream>>>(NVT, W1T, T, bh);
            k_mm2<<<dim3(4, 256), 256, 0, stream>>>(T, W2T, NV, V, bh);
        }
        // fcb via MFMA
        k_ln<<<TB * TL / 8, 256, 0, stream>>>(V, NV, fcb_ln_g + nb * TH, fcb_ln_b + nb * TH);
        k_ffuse<<<TB * TL * 4 / 64, 256, 0, stream>>>(NV, fcb_w1 + nb * TD * TFH,
                                                      fcb_w2 + nb * TFH * TD, ZB);
        k_gmm<<<TB * TL / 128, 256, 0, stream>>>(ZB, fcb_w3 + nb * TH * TH, NV, V);
    }
    k_pool<<<TB, 256, 0, stream>>>(V, wv, G);

    // ---- local intention (GAT, bf16 features) ----
    k_gather_bf<<<(TNI * 16 + 255) / 256, 256, 0, stream>>>(item_embed, item_ids, ITEMHB, TNI);
    k_gather_bf<<<(TNT * 16 + 255) / 256, 256, 0, stream>>>(tax_embed, tax_ids, TAXB0, TNT);

    unsigned short* curb = TAXB0;
    unsigned short* nxtb = TAXB1;
    for (int hop = 0; hop < 2; ++hop) {
        const float* Wi = gi_w + hop * TH * TH;
        const float* Wt = gt_w + hop * TH * TH;
        k_gmm<<<TNI / 128, 256, 0, stream>>>(ITEMHB, Wi, nullptr, FSI);
        k_gmm<<<TNT / 128, 256, 0, stream>>>(curb, Wi, nullptr, FDI);
        k_gmm<<<TNT / 128, 256, 0, stream>>>(curb, Wt, nullptr, FST);
        k_scores<<<(TNI * TNH + 255) / 256, 256, 0, stream>>>(FSI, gi_al + hop * TH, ELI, TNI);
        k_scores<<<(TNT * TNH + 255) / 256, 256, 0, stream>>>(FDI, gi_ar + hop * TH, ERI, TNT);
        k_scores<<<(TNT * TNH + 255) / 256, 256, 0, stream>>>(FST, gt_al + hop * TH, ELT, TNT);
        k_scores<<<(TNT * TNH + 255) / 256, 256, 0, stream>>>(FST, gt_ar + hop * TH, ERT, TNT);
        k_gat<<<TNT, 128, 0, stream>>>(curb, FSI, ELI, ERI, i2t_src, gi_b + hop * TH,
                                       FST, ELT, ERT, t2t_src, gt_b + hop * TH, nxtb, ACC, hop);
        unsigned short* tmp = curb; curb = nxtb; nxtb = tmp;
    }

    // ---- fuse + final ----
    k_local<<<TB * TFT, 128, 0, stream>>>(root, ACC, G, LOCAL, MUL);
    k_fuse<<<TB, 128, 0, stream>>>(MUL, LOCAL, G, liw_g, liw_b, int_g, int_b, uni_w, PB);
    k_ebc<<<(TIPAD * TH / 8 + 255) / 256, 256, 0, stream>>>(item_embed, EB);
    k_final_m<<<dim3(TIPAD / 128, TB / 128), 256, 0, stream>>>(PB, EB, (float*)d_out);
}

// Round 9
// 1029.706 us; speedup vs baseline: 22.4171x; 1.2037x over previous
//
#include <hip/hip_runtime.h>
#include <hip/hip_bf16.h>

// ---- model dims ----
constexpr int TB = 512, TL = 200, TH = 128, TNH = 4, TD = 32;
constexpr int TFT = 32, TTP = 64, TIP = 200;
constexpr int TSH = 512, TFH = 256;
constexpr int TITEMS = 100001;
constexpr int TNT = TB * TTP;   // 32768
constexpr int TNI = TB * TIP;   // 102400
constexpr int TLP = 224;        // L padded (K of scb GEMM1)
constexpr int TIPAD = 100096;   // items padded to 128

typedef __attribute__((ext_vector_type(8))) short short8v;
typedef __attribute__((ext_vector_type(4))) float f32x4;

__device__ inline float gelu_exact(float x) {
    return 0.5f * x * (1.0f + erff(x * 0.7071067811865476f));
}
// tanh-form gelu, |err| <= ~3e-4 (below bf16 quantization of the result)
__device__ inline float gelu_fast(float x) {
    float u = x + 0.044715f * x * x * x;
    float e = exp2f(-2.302208f * u);   // exp(-2*0.79788456*u)
    return x / (1.0f + e);
}
__device__ inline unsigned short to_bf16u(float x) {
    __hip_bfloat16 h = __float2bfloat16(x);
    return *reinterpret_cast<unsigned short*>(&h);
}
__device__ inline float bfu_to_f(unsigned short u) {
    unsigned int x = ((unsigned int)u) << 16;
    return __uint_as_float(x);
}

__device__ inline float block_reduce_sum(float v, float* red) {
    for (int o = 32; o > 0; o >>= 1) v += __shfl_down(v, o, 64);
    int nw = blockDim.x >> 6;
    if ((threadIdx.x & 63) == 0) red[threadIdx.x >> 6] = v;
    __syncthreads();
    float r = 0.f;
    for (int w = 0; w < nw; ++w) r += red[w];
    __syncthreads();
    return r;
}

__device__ inline float block_reduce_max(float v, float* red) {
    for (int o = 32; o > 0; o >>= 1) v = fmaxf(v, __shfl_down(v, o, 64));
    int nw = blockDim.x >> 6;
    if ((threadIdx.x & 63) == 0) red[threadIdx.x >> 6] = v;
    __syncthreads();
    float r = -INFINITY;
    for (int w = 0; w < nw; ++w) r = fmaxf(r, red[w]);
    __syncthreads();
    return r;
}

// out[r,:] = table[idx[r],:]  (f32)
__global__ __launch_bounds__(256) void k_gather(const float* __restrict__ tab,
                                                const int* __restrict__ idx,
                                                float* __restrict__ out, int nrows) {
    int e = blockIdx.x * blockDim.x + threadIdx.x;
    if (e >= nrows * 32) return;
    int r = e >> 5, c = e & 31;
    ((float4*)out)[e] = ((const float4*)tab)[(size_t)idx[r] * 32 + c];
}

// out[r,:] = bf16(table[idx[r],:])
__global__ __launch_bounds__(256) void k_gather_bf(const float* __restrict__ tab,
                                                   const int* __restrict__ idx,
                                                   unsigned short* __restrict__ out, int nrows) {
    int e = blockIdx.x * blockDim.x + threadIdx.x;
    if (e >= nrows * 16) return;
    int r = e >> 4, c = e & 15;
    const float4 a = ((const float4*)tab)[(size_t)idx[r] * 32 + c * 2];
    const float4 b = ((const float4*)tab)[(size_t)idx[r] * 32 + c * 2 + 1];
    uint4 u;
    u.x = (unsigned int)to_bf16u(a.x) | ((unsigned int)to_bf16u(a.y) << 16);
    u.y = (unsigned int)to_bf16u(a.z) | ((unsigned int)to_bf16u(a.w) << 16);
    u.z = (unsigned int)to_bf16u(b.x) | ((unsigned int)to_bf16u(b.y) << 16);
    u.w = (unsigned int)to_bf16u(b.z) | ((unsigned int)to_bf16u(b.w) << 16);
    *(uint4*)(out + (size_t)e * 8) = u;
}

// one-time conversion of small weights to bf16, pre-transposed to [n][k]
__global__ __launch_bounds__(256) void k_wcvt(const float* __restrict__ fw1, const float* __restrict__ fw2,
                                              const float* __restrict__ fw3, const float* __restrict__ giw,
                                              const float* __restrict__ gtw, unsigned short* __restrict__ WB) {
    int idx = blockIdx.x * 256 + threadIdx.x;  // 0..131071
    float v;
    if (idx < 16384) {           // fw1b[nb][n=256][k=32]
        int nb = idx >> 13, r = idx & 8191, n = r >> 5, k = r & 31;
        v = fw1[(size_t)nb * 8192 + k * 256 + n];
    } else if (idx < 32768) {    // fw2b[nb][n=32][k=256]
        int t = idx - 16384;
        int nb = t >> 13, r = t & 8191, n = r >> 8, k = r & 255;
        v = fw2[(size_t)nb * 8192 + k * 32 + n];
    } else if (idx < 65536) {    // fw3b[nb][n=128][k=128]
        int t = idx - 32768;
        int nb = t >> 14, r = t & 16383, n = r >> 7, k = r & 127;
        v = fw3[(size_t)nb * 16384 + k * 128 + n];
    } else if (idx < 98304) {    // giwb[hop][n][k]
        int t = idx - 65536;
        int hop = t >> 14, r = t & 16383, n = r >> 7, k = r & 127;
        v = giw[(size_t)hop * 16384 + k * 128 + n];
    } else {                     // gtwb[hop][n][k]
        int t = idx - 98304;
        int hop = t >> 14, r = t & 16383, n = r >> 7, k = r & 127;
        v = gtw[(size_t)hop * 16384 + k * 128 + n];
    }
    WB[idx] = to_bf16u(v);
}

// row-wise LayerNorm over H=128: 8 rows / 256-thread block
__global__ __launch_bounds__(256) void k_ln(const float* __restrict__ x, float* __restrict__ y,
                                            const float* __restrict__ g, const float* __restrict__ b) {
    int row = blockIdx.x * 8 + (threadIdx.x >> 5);
    int lane = threadIdx.x & 31;
    const float4 v = ((const float4*)(x + (size_t)row * TH))[lane];
    float s = v.x + v.y + v.z + v.w;
    for (int o = 16; o > 0; o >>= 1) s += __shfl_down(s, o, 32);
    float mean = __shfl(s, 0, 32) * (1.f / 128.f);
    float4 d;
    d.x = v.x - mean; d.y = v.y - mean; d.z = v.z - mean; d.w = v.w - mean;
    float q = d.x * d.x + d.y * d.y + d.z * d.z + d.w * d.w;
    for (int o = 16; o > 0; o >>= 1) q += __shfl_down(q, o, 32);
    float inv = rsqrtf(__shfl(q, 0, 32) * (1.f / 128.f) + 1e-8f);
    const float4 gg = ((const float4*)g)[lane];
    const float4 bb = ((const float4*)b)[lane];
    float4 o4;
    o4.x = d.x * inv * gg.x + bb.x;
    o4.y = d.y * inv * gg.y + bb.y;
    o4.z = d.z * inv * gg.z + bb.z;
    o4.w = d.w * inv * gg.w + bb.w;
    ((float4*)(y + (size_t)row * TH))[lane] = o4;
}

// NV[b][l][h] f32 -> NVT[b][h][lp] bf16 (l zero-padded to 224)
__global__ __launch_bounds__(128) void k_nvt(const float* __restrict__ NV,
                                             unsigned short* __restrict__ NVT) {
    __shared__ float tl[64][129];
    int b = blockIdx.y, l0 = blockIdx.x * 64, tid = threadIdx.x;
    for (int i = tid; i < 2048; i += 128) {
        int r = i >> 5, c = i & 31;
        int l = l0 + r;
        float4 v = {0.f, 0.f, 0.f, 0.f};
        if (l < TL) v = *(const float4*)(NV + ((size_t)b * TL + l) * TH + c * 4);
        tl[r][c * 4 + 0] = v.x; tl[r][c * 4 + 1] = v.y;
        tl[r][c * 4 + 2] = v.z; tl[r][c * 4 + 3] = v.w;
    }
    __syncthreads();
    int h = tid;
    int ng = (l0 + 64 > TLP) ? (TLP - l0) / 8 : 8;
    for (int lg = 0; lg < ng; ++lg) {
        uint4 u;
        unsigned int p[4];
#pragma unroll
        for (int q = 0; q < 4; ++q) {
            unsigned short ua = to_bf16u(tl[lg * 8 + q * 2 + 0][h]);
            unsigned short ub = to_bf16u(tl[lg * 8 + q * 2 + 1][h]);
            p[q] = (unsigned int)ua | ((unsigned int)ub << 16);
        }
        u.x = p[0]; u.y = p[1]; u.z = p[2]; u.w = p[3];
        *(uint4*)(NVT + ((size_t)b * TH + h) * TLP + l0 + lg * 8) = u;
    }
}

// merged scb weight transposes: blocks [0,512) -> W1T, [512,720) -> W2T
__global__ __launch_bounds__(256) void k_wscb(const float* __restrict__ w1, const float* __restrict__ w2,
                                              unsigned short* __restrict__ W1T,
                                              unsigned short* __restrict__ W2T) {
    int bx = blockIdx.x;
    if (bx < TSH) {
        int s = bx, l = threadIdx.x;
        if (l < TLP) W1T[(size_t)s * TLP + l] = to_bf16u(l < TL ? w1[(size_t)l * TSH + s] : 0.f);
    } else {
        int l = bx - TSH;   // 0..207
        for (int it = 0; it < 2; ++it) {
            int s = it * 256 + threadIdx.x;
            W2T[(size_t)l * TSH + s] = to_bf16u(l < TL ? w2[(size_t)s * TL + l] : 0.f);
        }
    }
}

// scb GEMM1: T[b][h][s] = gelu( sum_l NVT[b][h][l] * w1[l][s] )
__global__ __launch_bounds__(256) void k_mm1(const unsigned short* __restrict__ NVT,
                                             const unsigned short* __restrict__ W1T,
                                             unsigned short* __restrict__ T, int bh) {
    __shared__ unsigned short As[128][40];
    __shared__ unsigned short Bs[128][40];
    int tid = threadIdx.x;
    int b_local = blockIdx.y, b = bh * 256 + b_local;
    int s0 = blockIdx.x * 128;
    int lane = tid & 63, wid = tid >> 6;
    int mw = wid >> 1, nw = wid & 1;
    f32x4 acc[4][4];
#pragma unroll
    for (int i = 0; i < 4; ++i)
#pragma unroll
        for (int j = 0; j < 4; ++j) acc[i][j] = (f32x4){0.f, 0.f, 0.f, 0.f};
    const unsigned short* Abase = NVT + (size_t)b * TH * TLP;
    const unsigned short* Bbase = W1T + (size_t)s0 * TLP;
    for (int kc = 0; kc < 7; ++kc) {
        __syncthreads();
        for (int i = tid; i < 512; i += 256) {
            int r = i >> 2, q = i & 3;
            *(uint4*)&As[r][q * 8] = *(const uint4*)(Abase + (size_t)r * TLP + kc * 32 + q * 8);
            *(uint4*)&Bs[r][q * 8] = *(const uint4*)(Bbase + (size_t)r * TLP + kc * 32 + q * 8);
        }
        __syncthreads();
        int ko = (lane >> 4) * 8;
        short8v af[4], bfr[4];
#pragma unroll
        for (int t = 0; t < 4; ++t) {
            af[t] = *(const short8v*)&As[mw * 64 + t * 16 + (lane & 15)][ko];
            bfr[t] = *(const short8v*)&Bs[nw * 64 + t * 16 + (lane & 15)][ko];
        }
#pragma unroll
        for (int i = 0; i < 4; ++i)
#pragma unroll
            for (int j = 0; j < 4; ++j)
                acc[i][j] = __builtin_amdgcn_mfma_f32_16x16x32_bf16(af[i], bfr[j], acc[i][j], 0, 0, 0);
    }
    int rbase = (lane >> 4) * 4, col = lane & 15;
#pragma unroll
    for (int i = 0; i < 4; ++i)
#pragma unroll
        for (int j = 0; j < 4; ++j) {
            int h0 = mw * 64 + i * 16 + rbase;
            int s = s0 + nw * 64 + j * 16 + col;
#pragma unroll
            for (int r = 0; r < 4; ++r)
                T[((size_t)b_local * TH + h0 + r) * TSH + s] = to_bf16u(gelu_fast(acc[i][j][r]));
        }
}

// scb GEMM2: VS[b][l][h] = NV[b][l][h] + sum_s T[b][h][s] * w2[s][l]
__global__ __launch_bounds__(256) void k_mm2(const unsigned short* __restrict__ T,
                                             const unsigned short* __restrict__ W2T,
                                             const float* __restrict__ NV,
                                             float* __restrict__ VS, int bh) {
    __shared__ unsigned short As[128][40];
    __shared__ unsigned short Bs[64][40];
    int tid = threadIdx.x;
    int b_local = blockIdx.y, b = bh * 256 + b_local;
    int l0 = blockIdx.x * 64;
    int lane = tid & 63, wid = tid >> 6;
    f32x4 acc[2][4];
#pragma unroll
    for (int i = 0; i < 2; ++i)
#pragma unroll
        for (int j = 0; j < 4; ++j) acc[i][j] = (f32x4){0.f, 0.f, 0.f, 0.f};
    const unsigned short* Abase = T + (size_t)b_local * TH * TSH;
    for (int kc = 0; kc < 16; ++kc) {
        __syncthreads();
        for (int i = tid; i < 512; i += 256) {
            int r = i >> 2, q = i & 3;
            *(uint4*)&As[r][q * 8] = *(const uint4*)(Abase + (size_t)r * TSH + kc * 32 + q * 8);
        }
        {
            int r = tid >> 2, q = tid & 3;
            int l = l0 + r;
            uint4 v = {0u, 0u, 0u, 0u};
            if (l < 208) v = *(const uint4*)(W2T + (size_t)l * TSH + kc * 32 + q * 8);
            *(uint4*)&Bs[r][q * 8] = v;
        }
        __syncthreads();
        int ko = (lane >> 4) * 8;
        short8v af[2], bfr[4];
#pragma unroll
        for (int t = 0; t < 2; ++t)
            af[t] = *(const short8v*)&As[wid * 32 + t * 16 + (lane & 15)][ko];
#pragma unroll
        for (int j = 0; j < 4; ++j)
            bfr[j] = *(const short8v*)&Bs[j * 16 + (lane & 15)][ko];
#pragma unroll
        for (int i = 0; i < 2; ++i)
#pragma unroll
            for (int j = 0; j < 4; ++j)
                acc[i][j] = __builtin_amdgcn_mfma_f32_16x16x32_bf16(af[i], bfr[j], acc[i][j], 0, 0, 0);
    }
    int rbase = (lane >> 4) * 4, col = lane & 15;
#pragma unroll
    for (int i = 0; i < 2; ++i)
#pragma unroll
        for (int j = 0; j < 4; ++j) {
            int l = l0 + j * 16 + col;
            if (l < TL) {
                int h0 = wid * 32 + i * 16 + rbase;
                size_t off = ((size_t)b * TL + l) * TH + h0;
                const float4 res = *(const float4*)(NV + off);
                float4 o;
                o.x = acc[i][j][0] + res.x;
                o.y = acc[i][j][1] + res.y;
                o.z = acc[i][j][2] + res.z;
                o.w = acc[i][j][3] + res.w;
                *(float4*)(VS + off) = o;
            }
        }
}

// fused fcb stage1+2; bf16 pre-transposed weights; fast gelu; Yl XOR-swizzled
__global__ __launch_bounds__(256) void k_ffuse(const float* __restrict__ NV,
                                               const unsigned short* __restrict__ FW1B,
                                               const unsigned short* __restrict__ FW2B,
                                               unsigned short* __restrict__ Z) {
    __shared__ unsigned short As[64][40];
    __shared__ unsigned short BsBuf[256 * 40];     // f1: [256][40]; f2: [32][264]
    __shared__ unsigned short Yl[64 * 264];
    int tid = threadIdx.x;
    int m0 = blockIdx.x * 64;   // rows-of-32
    int lane = tid & 63, wid = tid >> 6;
    // stage A (64 x 32, f32 -> bf16)
    for (int i = tid; i < 512; i += 256) {
        int r = i >> 3, q = i & 7;
        const float4 v = *(const float4*)(NV + (size_t)(m0 + r) * 32 + q * 4);
        ushort4 u;
        u.x = to_bf16u(v.x); u.y = to_bf16u(v.y); u.z = to_bf16u(v.z); u.w = to_bf16u(v.w);
        *(ushort4*)&As[r][q * 4] = u;
    }
    // stage B1: FW1B[256][32] -> BsBuf[n][k] stride 40 (pure copy)
    for (int i = tid; i < 1024; i += 256) {
        int r = i >> 2, q = i & 3;
        *(uint4*)&BsBuf[r * 40 + q * 8] = *(const uint4*)(FW1B + r * 32 + q * 8);
    }
    __syncthreads();
    // f1 fragment loads (Bs1 dead after this)
    int ko = (lane >> 4) * 8;
    short8v af[4], bfr[4];
#pragma unroll
    for (int t = 0; t < 4; ++t) {
        af[t] = *(const short8v*)&As[t * 16 + (lane & 15)][ko];
        bfr[t] = *(const short8v*)&BsBuf[(wid * 64 + t * 16 + (lane & 15)) * 40 + ko];
    }
    __syncthreads();
    // f1 MFMA + gelu + swizzled Yl store
    {
        f32x4 acc[4][4];
#pragma unroll
        for (int i = 0; i < 4; ++i)
#pragma unroll
            for (int j = 0; j < 4; ++j) acc[i][j] = (f32x4){0.f, 0.f, 0.f, 0.f};
#pragma unroll
        for (int i = 0; i < 4; ++i)
#pragma unroll
            for (int j = 0; j < 4; ++j)
                acc[i][j] = __builtin_amdgcn_mfma_f32_16x16x32_bf16(af[i], bfr[j], acc[i][j], 0, 0, 0);
        int rbase = (lane >> 4) * 4, col = lane & 15;
#pragma unroll
        for (int i = 0; i < 4; ++i)
#pragma unroll
            for (int j = 0; j < 4; ++j)
#pragma unroll
                for (int r = 0; r < 4; ++r) {
                    int m = i * 16 + rbase + r;
                    int n = wid * 64 + j * 16 + col;
                    int idx = (m * 264 + n) ^ (((m >> 2) & 7) << 3);
                    Yl[idx] = to_bf16u(gelu_fast(acc[i][j][r]));
                }
    }
    // stage B2: FW2B[32][256] -> BsBuf[n'][k] stride 264 (pure copy), aliases Bs1
    for (int i = tid; i < 1024; i += 256) {
        int r = i >> 5, q = i & 31;
        *(uint4*)&BsBuf[r * 264 + q * 8] = *(const uint4*)(FW2B + r * 256 + q * 8);
    }
    __syncthreads();
    // f2: Z[m][n'] = Y @ W2, K=256
    {
        f32x4 acc2[2];
        acc2[0] = (f32x4){0.f, 0.f, 0.f, 0.f};
        acc2[1] = (f32x4){0.f, 0.f, 0.f, 0.f};
        int mrow = wid * 16 + (lane & 15);
        int sw = ((mrow >> 2) & 7) << 3;
        for (int kc = 0; kc < 8; ++kc) {
            int ko2 = kc * 32 + (lane >> 4) * 8;
            short8v a2 = *(const short8v*)&Yl[(mrow * 264 + ko2) ^ sw];
            short8v b0 = *(const short8v*)&BsBuf[(lane & 15) * 264 + ko2];
            short8v b1 = *(const short8v*)&BsBuf[(16 + (lane & 15)) * 264 + ko2];
            acc2[0] = __builtin_amdgcn_mfma_f32_16x16x32_bf16(a2, b0, acc2[0], 0, 0, 0);
            acc2[1] = __builtin_amdgcn_mfma_f32_16x16x32_bf16(a2, b1, acc2[1], 0, 0, 0);
        }
        int rbase = (lane >> 4) * 4, col = lane & 15;
#pragma unroll
        for (int j = 0; j < 2; ++j)
#pragma unroll
            for (int r = 0; r < 4; ++r)
                Z[(size_t)(m0 + wid * 16 + rbase + r) * 32 + j * 16 + col] =
                    to_bf16u(acc2[j][r]);
    }
}

// C[N,128] = A[N,128](bf16) @ WB[n][k](bf16, pre-transposed) (+R f32); N mult of 128
__global__ __launch_bounds__(256) void k_gmm_b(const unsigned short* __restrict__ A,
                                               const unsigned short* __restrict__ WB,
                                               const float* __restrict__ R,
                                               float* __restrict__ C) {
    __shared__ unsigned short As[128][40];
    __shared__ unsigned short Bs[128][40];
    int tid = threadIdx.x;
    int m0 = blockIdx.x * 128;
    int lane = tid & 63, wid = tid >> 6;
    int mw = wid >> 1, nw = wid & 1;
    f32x4 acc[4][4];
#pragma unroll
    for (int i = 0; i < 4; ++i)
#pragma unroll
        for (int j = 0; j < 4; ++j) acc[i][j] = (f32x4){0.f, 0.f, 0.f, 0.f};
    for (int kc = 0; kc < 4; ++kc) {
        __syncthreads();
        for (int i = tid; i < 512; i += 256) {
            int r = i >> 2, q = i & 3;
            *(uint4*)&As[r][q * 8] = *(const uint4*)(A + (size_t)(m0 + r) * TH + kc * 32 + q * 8);
            *(uint4*)&Bs[r][q * 8] = *(const uint4*)(WB + (size_t)r * TH + kc * 32 + q * 8);
        }
        __syncthreads();
        int ko = (lane >> 4) * 8;
        short8v af[4], bfr[4];
#pragma unroll
        for (int t = 0; t < 4; ++t) {
            af[t] = *(const short8v*)&As[mw * 64 + t * 16 + (lane & 15)][ko];
            bfr[t] = *(const short8v*)&Bs[nw * 64 + t * 16 + (lane & 15)][ko];
        }
#pragma unroll
        for (int i = 0; i < 4; ++i)
#pragma unroll
            for (int j = 0; j < 4; ++j)
                acc[i][j] = __builtin_amdgcn_mfma_f32_16x16x32_bf16(af[i], bfr[j], acc[i][j], 0, 0, 0);
    }
    int rbase = (lane >> 4) * 4, col = lane & 15;
#pragma unroll
    for (int i = 0; i < 4; ++i)
#pragma unroll
        for (int j = 0; j < 4; ++j) {
            int n = nw * 64 + j * 16 + col;
#pragma unroll
            for (int r = 0; r < 4; ++r) {
                size_t off = (size_t)(m0 + mw * 64 + i * 16 + rbase + r) * TH + n;
                float v = acc[i][j][r];
                if (R) v += R[off];
                C[off] = v;
            }
        }
}

// alpha = softmax(V@wv over L); g = sum_l alpha*V
__global__ __launch_bounds__(256) void k_pool(const float* __restrict__ V, const float* __restrict__ wv,
                                              float* __restrict__ g) {
    __shared__ float sc[TL];
    __shared__ float red[4];
    int b = blockIdx.x, tid = threadIdx.x;
    if (tid < TL) {
        float a = 0.f;
        const float* vp = V + (size_t)(b * TL + tid) * TH;
        for (int h = 0; h < TH; ++h) a += vp[h] * wv[h];
        sc[tid] = a;
    }
    __syncthreads();
    float m = (tid < TL) ? sc[tid] : -INFINITY;
    m = block_reduce_max(m, red);
    float e = (tid < TL) ? expf(sc[tid] - m) : 0.f;
    float s = block_reduce_sum(e, red);
    if (tid < TL) sc[tid] = e / s;
    __syncthreads();
    if (tid < TH) {
        float a = 0.f;
        for (int l = 0; l < TL; ++l) a += sc[l] * V[(size_t)(b * TL + l) * TH + tid];
        g[b * TH + tid] = a;
    }
}

// merged 4x scores: out[n,k] = sum_d f[n, k*32+d] * vec[k*32+d]
__global__ __launch_bounds__(256) void k_scores4(
        const float* __restrict__ f0, const float* __restrict__ v0, float* __restrict__ o0, int n0,
        const float* __restrict__ f1, const float* __restrict__ v1, float* __restrict__ o1, int n1,
        const float* __restrict__ f2, const float* __restrict__ v2, float* __restrict__ o2, int n2,
        const float* __restrict__ f3, const float* __restrict__ v3, float* __restrict__ o3, int n3) {
    int t = blockIdx.x * 256 + threadIdx.x;
    const float* f; const float* vec; float* o;
    if (t < n0 * 4) { f = f0; vec = v0; o = o0; }
    else {
        t -= n0 * 4;
        if (t < n1 * 4) { f = f1; vec = v1; o = o1; }
        else {
            t -= n1 * 4;
            if (t < n2 * 4) { f = f2; vec = v2; o = o2; }
            else {
                t -= n2 * 4;
                if (t >= n3 * 4) return;
                f = f3; vec = v3; o = o3;
            }
        }
    }
    int node = t >> 2, k = t & 3;
    const float* fp = f + (size_t)node * TH + k * TD;
    const float* vp = vec + k * TD;
    float a = 0.f;
#pragma unroll
    for (int d = 0; d < TD; ++d) a += fp[d] * vp[d];
    o[t] = a;
}

// fused per-dst-node GAT; cur bf16 in, nxt bf16 out, ACC f32
__global__ __launch_bounds__(128) void k_gat(const unsigned short* __restrict__ tax_cur,
                                             const float* __restrict__ fs_i, const float* __restrict__ el_i,
                                             const float* __restrict__ er_i, const int* __restrict__ src_i,
                                             const float* __restrict__ bi,
                                             const float* __restrict__ fs_t, const float* __restrict__ el_t,
                                             const float* __restrict__ er_t, const int* __restrict__ src_t,
                                             const float* __restrict__ bt,
                                             unsigned short* __restrict__ tax_nxt,
                                             float* __restrict__ acc, int hop) {
    int n = blockIdx.x, h = threadIdx.x, k = h >> 5;
    float cur = bfu_to_f(tax_cur[(size_t)n * TH + h]);
    float ti, tt2;
    {
        float er = er_i[n * 4 + k];
        int s[4]; float e[4]; float m = -INFINITY;
#pragma unroll
        for (int j = 0; j < 4; ++j) {
            s[j] = src_i[n * 4 + j];
            float xx = el_i[s[j] * 4 + k] + er;
            e[j] = xx > 0.f ? xx : 0.2f * xx;
            m = fmaxf(m, e[j]);
        }
        float ssum = 0.f, av = 0.f;
#pragma unroll
        for (int j = 0; j < 4; ++j) {
            float a = expf(e[j] - m);
            ssum += a;
            av += a * fs_i[(size_t)s[j] * TH + h];
        }
        ti = fmaxf(av / ssum + cur + bi[h], 0.f);
    }
    {
        float er = er_t[n * 4 + k];
        int s[2]; float e[2]; float m = -INFINITY;
#pragma unroll
        for (int j = 0; j < 2; ++j) {
            s[j] = src_t[n * 2 + j];
            float xx = el_t[s[j] * 4 + k] + er;
            e[j] = xx > 0.f ? xx : 0.2f * xx;
            m = fmaxf(m, e[j]);
        }
        float ssum = 0.f, av = 0.f;
#pragma unroll
        for (int j = 0; j < 2; ++j) {
            float a = expf(e[j] - m);
            ssum += a;
            av += a * fs_t[(size_t)s[j] * TH + h];
        }
        tt2 = fmaxf(av / ssum + cur + bt[h], 0.f);
    }
    float nx = ti + tt2;
    size_t ai = (size_t)n * TH + h;
    tax_nxt[ai] = to_bf16u(nx);
    acc[ai] = (hop == 0) ? nx : acc[ai] + nx;
}

// local + mul
__global__ __launch_bounds__(128) void k_local(const int* __restrict__ root, const float* __restrict__ acc,
                                               const float* __restrict__ g, float* __restrict__ local,
                                               float* __restrict__ mul) {
    __shared__ float red[2];
    int bf = blockIdx.x, b = bf >> 5;
    int h = threadIdx.x;
    int r = root[bf];
    float v = 0.f;
    if (r != -1) {
        int rc = r < 0 ? 0 : r;
        v = acc[(size_t)(b * TTP + rc) * TH + h] * 0.5f;
    }
    local[(size_t)bf * TH + h] = v;
    float s = block_reduce_sum(v * g[b * TH + h], red);
    if (h == 0) mul[bf] = s;
}

// per-b fuse; writes PB[b][h] bf16
__global__ __launch_bounds__(128) void k_fuse(const float* __restrict__ mul, const float* __restrict__ local,
                                              const float* __restrict__ g,
                                              const float* __restrict__ liw_g, const float* __restrict__ liw_b,
                                              const float* __restrict__ int_g, const float* __restrict__ int_b,
                                              const float* __restrict__ uni_w, unsigned short* __restrict__ PB) {
    __shared__ float lm[TFT], wv_[TFT], inten[TH];
    __shared__ float red[2];
    int b = blockIdx.x, tid = threadIdx.x;
    if (tid < TFT) lm[tid] = mul[b * TFT + tid];
    __syncthreads();
    if (tid < TFT) {
        float mean = 0.f;
        for (int f = 0; f < TFT; ++f) mean += lm[f];
        mean *= (1.f / TFT);
        float var = 0.f;
        for (int f = 0; f < TFT; ++f) { float d = lm[f] - mean; var += d * d; }
        var *= (1.f / TFT);
        float ln = (lm[tid] - mean) * rsqrtf(var + 1e-8f) * liw_g[tid] + liw_b[tid];
        wv_[tid] = (lm[tid] != 0.f) ? ln : -INFINITY;
    }
    __syncthreads();
    if (tid < TFT) {
        float mx = -INFINITY;
        for (int f = 0; f < TFT; ++f) mx = fmaxf(mx, wv_[f]);
        float s = 0.f;
        for (int f = 0; f < TFT; ++f) s += expf(wv_[f] - mx);
        lm[tid] = expf(wv_[tid] - mx) / s;
    }
    __syncthreads();
    float ip = g[b * TH + tid];
    for (int f = 0; f < TFT; ++f) ip += lm[f] * local[(size_t)(b * TFT + f) * TH + tid];
    float mean = block_reduce_sum(ip, red) * (1.f / TH);
    float d = ip - mean;
    float var = block_reduce_sum(d * d, red) * (1.f / TH);
    inten[tid] = d * rsqrtf(var + 1e-8f) * int_g[tid] + int_b[tid];
    __syncthreads();
    float a = 0.f;
    for (int hp = 0; hp < TH; ++hp) a += inten[hp] * uni_w[hp * TH + tid];
    PB[(size_t)b * TH + tid] = to_bf16u(a);
}

// E f32 -> EB bf16, rows padded to TIPAD
__global__ __launch_bounds__(256) void k_ebc(const float* __restrict__ E,
                                             unsigned short* __restrict__ EB) {
    int t = blockIdx.x * 256 + threadIdx.x;
    if (t >= TIPAD * TH / 8) return;
    size_t base = (size_t)t * 8;
    int row = (int)(base >> 7);
    float4 a = {0.f, 0.f, 0.f, 0.f}, b = {0.f, 0.f, 0.f, 0.f};
    if (row < TITEMS) {
        a = *(const float4*)(E + base);
        b = *(const float4*)(E + base + 4);
    }
    ushort4 u0, u1;
    u0.x = to_bf16u(a.x); u0.y = to_bf16u(a.y); u0.z = to_bf16u(a.z); u0.w = to_bf16u(a.w);
    u1.x = to_bf16u(b.x); u1.y = to_bf16u(b.y); u1.z = to_bf16u(b.z); u1.w = to_bf16u(b.w);
    *(ushort4*)(EB + base) = u0;
    *(ushort4*)(EB + base + 4) = u1;
}

// out[b,i] = PB[b,:] . EB[i,:]  (bf16 MFMA, 128b x 128i tile)
__global__ __launch_bounds__(256) void k_final_m(const unsigned short* __restrict__ PB,
                                                 const unsigned short* __restrict__ EB,
                                                 float* __restrict__ out) {
    __shared__ unsigned short As[128][136];
    __shared__ unsigned short Bs[128][136];
    int tid = threadIdx.x;
    int i0 = blockIdx.x * 128, b0 = blockIdx.y * 128;
    for (int i = tid; i < 2048; i += 256) {
        int r = i >> 4, q = i & 15;
        *(uint4*)&As[r][q * 8] = *(const uint4*)(PB + (size_t)(b0 + r) * TH + q * 8);
    }
    for (int i = tid; i < 2048; i += 256) {
        int r = i >> 4, q = i & 15;
        *(uint4*)&Bs[r][q * 8] = *(const uint4*)(EB + (size_t)(i0 + r) * TH + q * 8);
    }
    __syncthreads();
    int lane = tid & 63, wid = tid >> 6;
    int mw = wid >> 1, nw = wid & 1;
    f32x4 acc[4][4];
#pragma unroll
    for (int i = 0; i < 4; ++i)
#pragma unroll
        for (int j = 0; j < 4; ++j) acc[i][j] = (f32x4){0.f, 0.f, 0.f, 0.f};
#pragma unroll
    for (int kc = 0; kc < 4; ++kc) {
        int ko = kc * 32 + (lane >> 4) * 8;
        short8v af[4], bfr[4];
#pragma unroll
        for (int t = 0; t < 4; ++t) {
            af[t] = *(const short8v*)&As[mw * 64 + t * 16 + (lane & 15)][ko];
            bfr[t] = *(const short8v*)&Bs[nw * 64 + t * 16 + (lane & 15)][ko];
        }
#pragma unroll
        for (int i = 0; i < 4; ++i)
#pragma unroll
            for (int j = 0; j < 4; ++j)
                acc[i][j] = __builtin_amdgcn_mfma_f32_16x16x32_bf16(af[i], bfr[j], acc[i][j], 0, 0, 0);
    }
    int rbase = (lane >> 4) * 4, col = lane & 15;
#pragma unroll
    for (int i = 0; i < 4; ++i)
#pragma unroll
        for (int j = 0; j < 4; ++j) {
            int ii = i0 + nw * 64 + j * 16 + col;
            if (ii < TITEMS) {
#pragma unroll
                for (int r = 0; r < 4; ++r)
                    out[(size_t)(b0 + mw * 64 + i * 16 + rbase + r) * TITEMS + ii] = acc[i][j][r];
            }
        }
}

extern "C" void kernel_launch(void* const* d_in, const int* in_sizes, int n_in,
                              void* d_out, int out_size, void* d_ws, size_t ws_size,
                              hipStream_t stream) {
    const int*   seq        = (const int*)d_in[0];
    const int*   root       = (const int*)d_in[1];
    const int*   i2t_src    = (const int*)d_in[3];
    const int*   t2t_src    = (const int*)d_in[5];
    const int*   item_ids   = (const int*)d_in[6];
    const int*   tax_ids    = (const int*)d_in[7];
    const float* item_embed = (const float*)d_in[8];
    const float* tax_embed  = (const float*)d_in[9];
    const float* scb_ln_g   = (const float*)d_in[10];
    const float* scb_ln_b   = (const float*)d_in[11];
    const float* scb_w1     = (const float*)d_in[12];
    const float* scb_w2     = (const float*)d_in[13];
    const float* fcb_ln_g   = (const float*)d_in[14];
    const float* fcb_ln_b   = (const float*)d_in[15];
    const float* fcb_w1     = (const float*)d_in[16];
    const float* fcb_w2     = (const float*)d_in[17];
    const float* fcb_w3     = (const float*)d_in[18];
    const float* wv         = (const float*)d_in[19];
    const float* gi_w       = (const float*)d_in[20];
    const float* gi_al      = (const float*)d_in[21];
    const float* gi_ar      = (const float*)d_in[22];
    const float* gi_b       = (const float*)d_in[23];
    const float* gt_w       = (const float*)d_in[24];
    const float* gt_al      = (const float*)d_in[25];
    const float* gt_ar      = (const float*)d_in[26];
    const float* gt_b       = (const float*)d_in[27];
    const float* liw_g      = (const float*)d_in[28];
    const float* liw_b      = (const float*)d_in[29];
    const float* int_g      = (const float*)d_in[30];
    const float* int_b      = (const float*)d_in[31];
    const float* uni_w      = (const float*)d_in[32];

    char* w = (char*)d_ws;
    float* V     = (float*)(w + 0);           // 52.4MB (V / fs_i)
    float* NV    = (float*)(w + 52428800);    // 52.4MB (nv / ITEMHB)
    float* FSI   = V;
    unsigned short* ITEMHB = (unsigned short*)(w + 52428800);  // 26.2MB bf16 (GAT phase)
    // mixer-scb phase:
    unsigned short* NVT = (unsigned short*)(w + 104857600);  // 29.4MB
    unsigned short* T   = (unsigned short*)(w + 134217728);  // 33.6MB
    unsigned short* W1T = (unsigned short*)(w + 167772160);  // 229KB
    unsigned short* W2T = (unsigned short*)(w + 168001536);  // 213KB
    // mixer-fcb phase:
    unsigned short* ZB  = (unsigned short*)(w + 104857600);  // 26.2MB
    // GAT phase:
    unsigned short* TAXB0 = (unsigned short*)(w + 104857600); // 8.4MB bf16
    unsigned short* TAXB1 = (unsigned short*)(w + 113246208); // 8.4MB bf16
    float* ACC   = (float*)(w + 138412032);
    float* FDI   = (float*)(w + 155189248);
    float* FST   = (float*)(w + 171966464);
    float* ELI   = (float*)(w + 188743680);
    float* ERI   = (float*)(w + 190382080);
    float* ELT   = (float*)(w + 190906368);
    float* ERT   = (float*)(w + 191430656);
    float* LOCAL = (float*)(w + 191954944);   // 8.4MB; WB parked here until k_local
    float* G     = (float*)(w + 200343552);
    float* MUL   = (float*)(w + 200605696);
    // converted weights (262KB, dead before k_local writes LOCAL):
    unsigned short* WB = (unsigned short*)(w + 191954944);
    // final phase:
    unsigned short* EB = (unsigned short*)(w + 155189248);   // 25.6MB (aliases FDI+FST)
    unsigned short* PB = (unsigned short*)(w + 200671232);   // 128KB
    if (ws_size < 200933376ull) return;

    // one-time weight conversion (fcb w1/w2/w3, gi_w, gt_w -> bf16 [n][k])
    k_wcvt<<<512, 256, 0, stream>>>(fcb_w1, fcb_w2, fcb_w3, gi_w, gt_w, WB);

    // ---- global intention (mixer) ----
    k_gather<<<(TB * TL * 32 + 255) / 256, 256, 0, stream>>>(item_embed, seq, V, TB * TL);
    for (int nb = 0; nb < 2; ++nb) {
        k_ln<<<TB * TL / 8, 256, 0, stream>>>(V, NV, scb_ln_g + nb * TH, scb_ln_b + nb * TH);
        // scb via MFMA
        k_nvt<<<dim3(4, TB), 128, 0, stream>>>(NV, NVT);
        k_wscb<<<720, 256, 0, stream>>>(scb_w1 + nb * TL * TSH, scb_w2 + nb * TSH * TL, W1T, W2T);
        for (int bh = 0; bh < 2; ++bh) {
            k_mm1<<<dim3(4, 256), 256, 0, stream>>>(NVT, W1T, T, bh);
            k_mm2<<<dim3(4, 256), 256, 0, stream>>>(T, W2T, NV, V, bh);
        }
        // fcb via MFMA
        k_ln<<<TB * TL / 8, 256, 0, stream>>>(V, NV, fcb_ln_g + nb * TH, fcb_ln_b + nb * TH);
        k_ffuse<<<TB * TL * 4 / 64, 256, 0, stream>>>(NV, WB + nb * 8192, WB + 16384 + nb * 8192, ZB);
        k_gmm_b<<<TB * TL / 128, 256, 0, stream>>>(ZB, WB + 32768 + nb * 16384, NV, V);
    }
    k_pool<<<TB, 256, 0, stream>>>(V, wv, G);

    // ---- local intention (GAT, bf16 features) ----
    k_gather_bf<<<(TNI * 16 + 255) / 256, 256, 0, stream>>>(item_embed, item_ids, ITEMHB, TNI);
    k_gather_bf<<<(TNT * 16 + 255) / 256, 256, 0, stream>>>(tax_embed, tax_ids, TAXB0, TNT);

    unsigned short* curb = TAXB0;
    unsigned short* nxtb = TAXB1;
    for (int hop = 0; hop < 2; ++hop) {
        const unsigned short* WiB = WB + 65536 + hop * 16384;
        const unsigned short* WtB = WB + 98304 + hop * 16384;
        k_gmm_b<<<TNI / 128, 256, 0, stream>>>(ITEMHB, WiB, nullptr, FSI);
        k_gmm_b<<<TNT / 128, 256, 0, stream>>>(curb, WiB, nullptr, FDI);
        k_gmm_b<<<TNT / 128, 256, 0, stream>>>(curb, WtB, nullptr, FST);
        int total = (TNI + 3 * TNT) * TNH;
        k_scores4<<<(total + 255) / 256, 256, 0, stream>>>(
            FSI, gi_al + hop * TH, ELI, TNI,
            FDI, gi_ar + hop * TH, ERI, TNT,
            FST, gt_al + hop * TH, ELT, TNT,
            FST, gt_ar + hop * TH, ERT, TNT);
        k_gat<<<TNT, 128, 0, stream>>>(curb, FSI, ELI, ERI, i2t_src, gi_b + hop * TH,
                                       FST, ELT, ERT, t2t_src, gt_b + hop * TH, nxtb, ACC, hop);
        unsigned short* tmp = curb; curb = nxtb; nxtb = tmp;
    }

    // ---- fuse + final ----
    k_local<<<TB * TFT, 128, 0, stream>>>(root, ACC, G, LOCAL, MUL);
    k_fuse<<<TB, 128, 0, stream>>>(MUL, LOCAL, G, liw_g, liw_b, int_g, int_b, uni_w, PB);
    k_ebc<<<(TIPAD * TH / 8 + 255) / 256, 256, 0, stream>>>(item_embed, EB);
    k_final_m<<<dim3(TIPAD / 128, TB / 128), 256, 0, stream>>>(PB, EB, (float*)d_out);
}